// Round 3
// baseline (2800.433 us; speedup 1.0000x reference)
//
#include <hip/hip_runtime.h>
#include <hip/hip_bf16.h>

#define NN 100000
#define NE 3200000
// dims: IN=128, HID=128, INT=512, OUT=3
// Working model: float tensors are fp32 on device (contract; NaN evidence),
// edge_index dtype probed at runtime (int32 vs int64), output fp32.

typedef unsigned int uint32;
typedef unsigned short ushort16;
typedef long long ll64;

__device__ inline float bflo(uint32 u) { return __uint_as_float(u << 16); }
__device__ inline float bfhi(uint32 u) { return __uint_as_float(u & 0xffff0000u); }
__device__ inline ushort16 f2bf(float f) {
  __hip_bfloat16 h = __float2bfloat16(f);  // RNE
  return *reinterpret_cast<ushort16*>(&h);
}

// ---------------- edge dtype probe ----------------
// int64 edges: odd int32 words of first 16 entries are all 0 (values < 2^31).
// int32 edges: those words are random indices in [0,1e5) -> OR != 0 w.p. ~1.
__global__ void k_probe(const int* __restrict__ ei, int* __restrict__ flag) {
  int acc = 0;
#pragma unroll
  for (int i = 1; i < 32; i += 2) acc |= ei[i];
  *flag = (acc == 0) ? 1 : 0;  // 1 => int64
}

__device__ inline int edge_at(const void* ei, int is64, ll64 idx) {
  return is64 ? (int)((const ll64*)ei)[idx] : ((const int*)ei)[idx];
}

// ---------------- CSR build ----------------

__global__ void k_zero_int(int* p, int n) {
  int i = blockIdx.x * blockDim.x + threadIdx.x;
  if (i < n) p[i] = 0;
}

__global__ void k_count(const void* __restrict__ ei, const int* __restrict__ flag,
                        int* __restrict__ cnt, int e) {
  int i = blockIdx.x * blockDim.x + threadIdx.x;
  if (i < e) {
    int d = edge_at(ei, *flag, (ll64)NE + i);
    atomicAdd(&cnt[d], 1);
  }
}

__global__ void k_dinv(const int* __restrict__ cnt, float* __restrict__ dinv, int n) {
  int i = blockIdx.x * blockDim.x + threadIdx.x;
  if (i < n) dinv[i] = rsqrtf((float)(cnt[i] + 1));  // +1: self-loop
}

// single-block exclusive scan (100k elements); cnt may alias fill
__global__ void k_scan(const int* cnt, int* offs, int* fill, int n) {
  __shared__ int sd[1024];
  __shared__ int carry_s;
  int tid = threadIdx.x;
  if (tid == 0) carry_s = 0;
  __syncthreads();
  for (int base = 0; base < n; base += 1024) {
    int idx = base + tid;
    int v = (idx < n) ? cnt[idx] : 0;
    sd[tid] = v;
    __syncthreads();
    for (int off = 1; off < 1024; off <<= 1) {
      int t = (tid >= off) ? sd[tid - off] : 0;
      __syncthreads();
      sd[tid] += t;
      __syncthreads();
    }
    int carry = carry_s;
    int excl = carry + sd[tid] - v;
    if (idx < n) { offs[idx] = excl; fill[idx] = excl; }
    __syncthreads();
    if (tid == 1023) carry_s = carry + sd[1023];
    __syncthreads();
  }
  if (tid == 0) offs[n] = carry_s;
}

__global__ void k_fill(const void* __restrict__ ei, const int* __restrict__ flag,
                       int* fill, int* __restrict__ csr, int e) {
  int i = blockIdx.x * blockDim.x + threadIdx.x;
  if (i < e) {
    int is64 = *flag;
    int s = edge_at(ei, is64, i);
    int d = edge_at(ei, is64, (ll64)NE + i);
    int pos = atomicAdd(&fill[d], 1);
    csr[pos] = s;
  }
}

// ---------------- Aggregation (pull, 128-dim fp32, one wave per node) --------
// out[i] = dinv[i] * ( sum_{s->i} dinv[s]*x[s] + dinv[i]*x[i] )

__global__ void k_agg(const float* __restrict__ x, float* __restrict__ out,
                      const int* __restrict__ csr, const int* __restrict__ offs,
                      const float* __restrict__ dinv, int n) {
  int node = blockIdx.x * 4 + (threadIdx.x >> 6);
  int lane = threadIdx.x & 63;
  if (node >= n) return;
  const float2* xv = (const float2*)x;  // 64 float2 per row
  int beg = offs[node], end = offs[node + 1];
  float ax = 0.f, ay = 0.f;
  int j = beg;
  for (; j + 1 < end; j += 2) {
    int s0 = csr[j], s1 = csr[j + 1];
    float d0 = dinv[s0], d1 = dinv[s1];
    float2 r0 = xv[s0 * 64 + lane];
    float2 r1 = xv[s1 * 64 + lane];
    ax += d0 * r0.x + d1 * r1.x;
    ay += d0 * r0.y + d1 * r1.y;
  }
  if (j < end) {
    int s = csr[j];
    float d = dinv[s];
    float2 r = xv[s * 64 + lane];
    ax += d * r.x;
    ay += d * r.y;
  }
  float di = dinv[node];
  float2 sf = xv[node * 64 + lane];
  float2 o;
  o.x = di * (ax + di * sf.x);
  o.y = di * (ay + di * sf.y);
  ((float2*)out)[node * 64 + lane] = o;
}

// ------- GEMM: C = relu(A[MxK] @ W[KxN] + bias); C fp32 or bf16 per flag ----

__global__ __launch_bounds__(256) void k_gemm_relu(
    const float* __restrict__ A, const float* __restrict__ W,
    const float* __restrict__ bias, void* __restrict__ Cout,
    int M, int N, int K, int bf16out) {
  __shared__ float As[16][65];
  __shared__ float Bs[16][68];
  int tid = threadIdx.x;
  int tx = tid & 15, ty = tid >> 4;
  int row0 = blockIdx.x * 64;
  int col0 = blockIdx.y * 64;
  float acc[4][4] = {};
  for (int kt = 0; kt < K; kt += 16) {
#pragma unroll
    for (int i = 0; i < 4; i++) {
      int idx = tid + i * 256;
      int m = idx >> 4, k = idx & 15;
      int r = row0 + m;
      As[k][m] = (r < M) ? A[r * K + kt + k] : 0.0f;
    }
#pragma unroll
    for (int i = 0; i < 4; i++) {
      int idx = tid + i * 256;
      int k = idx >> 6, nn = idx & 63;
      Bs[k][nn] = W[(kt + k) * N + col0 + nn];
    }
    __syncthreads();
#pragma unroll
    for (int kk = 0; kk < 16; kk++) {
      float a0 = As[kk][ty * 4 + 0];
      float a1 = As[kk][ty * 4 + 1];
      float a2 = As[kk][ty * 4 + 2];
      float a3 = As[kk][ty * 4 + 3];
      float4 b = *(const float4*)&Bs[kk][tx * 4];
      acc[0][0] += a0 * b.x; acc[0][1] += a0 * b.y; acc[0][2] += a0 * b.z; acc[0][3] += a0 * b.w;
      acc[1][0] += a1 * b.x; acc[1][1] += a1 * b.y; acc[1][2] += a1 * b.z; acc[1][3] += a1 * b.w;
      acc[2][0] += a2 * b.x; acc[2][1] += a2 * b.y; acc[2][2] += a2 * b.z; acc[2][3] += a2 * b.w;
      acc[3][0] += a3 * b.x; acc[3][1] += a3 * b.y; acc[3][2] += a3 * b.z; acc[3][3] += a3 * b.w;
    }
    __syncthreads();
  }
#pragma unroll
  for (int i = 0; i < 4; i++) {
    int r = row0 + ty * 4 + i;
    if (r < M) {
#pragma unroll
      for (int j = 0; j < 4; j++) {
        int c = col0 + tx * 4 + j;
        float v = fmaxf(acc[i][j] + bias[c], 0.0f);
        if (bf16out) ((ushort16*)Cout)[(ll64)r * N + c] = f2bf(v);
        else         ((float*)Cout)[(ll64)r * N + c] = v;
      }
    }
  }
}

// ---------------- Fused tail: out = relu(h3 @ Wi + bi) @ Wc + bc ------------
// h3: [M x 512] bf16, Wi: [512 x 512] fp32, Wc: [512 x 3] fp32; out fp32 [M x 3]

__global__ __launch_bounds__(256) void k_tail(
    const ushort16* __restrict__ A, const float* __restrict__ Wi,
    const float* __restrict__ bi, const float* __restrict__ Wc,
    const float* __restrict__ bc, float* __restrict__ out, int M) {
  __shared__ float As[16][65];
  __shared__ float Bs[16][68];
  __shared__ float sOut[64][3];
  int tid = threadIdx.x;
  int tx = tid & 15, ty = tid >> 4;
  int row0 = blockIdx.x * 64;
  const uint32* A2 = (const uint32*)A;  // bf16 pairs
  if (tid < 192) ((float*)sOut)[tid] = 0.0f;
  float myout[4][3] = {};
  for (int nc = 0; nc < 8; nc++) {
    int col0 = nc * 64;
    float acc[4][4] = {};
    for (int kt = 0; kt < 512; kt += 16) {
#pragma unroll
      for (int i = 0; i < 2; i++) {
        int l = tid + i * 256;
        int m = l >> 3, kp = l & 7;
        int r = row0 + m;
        uint32 v = (r < M) ? A2[((ll64)r * 512 + kt) / 2 + kp] : 0u;
        As[kp * 2 + 0][m] = bflo(v);
        As[kp * 2 + 1][m] = bfhi(v);
      }
#pragma unroll
      for (int i = 0; i < 4; i++) {
        int idx = tid + i * 256;
        int k = idx >> 6, nn = idx & 63;
        Bs[k][nn] = Wi[(kt + k) * 512 + col0 + nn];
      }
      __syncthreads();
#pragma unroll
      for (int kk = 0; kk < 16; kk++) {
        float a0 = As[kk][ty * 4 + 0];
        float a1 = As[kk][ty * 4 + 1];
        float a2 = As[kk][ty * 4 + 2];
        float a3 = As[kk][ty * 4 + 3];
        float4 b = *(const float4*)&Bs[kk][tx * 4];
        acc[0][0] += a0 * b.x; acc[0][1] += a0 * b.y; acc[0][2] += a0 * b.z; acc[0][3] += a0 * b.w;
        acc[1][0] += a1 * b.x; acc[1][1] += a1 * b.y; acc[1][2] += a1 * b.z; acc[1][3] += a1 * b.w;
        acc[2][0] += a2 * b.x; acc[2][1] += a2 * b.y; acc[2][2] += a2 * b.z; acc[2][3] += a2 * b.w;
        acc[3][0] += a3 * b.x; acc[3][1] += a3 * b.y; acc[3][2] += a3 * b.z; acc[3][3] += a3 * b.w;
      }
      __syncthreads();
    }
    // h4 chunk -> accumulate into 3-wide output via Wc
#pragma unroll
    for (int j = 0; j < 4; j++) {
      int n = col0 + tx * 4 + j;
      float w0 = Wc[n * 3 + 0], w1 = Wc[n * 3 + 1], w2 = Wc[n * 3 + 2];
      float bv = bi[n];
#pragma unroll
      for (int i = 0; i < 4; i++) {
        float v = fmaxf(acc[i][j] + bv, 0.0f);
        myout[i][0] += v * w0;
        myout[i][1] += v * w1;
        myout[i][2] += v * w2;
      }
    }
  }
#pragma unroll
  for (int i = 0; i < 4; i++)
#pragma unroll
    for (int c = 0; c < 3; c++)
      atomicAdd(&sOut[ty * 4 + i][c], myout[i][c]);
  __syncthreads();
  if (tid < 192) {
    int r = tid / 3, c = tid % 3;
    int gr = row0 + r;
    if (gr < M) out[gr * 3 + c] = sOut[r][c] + bc[c];
  }
}

// ---------------- launcher ----------------

extern "C" void kernel_launch(void* const* d_in, const int* in_sizes, int n_in,
                              void* d_out, int out_size, void* d_ws, size_t ws_size,
                              hipStream_t stream) {
  const float* x  = (const float*)d_in[0];   // fp32 [NN x 128]
  const void*  ei = d_in[1];                 // int32 or int64 [2 x NE] (probed)
  const float* W1 = (const float*)d_in[2];
  const float* b1 = (const float*)d_in[3];
  const float* W2 = (const float*)d_in[4];
  const float* b2 = (const float*)d_in[5];
  const float* W3 = (const float*)d_in[6];
  const float* b3 = (const float*)d_in[7];
  const float* Wi = (const float*)d_in[8];
  const float* bi = (const float*)d_in[9];
  const float* Wc = (const float*)d_in[10];
  const float* bc = (const float*)d_in[11];
  float* out = (float*)d_out;                // fp32 [NN x 3]

  char* ws = (char*)d_ws;
  float* dinv  = (float*)(ws + 0);                 // 400 KB
  int*   offs  = (int*)(ws + (512ll << 10));       // 400 KB (NN+1)
  int*   fill  = (int*)(ws + (1ll << 20));         // 400 KB
  int*   flag  = (int*)(ws + (1536ll << 10));      // 4 B
  int*   csr   = (int*)(ws + (2ll << 20));         // 12.8 MB -> ends 14.8 MB
  float* bufA  = (float*)(ws + (16ll << 20));      // 51.2 MB fp32 [NN x 128] -> 67.2
  float* bufB  = (float*)(ws + (68ll << 20));      // 51.2 MB fp32 [NN x 128] -> 119.2
  ushort16* h3 = (ushort16*)(ws + (68ll << 20));   // 102.4 MB bf16 [NN x 512] -> 170.4
  // h3 overlaps bufB: h2 (bufB) is dead once Agg3 has produced a3 (bufA).

  const int TB = 256;
  k_probe<<<1, 1, 0, stream>>>((const int*)ei, flag);
  k_zero_int<<<(NN + TB - 1) / TB, TB, 0, stream>>>(fill, NN);
  k_count<<<(NE + TB - 1) / TB, TB, 0, stream>>>(ei, flag, fill, NE);
  k_dinv<<<(NN + TB - 1) / TB, TB, 0, stream>>>(fill, dinv, NN);
  k_scan<<<1, 1024, 0, stream>>>(fill, offs, fill, NN);
  k_fill<<<(NE + TB - 1) / TB, TB, 0, stream>>>(ei, flag, fill, csr, NE);

  const int MB = (NN + 63) / 64;  // 1563
  dim3 g128(MB, 2), g512(MB, 8);
  int aggBlocks = (NN + 3) / 4;

  // layer 1: h1 = relu(Agg(x) @ W1 + b1)
  k_agg<<<aggBlocks, TB, 0, stream>>>(x, bufA, csr, offs, dinv, NN);
  k_gemm_relu<<<g128, TB, 0, stream>>>(bufA, W1, b1, bufB, NN, 128, 128, 0);
  // layer 2
  k_agg<<<aggBlocks, TB, 0, stream>>>(bufB, bufA, csr, offs, dinv, NN);
  k_gemm_relu<<<g128, TB, 0, stream>>>(bufA, W2, b2, bufB, NN, 128, 128, 0);
  // layer 3: aggregate at 128 dims, then 128->512, h3 stored bf16
  k_agg<<<aggBlocks, TB, 0, stream>>>(bufB, bufA, csr, offs, dinv, NN);
  k_gemm_relu<<<g512, TB, 0, stream>>>(bufA, W3, b3, h3, NN, 512, 128, 1);
  // fused MLP head: relu(h3 @ Wi + bi) @ Wc + bc
  k_tail<<<MB, TB, 0, stream>>>(h3, Wi, bi, Wc, bc, out, NN);
}

// Round 4
// 2225.997 us; speedup vs baseline: 1.2581x; 1.2581x over previous
//
#include <hip/hip_runtime.h>
#include <hip/hip_bf16.h>

#define NN 100000
#define NE 3200000
// dims: IN=128, HID=128, INT=512, OUT=3
// fp32 tensors on device; edge_index dtype probed (int32/int64); fp32 output.
// GEMMs on bf16 MFMA with hi/lo split precision (error ~2^-17 per GEMM).

typedef unsigned int uint32;
typedef unsigned short u16;
typedef long long ll64;
typedef __attribute__((ext_vector_type(8))) short short8;
typedef __attribute__((ext_vector_type(4))) float f32x4;

__device__ inline float bflo(uint32 u) { return __uint_as_float(u << 16); }
__device__ inline float bfhi_f(uint32 u) { return __uint_as_float(u & 0xffff0000u); }
__device__ inline float bf2f(u16 s) { return __uint_as_float(((uint32)s) << 16); }
__device__ inline u16 f2bf(float f) {
  __hip_bfloat16 h = __float2bfloat16(f);  // RNE
  return *reinterpret_cast<u16*>(&h);
}

// ---------------- edge dtype probe ----------------
__global__ void k_probe(const int* __restrict__ ei, int* __restrict__ flag) {
  int acc = 0;
#pragma unroll
  for (int i = 1; i < 32; i += 2) acc |= ei[i];
  *flag = (acc == 0) ? 1 : 0;  // 1 => int64
}

__device__ inline int edge_at(const void* ei, int is64, ll64 idx) {
  return is64 ? (int)((const ll64*)ei)[idx] : ((const int*)ei)[idx];
}

// ---------------- CSR build ----------------

__global__ void k_zero_int(int* p, int n) {
  int i = blockIdx.x * blockDim.x + threadIdx.x;
  if (i < n) p[i] = 0;
}

__global__ void k_count(const void* __restrict__ ei, const int* __restrict__ flag,
                        int* __restrict__ cnt, int e) {
  int i = blockIdx.x * blockDim.x + threadIdx.x;
  if (i < e) {
    int d = edge_at(ei, *flag, (ll64)NE + i);
    atomicAdd(&cnt[d], 1);
  }
}

__global__ void k_dinv(const int* __restrict__ cnt, float* __restrict__ dinv, int n) {
  int i = blockIdx.x * blockDim.x + threadIdx.x;
  if (i < n) dinv[i] = rsqrtf((float)(cnt[i] + 1));  // +1: self-loop
}

__global__ void k_scan(const int* cnt, int* offs, int* fill, int n) {
  __shared__ int sd[1024];
  __shared__ int carry_s;
  int tid = threadIdx.x;
  if (tid == 0) carry_s = 0;
  __syncthreads();
  for (int base = 0; base < n; base += 1024) {
    int idx = base + tid;
    int v = (idx < n) ? cnt[idx] : 0;
    sd[tid] = v;
    __syncthreads();
    for (int off = 1; off < 1024; off <<= 1) {
      int t = (tid >= off) ? sd[tid - off] : 0;
      __syncthreads();
      sd[tid] += t;
      __syncthreads();
    }
    int carry = carry_s;
    int excl = carry + sd[tid] - v;
    if (idx < n) { offs[idx] = excl; fill[idx] = excl; }
    __syncthreads();
    if (tid == 1023) carry_s = carry + sd[1023];
    __syncthreads();
  }
  if (tid == 0) offs[n] = carry_s;
}

__global__ void k_fill(const void* __restrict__ ei, const int* __restrict__ flag,
                       int* fill, int* __restrict__ csr, int e) {
  int i = blockIdx.x * blockDim.x + threadIdx.x;
  if (i < e) {
    int is64 = *flag;
    int s = edge_at(ei, is64, i);
    int d = edge_at(ei, is64, (ll64)NE + i);
    int pos = atomicAdd(&fill[d], 1);
    csr[pos] = s;
  }
}

// ---------------- weight pack: fp32 W[KxN] -> MFMA B-fragment order, split ----
// t = ((ntile*(K/32)+kb)*64 + lane)*8 + j  holds  W[kb*32+(lane>>4)*8+j][ntile*16+(lane&15)]
__global__ void k_packW(const float* __restrict__ W, u16* __restrict__ ph,
                        u16* __restrict__ pl, int K, int N) {
  int t = blockIdx.x * blockDim.x + threadIdx.x;
  if (t >= K * N) return;
  int j = t & 7, lane = (t >> 3) & 63, tl = t >> 9;
  int kbn = K >> 5;
  int kb = tl % kbn, ntile = tl / kbn;
  int k = kb * 32 + (lane >> 4) * 8 + j;
  int n2 = ntile * 16 + (lane & 15);
  float v = W[k * N + n2];
  u16 hi = f2bf(v);
  ph[t] = hi;
  pl[t] = f2bf(v - bf2f(hi));
}

// ---------------- Aggregation (pull, 128-dim, one wave per node) ----------------
// out[i] = dinv[i]*( sum dinv[s]*x[s] + dinv[i]*x[i] ), written as split bf16 planes.
// Input: fp32 plane (xf != null) or split bf16 planes.

__global__ void k_agg(const float* __restrict__ xf,
                      const uint32* __restrict__ xhi, const uint32* __restrict__ xlo,
                      uint32* __restrict__ ohi, uint32* __restrict__ olo,
                      const int* __restrict__ csr, const int* __restrict__ offs,
                      const float* __restrict__ dinv, int n) {
  int node = blockIdx.x * 4 + (threadIdx.x >> 6);
  int lane = threadIdx.x & 63;
  if (node >= n) return;
  int beg = offs[node], end = offs[node + 1];
  float ax = 0.f, ay = 0.f;
  if (xf) {
    const float2* xv = (const float2*)xf;
    for (int j = beg; j < end; j++) {
      int s = csr[j];
      float d = dinv[s];
      float2 r = xv[s * 64 + lane];
      ax += d * r.x;
      ay += d * r.y;
    }
    float di = dinv[node];
    float2 sf = xv[node * 64 + lane];
    float vx = di * (ax + di * sf.x);
    float vy = di * (ay + di * sf.y);
    u16 hx = f2bf(vx), hy = f2bf(vy);
    ohi[node * 64 + lane] = (uint32)hx | ((uint32)hy << 16);
    olo[node * 64 + lane] = (uint32)f2bf(vx - bf2f(hx)) | ((uint32)f2bf(vy - bf2f(hy)) << 16);
  } else {
    for (int j = beg; j < end; j++) {
      int s = csr[j];
      float d = dinv[s];
      uint32 h = xhi[s * 64 + lane];
      uint32 l = xlo[s * 64 + lane];
      ax += d * (bflo(h) + bflo(l));
      ay += d * (bfhi_f(h) + bfhi_f(l));
    }
    float di = dinv[node];
    uint32 h = xhi[node * 64 + lane];
    uint32 l = xlo[node * 64 + lane];
    float vx = di * (ax + di * (bflo(h) + bflo(l)));
    float vy = di * (ay + di * (bfhi_f(h) + bfhi_f(l)));
    u16 hx = f2bf(vx), hy = f2bf(vy);
    ohi[node * 64 + lane] = (uint32)hx | ((uint32)hy << 16);
    olo[node * 64 + lane] = (uint32)f2bf(vx - bf2f(hx)) | ((uint32)f2bf(vy - bf2f(hy)) << 16);
  }
}

// ---------------- MFMA GEMM: C = relu(A @ W + bias) ----------------
// A: split bf16 planes [MxK] row-major. W: packed fragments (hi/lo).
// 3-pass: Ahi*Whi + Ahi*Wlo + Alo*Whi. Block 64 rows x 64 cols, 4 waves.
// Output: split planes (outLo != null) or single bf16 (outLo == null).

__global__ __launch_bounds__(256) void k_gemm_mfma(
    const u16* __restrict__ Ahi, const u16* __restrict__ Alo,
    const u16* __restrict__ Bph, const u16* __restrict__ Bpl,
    const float* __restrict__ bias, u16* __restrict__ outHi,
    u16* __restrict__ outLo, int M, int N, int K) {
  int wave = threadIdx.x >> 6, lane = threadIdx.x & 63;
  int quad = lane >> 4, l16 = lane & 15;
  int row0 = blockIdx.x * 64, col0 = blockIdx.y * 64;
  int m = row0 + wave * 16 + l16;  // A-fragment row for this lane
  bool mok = (m < M);
  int kbn = K >> 5;
  f32x4 acc[4] = {{0,0,0,0},{0,0,0,0},{0,0,0,0},{0,0,0,0}};
  short8 zz = {0,0,0,0,0,0,0,0};
  for (int kt = 0; kt < K; kt += 32) {
    short8 ah = zz, al = zz;
    if (mok) {
      ah = *(const short8*)&Ahi[(ll64)m * K + kt + quad * 8];
      al = *(const short8*)&Alo[(ll64)m * K + kt + quad * 8];
    }
    int kb = kt >> 5;
#pragma unroll
    for (int nt = 0; nt < 4; nt++) {
      int ntile = (col0 >> 4) + nt;
      ll64 bidx = ((ll64)(ntile * kbn + kb) * 64 + lane) * 8;
      short8 bh = *(const short8*)&Bph[bidx];
      short8 bl = *(const short8*)&Bpl[bidx];
      acc[nt] = __builtin_amdgcn_mfma_f32_16x16x32_bf16(ah, bh, acc[nt], 0, 0, 0);
      acc[nt] = __builtin_amdgcn_mfma_f32_16x16x32_bf16(ah, bl, acc[nt], 0, 0, 0);
      acc[nt] = __builtin_amdgcn_mfma_f32_16x16x32_bf16(al, bh, acc[nt], 0, 0, 0);
    }
  }
  // C/D layout: row = quad*4 + r, col = l16 (within 16x16 tile)
#pragma unroll
  for (int nt = 0; nt < 4; nt++) {
    int cc = col0 + nt * 16 + l16;
    float bv = bias[cc];
#pragma unroll
    for (int r = 0; r < 4; r++) {
      int rr = row0 + wave * 16 + quad * 4 + r;
      if (rr < M) {
        float v = fmaxf(acc[nt][r] + bv, 0.0f);
        u16 h = f2bf(v);
        outHi[(ll64)rr * N + cc] = h;
        if (outLo) outLo[(ll64)rr * N + cc] = f2bf(v - bf2f(h));
      }
    }
  }
}

// ---------------- Fused tail: out = relu(h3 @ Wi + bi) @ Wc + bc ------------
// h3 bf16 [Mx512] staged once in LDS (XOR-swizzled 16B blocks); Wi packed split
// (2-pass MFMA); h4 chunks fold into Wc in registers; shuffle reduction.

__global__ __launch_bounds__(256) void k_tail_mfma(
    const u16* __restrict__ h3, const u16* __restrict__ Wph,
    const u16* __restrict__ Wpl, const float* __restrict__ bi,
    const float* __restrict__ Wc, const float* __restrict__ bc,
    float* __restrict__ out, int M) {
  __shared__ u16 Als[64 * 512];  // 64 KB, k-blocks xor-swizzled by row&7
  int tid = threadIdx.x;
  int wave = tid >> 6, lane = tid & 63, quad = lane >> 4, l16 = lane & 15;
  int row0 = blockIdx.x * 64;
  short8 zz = {0,0,0,0,0,0,0,0};
  // stage 64 rows x 512 bf16
  for (int c = tid; c < 4096; c += 256) {
    int r = c >> 6, b = c & 63;
    int gr = row0 + r;
    short8 v = zz;
    if (gr < M) v = *(const short8*)&h3[(ll64)gr * 512 + b * 8];
    *(short8*)&Als[r * 512 + (b ^ (r & 7)) * 8] = v;
  }
  __syncthreads();
  float acc3[4][3] = {};
  int arow = wave * 16 + l16;
  for (int nc = 0; nc < 8; nc++) {
    f32x4 acc[4] = {{0,0,0,0},{0,0,0,0},{0,0,0,0},{0,0,0,0}};
    for (int kt = 0; kt < 512; kt += 32) {
      int b8 = (kt >> 3) + quad;  // k-octet index
      short8 a = *(const short8*)&Als[arow * 512 + (b8 ^ (arow & 7)) * 8];
      int kb = kt >> 5;
#pragma unroll
      for (int nt = 0; nt < 4; nt++) {
        int ntile = nc * 4 + nt;
        ll64 bidx = ((ll64)(ntile * 16 + kb) * 64 + lane) * 8;
        short8 bh = *(const short8*)&Wph[bidx];
        short8 bl = *(const short8*)&Wpl[bidx];
        acc[nt] = __builtin_amdgcn_mfma_f32_16x16x32_bf16(a, bh, acc[nt], 0, 0, 0);
        acc[nt] = __builtin_amdgcn_mfma_f32_16x16x32_bf16(a, bl, acc[nt], 0, 0, 0);
      }
    }
#pragma unroll
    for (int nt = 0; nt < 4; nt++) {
      int cc = nc * 64 + nt * 16 + l16;
      float bv = bi[cc];
      float w0 = Wc[cc * 3 + 0], w1 = Wc[cc * 3 + 1], w2 = Wc[cc * 3 + 2];
#pragma unroll
      for (int r = 0; r < 4; r++) {
        float v = fmaxf(acc[nt][r] + bv, 0.0f);
        acc3[r][0] += v * w0;
        acc3[r][1] += v * w1;
        acc3[r][2] += v * w2;
      }
    }
  }
  // reduce over the 16 lanes (l16) sharing rows quad*4+r
#pragma unroll
  for (int r = 0; r < 4; r++)
#pragma unroll
    for (int c = 0; c < 3; c++) {
      float v = acc3[r][c];
      v += __shfl_xor(v, 1);
      v += __shfl_xor(v, 2);
      v += __shfl_xor(v, 4);
      v += __shfl_xor(v, 8);
      acc3[r][c] = v;
    }
  if (l16 == 0) {
    int rbase = row0 + wave * 16 + quad * 4;
#pragma unroll
    for (int r = 0; r < 4; r++) {
      int rr = rbase + r;
      if (rr < M) {
#pragma unroll
        for (int c = 0; c < 3; c++)
          out[(ll64)rr * 3 + c] = acc3[r][c] + bc[c];
      }
    }
  }
}

// ---------------- launcher ----------------

extern "C" void kernel_launch(void* const* d_in, const int* in_sizes, int n_in,
                              void* d_out, int out_size, void* d_ws, size_t ws_size,
                              hipStream_t stream) {
  const float* x  = (const float*)d_in[0];
  const void*  ei = d_in[1];
  const float* W1 = (const float*)d_in[2];
  const float* b1 = (const float*)d_in[3];
  const float* W2 = (const float*)d_in[4];
  const float* b2 = (const float*)d_in[5];
  const float* W3 = (const float*)d_in[6];
  const float* b3 = (const float*)d_in[7];
  const float* Wi = (const float*)d_in[8];
  const float* bi = (const float*)d_in[9];
  const float* Wc = (const float*)d_in[10];
  const float* bc = (const float*)d_in[11];
  float* out = (float*)d_out;

  char* ws = (char*)d_ws;
  const ll64 MB1 = 1ll << 20;
  float* dinv  = (float*)(ws + 0);
  int*   offs  = (int*)(ws + (ll64)(0.5 * MB1));
  int*   fill  = (int*)(ws + 1 * MB1);
  int*   flag  = (int*)(ws + (ll64)(1.5 * MB1));
  int*   csr   = (int*)(ws + 2 * MB1);            // 12.8 MB -> 14.8
  u16* pW1h = (u16*)(ws + 15 * MB1);              // 32 KB each
  u16* pW1l = (u16*)(ws + 15 * MB1 + (128ll << 10));
  u16* pW2h = (u16*)(ws + 15 * MB1 + (256ll << 10));
  u16* pW2l = (u16*)(ws + 15 * MB1 + (384ll << 10));
  u16* pW3h = (u16*)(ws + 15 * MB1 + (512ll << 10));  // 128 KB each
  u16* pW3l = (u16*)(ws + 15 * MB1 + (768ll << 10));
  u16* pWih = (u16*)(ws + 16 * MB1);              // 512 KB each
  u16* pWil = (u16*)(ws + 16 * MB1 + (512ll << 10));
  u16* bufPh = (u16*)(ws + 17 * MB1);             // 25.6 MB -> 42.6
  u16* bufPl = (u16*)(ws + 43 * MB1);             // 25.6 MB -> 68.6
  u16* bufQh = (u16*)(ws + 69 * MB1);             // 25.6 MB -> 94.6
  u16* bufQl = (u16*)(ws + 95 * MB1);             // 25.6 MB -> 120.6
  u16* h3    = (u16*)(ws + 69 * MB1);             // 102.4 MB -> 171.4 (bufQ dead by then)

  const int TB = 256;
  k_probe<<<1, 1, 0, stream>>>((const int*)ei, flag);
  k_zero_int<<<(NN + TB - 1) / TB, TB, 0, stream>>>(fill, NN);
  k_count<<<(NE + TB - 1) / TB, TB, 0, stream>>>(ei, flag, fill, NE);
  k_dinv<<<(NN + TB - 1) / TB, TB, 0, stream>>>(fill, dinv, NN);
  k_scan<<<1, 1024, 0, stream>>>(fill, offs, fill, NN);
  k_fill<<<(NE + TB - 1) / TB, TB, 0, stream>>>(ei, flag, fill, csr, NE);

  // weight packing
  k_packW<<<(128 * 128 + TB - 1) / TB, TB, 0, stream>>>(W1, pW1h, pW1l, 128, 128);
  k_packW<<<(128 * 128 + TB - 1) / TB, TB, 0, stream>>>(W2, pW2h, pW2l, 128, 128);
  k_packW<<<(128 * 512 + TB - 1) / TB, TB, 0, stream>>>(W3, pW3h, pW3l, 128, 512);
  k_packW<<<(512 * 512 + TB - 1) / TB, TB, 0, stream>>>(Wi, pWih, pWil, 512, 512);

  const int MBk = (NN + 63) / 64;  // 1563
  int aggBlocks = (NN + 3) / 4;
  dim3 g128(MBk, 2), g512(MBk, 8);

  // layer 1
  k_agg<<<aggBlocks, TB, 0, stream>>>(x, nullptr, nullptr, (uint32*)bufPh, (uint32*)bufPl,
                                      csr, offs, dinv, NN);
  k_gemm_mfma<<<g128, TB, 0, stream>>>(bufPh, bufPl, pW1h, pW1l, b1, bufQh, bufQl,
                                       NN, 128, 128);
  // layer 2
  k_agg<<<aggBlocks, TB, 0, stream>>>(nullptr, (const uint32*)bufQh, (const uint32*)bufQl,
                                      (uint32*)bufPh, (uint32*)bufPl, csr, offs, dinv, NN);
  k_gemm_mfma<<<g128, TB, 0, stream>>>(bufPh, bufPl, pW2h, pW2l, b2, bufQh, bufQl,
                                       NN, 128, 128);
  // layer 3: aggregate at 128 dims, GEMM 128->512, h3 single bf16
  k_agg<<<aggBlocks, TB, 0, stream>>>(nullptr, (const uint32*)bufQh, (const uint32*)bufQl,
                                      (uint32*)bufPh, (uint32*)bufPl, csr, offs, dinv, NN);
  k_gemm_mfma<<<g512, TB, 0, stream>>>(bufPh, bufPl, pW3h, pW3l, b3, h3, nullptr,
                                       NN, 512, 128);
  // fused MLP head
  k_tail_mfma<<<MBk, TB, 0, stream>>>(h3, pWih, pWil, bi, Wc, bc, out, NN);
}

// Round 5
// 1675.728 us; speedup vs baseline: 1.6712x; 1.3284x over previous
//
#include <hip/hip_runtime.h>
#include <hip/hip_bf16.h>

#define NN 100000
#define NE 3200000
// dims: IN=128, HID=128, INT=512, OUT=3
// fp32 tensors on device; edge_index dtype probed (int32/int64); fp32 output.
// Split precision: every intermediate feature stored as one uint32 = bf16(hi) | bf16(lo)<<16.
// GEMMs: bf16 MFMA 16x16x32, 3-pass (Ah*Bh + Ah*Bl + Al*Bh), fp32 accumulate.

typedef unsigned int uint32;
typedef unsigned short u16;
typedef long long ll64;
typedef __attribute__((ext_vector_type(8))) short short8;
typedef __attribute__((ext_vector_type(4))) float f32x4;

__device__ inline float bflo(uint32 u) { return __uint_as_float(u << 16); }
__device__ inline float bfhi_f(uint32 u) { return __uint_as_float(u & 0xffff0000u); }
__device__ inline float bf2f(u16 s) { return __uint_as_float(((uint32)s) << 16); }
__device__ inline u16 f2bf(float f) {
  __hip_bfloat16 h = __float2bfloat16(f);  // RNE
  return *reinterpret_cast<u16*>(&h);
}
__device__ inline uint32 packsplit(float v) {
  u16 h = f2bf(v);
  u16 l = f2bf(v - bf2f(h));
  return (uint32)h | ((uint32)l << 16);
}
// 8 interleaved words -> hi-plane frag + lo-plane frag
__device__ inline void unpack8(const uint32* __restrict__ p, short8& ah, short8& al) {
  uint4 w0 = *(const uint4*)p;
  uint4 w1 = *(const uint4*)(p + 4);
  ah[0] = (short)(w0.x & 0xffff); al[0] = (short)(w0.x >> 16);
  ah[1] = (short)(w0.y & 0xffff); al[1] = (short)(w0.y >> 16);
  ah[2] = (short)(w0.z & 0xffff); al[2] = (short)(w0.z >> 16);
  ah[3] = (short)(w0.w & 0xffff); al[3] = (short)(w0.w >> 16);
  ah[4] = (short)(w1.x & 0xffff); al[4] = (short)(w1.x >> 16);
  ah[5] = (short)(w1.y & 0xffff); al[5] = (short)(w1.y >> 16);
  ah[6] = (short)(w1.z & 0xffff); al[6] = (short)(w1.z >> 16);
  ah[7] = (short)(w1.w & 0xffff); al[7] = (short)(w1.w >> 16);
}

// ---------------- edge dtype probe ----------------
__global__ void k_probe(const int* __restrict__ ei, int* __restrict__ flag) {
  int acc = 0;
#pragma unroll
  for (int i = 1; i < 32; i += 2) acc |= ei[i];
  *flag = (acc == 0) ? 1 : 0;  // 1 => int64
}
__device__ inline int edge_at(const void* ei, int is64, ll64 idx) {
  return is64 ? (int)((const ll64*)ei)[idx] : ((const int*)ei)[idx];
}

// ---------------- CSR build ----------------
__global__ void k_zero_int(int* p, int n) {
  int i = blockIdx.x * blockDim.x + threadIdx.x;
  if (i < n) p[i] = 0;
}
__global__ void k_count(const void* __restrict__ ei, const int* __restrict__ flag,
                        int* __restrict__ cnt, int e) {
  int i = blockIdx.x * blockDim.x + threadIdx.x;
  if (i < e) atomicAdd(&cnt[edge_at(ei, *flag, (ll64)NE + i)], 1);
}
__global__ void k_dinv(const int* __restrict__ cnt, float* __restrict__ dinv, int n) {
  int i = blockIdx.x * blockDim.x + threadIdx.x;
  if (i < n) dinv[i] = rsqrtf((float)(cnt[i] + 1));  // +1: self-loop
}
// 3-phase scan: block-local excl scan + partials, scan partials, add back
__global__ void k_scan1(const int* __restrict__ cnt, int* __restrict__ offs,
                        int* __restrict__ part, int n) {
  __shared__ int sd[256];
  int tid = threadIdx.x, idx = blockIdx.x * 256 + tid;
  int v = (idx < n) ? cnt[idx] : 0;
  sd[tid] = v;
  __syncthreads();
  for (int off = 1; off < 256; off <<= 1) {
    int t = (tid >= off) ? sd[tid - off] : 0;
    __syncthreads();
    sd[tid] += t;
    __syncthreads();
  }
  if (idx < n) offs[idx] = sd[tid] - v;
  if (tid == 255) part[blockIdx.x] = sd[255];
}
__global__ void k_scan2(int* __restrict__ part, int* __restrict__ total, int nb) {
  __shared__ int sd[512];
  int tid = threadIdx.x;
  int v = (tid < nb) ? part[tid] : 0;
  sd[tid] = v;
  __syncthreads();
  for (int off = 1; off < 512; off <<= 1) {
    int t = (tid >= off) ? sd[tid - off] : 0;
    __syncthreads();
    sd[tid] += t;
    __syncthreads();
  }
  if (tid < nb) part[tid] = sd[tid] - v;
  if (tid == 511) *total = sd[511];
}
__global__ void k_scan3(int* __restrict__ offs, int* __restrict__ fill,
                        const int* __restrict__ part, const int* __restrict__ total, int n) {
  int i = blockIdx.x * 256 + threadIdx.x;
  if (i < n) {
    int o = offs[i] + part[blockIdx.x];
    offs[i] = o;
    fill[i] = o;
  }
  if (i == 0) offs[n] = *total;
}
__global__ void k_fill(const void* __restrict__ ei, const int* __restrict__ flag,
                       int* fill, int* __restrict__ csr, int e) {
  int i = blockIdx.x * blockDim.x + threadIdx.x;
  if (i < e) {
    int is64 = *flag;
    int s = edge_at(ei, is64, i);
    int d = edge_at(ei, is64, (ll64)NE + i);
    int pos = atomicAdd(&fill[d], 1);
    csr[pos] = s;
  }
}

// -------- weight pack: fp32 W[KxN] -> MFMA B-fragment order, hi/lo planes --------
// t = ((ntile*(K/32)+kb)*64 + lane)*8 + j  holds  W[kb*32+(lane>>4)*8+j][ntile*16+(lane&15)]
__global__ void k_packW(const float* __restrict__ W, u16* __restrict__ ph,
                        u16* __restrict__ pl, int K, int N) {
  int t = blockIdx.x * blockDim.x + threadIdx.x;
  if (t >= K * N) return;
  int j = t & 7, lane = (t >> 3) & 63, tl = t >> 9;
  int kbn = K >> 5;
  int kb = tl % kbn, ntile = tl / kbn;
  int k = kb * 32 + (lane >> 4) * 8 + j;
  int n2 = ntile * 16 + (lane & 15);
  float v = W[k * N + n2];
  u16 hi = f2bf(v);
  ph[t] = hi;
  pl[t] = f2bf(v - bf2f(hi));
}

// ---------------- Aggregation (pull, one wave per node, interleaved IO) ----------
// out[i] = dinv[i]*( sum dinv[s]*x[s] + dinv[i]*x[i] )
// Lane covers features {2*lane, 2*lane+1}: one uint2 (8 B) per source row.
__global__ void k_agg(const float* __restrict__ xf, const uint32* __restrict__ xi,
                      uint32* __restrict__ o, const int* __restrict__ csr,
                      const int* __restrict__ offs, const float* __restrict__ dinv, int n) {
  int node = blockIdx.x * 4 + (threadIdx.x >> 6);
  int lane = threadIdx.x & 63;
  if (node >= n) return;
  int beg = offs[node], end = offs[node + 1];
  float ax = 0.f, ay = 0.f;
  float vx, vy;
  if (xf) {
    const float2* xv = (const float2*)xf;
    int j = beg;
    for (; j + 1 < end; j += 2) {
      int s0 = csr[j], s1 = csr[j + 1];
      float d0 = dinv[s0], d1 = dinv[s1];
      float2 r0 = xv[(ll64)s0 * 64 + lane];
      float2 r1 = xv[(ll64)s1 * 64 + lane];
      ax += d0 * r0.x + d1 * r1.x;
      ay += d0 * r0.y + d1 * r1.y;
    }
    if (j < end) {
      int s = csr[j];
      float d = dinv[s];
      float2 r = xv[(ll64)s * 64 + lane];
      ax += d * r.x;
      ay += d * r.y;
    }
    float di = dinv[node];
    float2 sf = xv[(ll64)node * 64 + lane];
    vx = di * (ax + di * sf.x);
    vy = di * (ay + di * sf.y);
  } else {
    const uint2* xv = (const uint2*)xi;
    int j = beg;
    for (; j + 1 < end; j += 2) {
      int s0 = csr[j], s1 = csr[j + 1];
      float d0 = dinv[s0], d1 = dinv[s1];
      uint2 r0 = xv[(ll64)s0 * 64 + lane];
      uint2 r1 = xv[(ll64)s1 * 64 + lane];
      ax += d0 * (bflo(r0.x) + bfhi_f(r0.x)) + d1 * (bflo(r1.x) + bfhi_f(r1.x));
      ay += d0 * (bflo(r0.y) + bfhi_f(r0.y)) + d1 * (bflo(r1.y) + bfhi_f(r1.y));
    }
    if (j < end) {
      int s = csr[j];
      float d = dinv[s];
      uint2 r = xv[(ll64)s * 64 + lane];
      ax += d * (bflo(r.x) + bfhi_f(r.x));
      ay += d * (bflo(r.y) + bfhi_f(r.y));
    }
    float di = dinv[node];
    uint2 sf = xv[(ll64)node * 64 + lane];
    vx = di * (ax + di * (bflo(sf.x) + bfhi_f(sf.x)));
    vy = di * (ay + di * (bflo(sf.y) + bfhi_f(sf.y)));
  }
  ((uint2*)o)[(ll64)node * 64 + lane] = make_uint2(packsplit(vx), packsplit(vy));
}

// -------- MFMA GEMM: C = relu(A @ W + bias); A,C interleaved split --------
// Block 64 rows x 64 cols, 4 waves; wave w = rows [row0+16w, +16).
__global__ __launch_bounds__(256) void k_gemm_mfma(
    const uint32* __restrict__ Ai, const u16* __restrict__ Bph,
    const u16* __restrict__ Bpl, const float* __restrict__ bias,
    uint32* __restrict__ Co, int M, int N, int K) {
  int wave = threadIdx.x >> 6, lane = threadIdx.x & 63;
  int quad = lane >> 4, l16 = lane & 15;
  int row0 = blockIdx.x * 64, col0 = blockIdx.y * 64;
  int m = row0 + wave * 16 + l16;
  bool mok = (m < M);
  int kbn = K >> 5;
  f32x4 acc[4] = {{0,0,0,0},{0,0,0,0},{0,0,0,0},{0,0,0,0}};
  short8 zz = {0,0,0,0,0,0,0,0};
  for (int kb = 0; kb < kbn; kb++) {
    short8 ah = zz, al = zz;
    if (mok) unpack8(&Ai[(ll64)m * K + kb * 32 + quad * 8], ah, al);
#pragma unroll
    for (int nt = 0; nt < 4; nt++) {
      int ntile = (col0 >> 4) + nt;
      ll64 bidx = ((ll64)(ntile * kbn + kb) * 64 + lane) * 8;
      short8 bh = *(const short8*)&Bph[bidx];
      short8 bl = *(const short8*)&Bpl[bidx];
      acc[nt] = __builtin_amdgcn_mfma_f32_16x16x32_bf16(ah, bh, acc[nt], 0, 0, 0);
      acc[nt] = __builtin_amdgcn_mfma_f32_16x16x32_bf16(ah, bl, acc[nt], 0, 0, 0);
      acc[nt] = __builtin_amdgcn_mfma_f32_16x16x32_bf16(al, bh, acc[nt], 0, 0, 0);
    }
  }
#pragma unroll
  for (int nt = 0; nt < 4; nt++) {
    int cc = col0 + nt * 16 + l16;
    float bv = bias[cc];
#pragma unroll
    for (int r = 0; r < 4; r++) {
      int rr = row0 + wave * 16 + quad * 4 + r;
      if (rr < M) Co[(ll64)rr * N + cc] = packsplit(fmaxf(acc[nt][r] + bv, 0.0f));
    }
  }
}

// -------- Fused: h3 = relu(a3@W3+b3) (LDS, bf16) ; out = relu(h3@Wi+bi)@Wc + bc --------
// Block = 64 rows, 4 waves; each wave owns 128 output columns (8 ntiles).
__global__ __launch_bounds__(256) void k_tail_fused(
    const uint32* __restrict__ a3, const u16* __restrict__ W3h,
    const u16* __restrict__ W3l, const float* __restrict__ b3,
    const u16* __restrict__ Wih, const u16* __restrict__ Wil,
    const float* __restrict__ bi, const float* __restrict__ Wc,
    const float* __restrict__ bc, float* __restrict__ out, int M) {
  __shared__ u16 h3s[64 * 512];     // 64 KB, col-octets xor-swizzled by row&7
  __shared__ float sRed[4][64][3];  // 3 KB
  int tid = threadIdx.x;
  int wave = tid >> 6, lane = tid & 63, quad = lane >> 4, l16 = lane & 15;
  int row0 = blockIdx.x * 64;
  short8 zz = {0,0,0,0,0,0,0,0};

  // ---- phase 1: layer-3 GEMM (K=128, kbn=4; N=512) into LDS ----
  for (int half = 0; half < 2; half++) {
    f32x4 acc[4][4];
#pragma unroll
    for (int f = 0; f < 4; f++)
#pragma unroll
      for (int nt = 0; nt < 4; nt++) acc[f][nt] = (f32x4){0, 0, 0, 0};
    for (int kb = 0; kb < 4; kb++) {
      short8 ah[4], al[4];
#pragma unroll
      for (int f = 0; f < 4; f++) {
        int r = row0 + f * 16 + l16;
        ah[f] = zz; al[f] = zz;
        if (r < M) unpack8(&a3[(ll64)r * 128 + kb * 32 + quad * 8], ah[f], al[f]);
      }
#pragma unroll
      for (int nt = 0; nt < 4; nt++) {
        int ntile = wave * 8 + half * 4 + nt;
        ll64 bidx = ((ll64)(ntile * 4 + kb) * 64 + lane) * 8;
        short8 bh = *(const short8*)&W3h[bidx];
        short8 bl = *(const short8*)&W3l[bidx];
#pragma unroll
        for (int f = 0; f < 4; f++) {
          acc[f][nt] = __builtin_amdgcn_mfma_f32_16x16x32_bf16(ah[f], bh, acc[f][nt], 0, 0, 0);
          acc[f][nt] = __builtin_amdgcn_mfma_f32_16x16x32_bf16(ah[f], bl, acc[f][nt], 0, 0, 0);
          acc[f][nt] = __builtin_amdgcn_mfma_f32_16x16x32_bf16(al[f], bh, acc[f][nt], 0, 0, 0);
        }
      }
    }
#pragma unroll
    for (int nt = 0; nt < 4; nt++) {
      int col = (wave * 8 + half * 4 + nt) * 16 + l16;
      float bv = b3[col];
#pragma unroll
      for (int f = 0; f < 4; f++)
#pragma unroll
        for (int r = 0; r < 4; r++) {
          int row = f * 16 + quad * 4 + r;
          float v = fmaxf(acc[f][nt][r] + bv, 0.0f);
          h3s[row * 512 + (((col >> 3) ^ (row & 7)) << 3) + (col & 7)] = f2bf(v);
        }
    }
  }
  __syncthreads();

  // ---- phase 2: h3 @ Wi (K=512, kbn=16) + fold Wc ----
  float acc3[4][4][3] = {};
  for (int half = 0; half < 2; half++) {
    f32x4 acc[4][4];
#pragma unroll
    for (int f = 0; f < 4; f++)
#pragma unroll
      for (int nt = 0; nt < 4; nt++) acc[f][nt] = (f32x4){0, 0, 0, 0};
    for (int kb = 0; kb < 16; kb++) {
      short8 a[4];
#pragma unroll
      for (int f = 0; f < 4; f++) {
        int row = f * 16 + l16;
        int b8 = kb * 4 + quad;
        a[f] = *(const short8*)&h3s[row * 512 + ((b8 ^ (row & 7)) << 3)];
      }
#pragma unroll
      for (int nt = 0; nt < 4; nt++) {
        int ntile = wave * 8 + half * 4 + nt;
        ll64 bidx = ((ll64)(ntile * 16 + kb) * 64 + lane) * 8;
        short8 bh = *(const short8*)&Wih[bidx];
        short8 bl = *(const short8*)&Wil[bidx];
#pragma unroll
        for (int f = 0; f < 4; f++) {
          acc[f][nt] = __builtin_amdgcn_mfma_f32_16x16x32_bf16(a[f], bh, acc[f][nt], 0, 0, 0);
          acc[f][nt] = __builtin_amdgcn_mfma_f32_16x16x32_bf16(a[f], bl, acc[f][nt], 0, 0, 0);
        }
      }
    }
#pragma unroll
    for (int nt = 0; nt < 4; nt++) {
      int col = (wave * 8 + half * 4 + nt) * 16 + l16;
      float bv = bi[col];
      float w0 = Wc[col * 3 + 0], w1 = Wc[col * 3 + 1], w2 = Wc[col * 3 + 2];
#pragma unroll
      for (int f = 0; f < 4; f++)
#pragma unroll
        for (int r = 0; r < 4; r++) {
          float v = fmaxf(acc[f][nt][r] + bv, 0.0f);
          acc3[f][r][0] += v * w0;
          acc3[f][r][1] += v * w1;
          acc3[f][r][2] += v * w2;
        }
    }
  }
  // reduce over the 16 l16 lanes
#pragma unroll
  for (int f = 0; f < 4; f++)
#pragma unroll
    for (int r = 0; r < 4; r++)
#pragma unroll
      for (int c = 0; c < 3; c++) {
        float v = acc3[f][r][c];
        v += __shfl_xor(v, 1);
        v += __shfl_xor(v, 2);
        v += __shfl_xor(v, 4);
        v += __shfl_xor(v, 8);
        acc3[f][r][c] = v;
      }
  if (l16 == 0) {
#pragma unroll
    for (int f = 0; f < 4; f++)
#pragma unroll
      for (int r = 0; r < 4; r++)
#pragma unroll
        for (int c = 0; c < 3; c++)
          sRed[wave][f * 16 + quad * 4 + r][c] = acc3[f][r][c];
  }
  __syncthreads();
  if (tid < 192) {
    int row = tid / 3, c = tid % 3;
    int gr = row0 + row;
    if (gr < M)
      out[(ll64)gr * 3 + c] = sRed[0][row][c] + sRed[1][row][c] +
                              sRed[2][row][c] + sRed[3][row][c] + bc[c];
  }
}

// ---------------- launcher ----------------
extern "C" void kernel_launch(void* const* d_in, const int* in_sizes, int n_in,
                              void* d_out, int out_size, void* d_ws, size_t ws_size,
                              hipStream_t stream) {
  const float* x  = (const float*)d_in[0];
  const void*  ei = d_in[1];
  const float* W1 = (const float*)d_in[2];
  const float* b1 = (const float*)d_in[3];
  const float* W2 = (const float*)d_in[4];
  const float* b2 = (const float*)d_in[5];
  const float* W3 = (const float*)d_in[6];
  const float* b3 = (const float*)d_in[7];
  const float* Wi = (const float*)d_in[8];
  const float* bi = (const float*)d_in[9];
  const float* Wc = (const float*)d_in[10];
  const float* bc = (const float*)d_in[11];
  float* out = (float*)d_out;

  char* ws = (char*)d_ws;
  const ll64 KB = 1ll << 10, MB = 1ll << 20;
  float* dinv  = (float*)(ws + 0);
  int*   offs  = (int*)(ws + 512 * KB);
  int*   fill  = (int*)(ws + 1 * MB);
  int*   flag  = (int*)(ws + 1536 * KB);
  int*   part  = (int*)(ws + 1600 * KB);
  int*   total = (int*)(ws + 1700 * KB);
  int*   csr   = (int*)(ws + 2 * MB);            // 12.8 MB -> 14.8
  u16* pW1h = (u16*)(ws + 15 * MB);
  u16* pW1l = (u16*)(ws + 15 * MB + 256 * KB);
  u16* pW2h = (u16*)(ws + 15 * MB + 512 * KB);
  u16* pW2l = (u16*)(ws + 15 * MB + 768 * KB);
  u16* pW3h = (u16*)(ws + 16 * MB);
  u16* pW3l = (u16*)(ws + 16 * MB + 256 * KB);
  u16* pWih = (u16*)(ws + 16 * MB + 512 * KB);   // 512 KB
  u16* pWil = (u16*)(ws + 17 * MB);              // 512 KB
  uint32* bufA = (uint32*)(ws + 18 * MB);        // 51.2 MB -> 69.2
  uint32* bufB = (uint32*)(ws + 70 * MB);        // 51.2 MB -> 121.2

  const int TB = 256;
  const int SB = (NN + 255) / 256;  // 391 scan blocks
  k_probe<<<1, 1, 0, stream>>>((const int*)ei, flag);
  k_zero_int<<<SB, TB, 0, stream>>>(fill, NN);
  k_count<<<(NE + TB - 1) / TB, TB, 0, stream>>>(ei, flag, fill, NE);
  k_dinv<<<SB, TB, 0, stream>>>(fill, dinv, NN);
  k_scan1<<<SB, TB, 0, stream>>>(fill, offs, part, NN);
  k_scan2<<<1, 512, 0, stream>>>(part, total, SB);
  k_scan3<<<SB, TB, 0, stream>>>(offs, fill, part, total, NN);
  k_fill<<<(NE + TB - 1) / TB, TB, 0, stream>>>(ei, flag, fill, csr, NE);

  k_packW<<<(128 * 128 + TB - 1) / TB, TB, 0, stream>>>(W1, pW1h, pW1l, 128, 128);
  k_packW<<<(128 * 128 + TB - 1) / TB, TB, 0, stream>>>(W2, pW2h, pW2l, 128, 128);
  k_packW<<<(128 * 512 + TB - 1) / TB, TB, 0, stream>>>(W3, pW3h, pW3l, 128, 512);
  k_packW<<<(512 * 512 + TB - 1) / TB, TB, 0, stream>>>(Wi, pWih, pWil, 512, 512);

  const int MBk = (NN + 63) / 64;  // 1563
  int aggBlocks = (NN + 3) / 4;
  dim3 g128(MBk, 2);

  // layer 1
  k_agg<<<aggBlocks, TB, 0, stream>>>(x, nullptr, bufA, csr, offs, dinv, NN);
  k_gemm_mfma<<<g128, TB, 0, stream>>>(bufA, pW1h, pW1l, b1, bufB, NN, 128, 128);
  // layer 2
  k_agg<<<aggBlocks, TB, 0, stream>>>(nullptr, bufB, bufA, csr, offs, dinv, NN);
  k_gemm_mfma<<<g128, TB, 0, stream>>>(bufA, pW2h, pW2l, b2, bufB, NN, 128, 128);
  // layer 3 aggregation (128-dim), then fused GEMM512 + MLP head
  k_agg<<<aggBlocks, TB, 0, stream>>>(nullptr, bufB, bufA, csr, offs, dinv, NN);
  k_tail_fused<<<MBk, TB, 0, stream>>>(bufA, pW3h, pW3l, b3, pWih, pWil, bi,
                                       Wc, bc, out, NN);
}

// Round 6
// 1621.399 us; speedup vs baseline: 1.7272x; 1.0335x over previous
//
#include <hip/hip_runtime.h>
#include <hip/hip_bf16.h>

#define NN 100000
#define NE 3200000
// dims: IN=128, HID=128, INT=512, OUT=3
// fp32 tensors on device; edge_index dtype probed (int32/int64); fp32 output.
// Split precision: every intermediate feature stored as one uint32 = bf16(hi) | bf16(lo)<<16.
// GEMMs: bf16 MFMA 16x16x32, 3-pass (Ah*Bh + Ah*Bl + Al*Bh), fp32 accumulate.
// Round 6: register double-buffer (one-deep prefetch) in all MFMA kernels; agg unroll-4;
// merged small kernels (13 dispatches).

typedef unsigned int uint32;
typedef unsigned short u16;
typedef long long ll64;
typedef __attribute__((ext_vector_type(8))) short short8;
typedef __attribute__((ext_vector_type(4))) float f32x4;

__device__ inline float bflo(uint32 u) { return __uint_as_float(u << 16); }
__device__ inline float bfhi_f(uint32 u) { return __uint_as_float(u & 0xffff0000u); }
__device__ inline float bf2f(u16 s) { return __uint_as_float(((uint32)s) << 16); }
__device__ inline u16 f2bf(float f) {
  __hip_bfloat16 h = __float2bfloat16(f);  // RNE
  return *reinterpret_cast<u16*>(&h);
}
__device__ inline uint32 packsplit(float v) {
  u16 h = f2bf(v);
  u16 l = f2bf(v - bf2f(h));
  return (uint32)h | ((uint32)l << 16);
}
__device__ inline void unpack_raw(uint4 w0, uint4 w1, short8& ah, short8& al) {
  ah[0] = (short)(w0.x & 0xffff); al[0] = (short)(w0.x >> 16);
  ah[1] = (short)(w0.y & 0xffff); al[1] = (short)(w0.y >> 16);
  ah[2] = (short)(w0.z & 0xffff); al[2] = (short)(w0.z >> 16);
  ah[3] = (short)(w0.w & 0xffff); al[3] = (short)(w0.w >> 16);
  ah[4] = (short)(w1.x & 0xffff); al[4] = (short)(w1.x >> 16);
  ah[5] = (short)(w1.y & 0xffff); al[5] = (short)(w1.y >> 16);
  ah[6] = (short)(w1.z & 0xffff); al[6] = (short)(w1.z >> 16);
  ah[7] = (short)(w1.w & 0xffff); al[7] = (short)(w1.w >> 16);
}

__device__ inline int edge_at(const void* ei, int is64, ll64 idx) {
  return is64 ? (int)((const ll64*)ei)[idx] : ((const int*)ei)[idx];
}

// ---------------- init: zero degree counters + edge dtype probe ----------------
__global__ void k_init(const int* __restrict__ ei, int* __restrict__ flag,
                       int* __restrict__ fill, int n) {
  int i = blockIdx.x * blockDim.x + threadIdx.x;
  if (i < n) fill[i] = 0;
  if (i == 0) {
    int acc = 0;
#pragma unroll
    for (int k = 1; k < 32; k += 2) acc |= ei[k];
    *flag = (acc == 0) ? 1 : 0;  // 1 => int64
  }
}
__global__ void k_count(const void* __restrict__ ei, const int* __restrict__ flag,
                        int* __restrict__ cnt, int e) {
  int i = blockIdx.x * blockDim.x + threadIdx.x;
  if (i < e) atomicAdd(&cnt[edge_at(ei, *flag, (ll64)NE + i)], 1);
}
// block-local exclusive scan + partials; also computes dinv from counts
__global__ void k_scan1(const int* __restrict__ cnt, int* __restrict__ offs,
                        int* __restrict__ part, float* __restrict__ dinv, int n) {
  __shared__ int sd[256];
  int tid = threadIdx.x, idx = blockIdx.x * 256 + tid;
  int v = (idx < n) ? cnt[idx] : 0;
  sd[tid] = v;
  __syncthreads();
  for (int off = 1; off < 256; off <<= 1) {
    int t = (tid >= off) ? sd[tid - off] : 0;
    __syncthreads();
    sd[tid] += t;
    __syncthreads();
  }
  if (idx < n) {
    offs[idx] = sd[tid] - v;
    dinv[idx] = rsqrtf((float)(v + 1));  // +1: self-loop
  }
  if (tid == 255) part[blockIdx.x] = sd[255];
}
__global__ void k_scan2(int* __restrict__ part, int* __restrict__ total, int nb) {
  __shared__ int sd[512];
  int tid = threadIdx.x;
  int v = (tid < nb) ? part[tid] : 0;
  sd[tid] = v;
  __syncthreads();
  for (int off = 1; off < 512; off <<= 1) {
    int t = (tid >= off) ? sd[tid - off] : 0;
    __syncthreads();
    sd[tid] += t;
    __syncthreads();
  }
  if (tid < nb) part[tid] = sd[tid] - v;
  if (tid == 511) *total = sd[511];
}
__global__ void k_scan3(int* __restrict__ offs, int* __restrict__ fill,
                        const int* __restrict__ part, const int* __restrict__ total, int n) {
  int i = blockIdx.x * 256 + threadIdx.x;
  if (i < n) {
    int o = offs[i] + part[blockIdx.x];
    offs[i] = o;
    fill[i] = o;
  }
  if (i == 0) offs[n] = *total;
}
__global__ void k_fill(const void* __restrict__ ei, const int* __restrict__ flag,
                       int* fill, int* __restrict__ csr, int e) {
  int i = blockIdx.x * blockDim.x + threadIdx.x;
  if (i < e) {
    int is64 = *flag;
    int s = edge_at(ei, is64, i);
    int d = edge_at(ei, is64, (ll64)NE + i);
    int pos = atomicAdd(&fill[d], 1);
    csr[pos] = s;
  }
}

// -------- weight pack: fp32 W[KxN] -> MFMA B-fragment order, hi/lo planes --------
__device__ inline void packOne(const float* __restrict__ W, u16* __restrict__ ph,
                               u16* __restrict__ pl, int K, int N, int t) {
  int j = t & 7, lane = (t >> 3) & 63, tl = t >> 9;
  int kbn = K >> 5;
  int kb = tl % kbn, ntile = tl / kbn;
  int k = kb * 32 + (lane >> 4) * 8 + j;
  int n2 = ntile * 16 + (lane & 15);
  float v = W[k * N + n2];
  u16 hi = f2bf(v);
  ph[t] = hi;
  pl[t] = f2bf(v - bf2f(hi));
}
__global__ void k_packAll(const float* W1, const float* W2, const float* W3,
                          const float* Wi, u16* p1h, u16* p1l, u16* p2h, u16* p2l,
                          u16* p3h, u16* p3l, u16* pih, u16* pil) {
  int t = blockIdx.x * blockDim.x + threadIdx.x;
  if (t < 16384) packOne(W1, p1h, p1l, 128, 128, t);
  else if (t < 32768) packOne(W2, p2h, p2l, 128, 128, t - 16384);
  else if (t < 98304) packOne(W3, p3h, p3l, 128, 512, t - 32768);
  else if (t < 360448) packOne(Wi, pih, pil, 512, 512, t - 98304);
}

// ---------------- Aggregation (pull, one wave per node, unroll-4) ----------------
// out[i] = dinv[i]*( sum dinv[s]*x[s] + dinv[i]*x[i] ); lane covers feats {2l,2l+1}.
__global__ void k_agg(const float* __restrict__ xf, const uint32* __restrict__ xi,
                      uint32* __restrict__ o, const int* __restrict__ csr,
                      const int* __restrict__ offs, const float* __restrict__ dinv, int n) {
  int node = blockIdx.x * 4 + (threadIdx.x >> 6);
  int lane = threadIdx.x & 63;
  if (node >= n) return;
  int beg = offs[node], end = offs[node + 1];
  float ax = 0.f, ay = 0.f;
  float vx, vy;
  if (xf) {
    const float2* xv = (const float2*)xf;
    int j = beg;
    for (; j + 3 < end; j += 4) {
      int s0 = csr[j], s1 = csr[j + 1], s2 = csr[j + 2], s3 = csr[j + 3];
      float d0 = dinv[s0], d1 = dinv[s1], d2 = dinv[s2], d3 = dinv[s3];
      float2 r0 = xv[(ll64)s0 * 64 + lane];
      float2 r1 = xv[(ll64)s1 * 64 + lane];
      float2 r2 = xv[(ll64)s2 * 64 + lane];
      float2 r3 = xv[(ll64)s3 * 64 + lane];
      ax += d0 * r0.x + d1 * r1.x + d2 * r2.x + d3 * r3.x;
      ay += d0 * r0.y + d1 * r1.y + d2 * r2.y + d3 * r3.y;
    }
    for (; j < end; j++) {
      int s = csr[j];
      float d = dinv[s];
      float2 r = xv[(ll64)s * 64 + lane];
      ax += d * r.x;
      ay += d * r.y;
    }
    float di = dinv[node];
    float2 sf = xv[(ll64)node * 64 + lane];
    vx = di * (ax + di * sf.x);
    vy = di * (ay + di * sf.y);
  } else {
    const uint2* xv = (const uint2*)xi;
    int j = beg;
    for (; j + 3 < end; j += 4) {
      int s0 = csr[j], s1 = csr[j + 1], s2 = csr[j + 2], s3 = csr[j + 3];
      float d0 = dinv[s0], d1 = dinv[s1], d2 = dinv[s2], d3 = dinv[s3];
      uint2 r0 = xv[(ll64)s0 * 64 + lane];
      uint2 r1 = xv[(ll64)s1 * 64 + lane];
      uint2 r2 = xv[(ll64)s2 * 64 + lane];
      uint2 r3 = xv[(ll64)s3 * 64 + lane];
      ax += d0 * (bflo(r0.x) + bfhi_f(r0.x)) + d1 * (bflo(r1.x) + bfhi_f(r1.x)) +
            d2 * (bflo(r2.x) + bfhi_f(r2.x)) + d3 * (bflo(r3.x) + bfhi_f(r3.x));
      ay += d0 * (bflo(r0.y) + bfhi_f(r0.y)) + d1 * (bflo(r1.y) + bfhi_f(r1.y)) +
            d2 * (bflo(r2.y) + bfhi_f(r2.y)) + d3 * (bflo(r3.y) + bfhi_f(r3.y));
    }
    for (; j < end; j++) {
      int s = csr[j];
      float d = dinv[s];
      uint2 r = xv[(ll64)s * 64 + lane];
      ax += d * (bflo(r.x) + bfhi_f(r.x));
      ay += d * (bflo(r.y) + bfhi_f(r.y));
    }
    float di = dinv[node];
    uint2 sf = xv[(ll64)node * 64 + lane];
    vx = di * (ax + di * (bflo(sf.x) + bfhi_f(sf.x)));
    vy = di * (ay + di * (bflo(sf.y) + bfhi_f(sf.y)));
  }
  ((uint2*)o)[(ll64)node * 64 + lane] = make_uint2(packsplit(vx), packsplit(vy));
}

// -------- MFMA GEMM: C = relu(A @ W + bias); A,C interleaved split; reg dbuf --------
__global__ __launch_bounds__(256) void k_gemm_mfma(
    const uint32* __restrict__ Ai, const u16* __restrict__ Bph,
    const u16* __restrict__ Bpl, const float* __restrict__ bias,
    uint32* __restrict__ Co, int M, int N, int K) {
  int wave = threadIdx.x >> 6, lane = threadIdx.x & 63;
  int quad = lane >> 4, l16 = lane & 15;
  int row0 = blockIdx.x * 64, col0 = blockIdx.y * 64;
  int m = row0 + wave * 16 + l16;
  bool mok = (m < M);
  int kbn = K >> 5;
  f32x4 acc[4] = {{0,0,0,0},{0,0,0,0},{0,0,0,0},{0,0,0,0}};
  const uint4* A4 = (const uint4*)&Ai[(ll64)m * K];  // row base, 16B units
  uint4 z4 = {0, 0, 0, 0};
  uint4 aw0c = z4, aw1c = z4, aw0n = z4, aw1n = z4;
  short8 bhc[4] = {}, blc[4] = {}, bhn[4] = {}, bln[4] = {};
  if (mok) { aw0c = A4[quad * 2]; aw1c = A4[quad * 2 + 1]; }
#pragma unroll
  for (int nt = 0; nt < 4; nt++) {
    ll64 bi0 = ((ll64)(((col0 >> 4) + nt) * kbn) * 64 + lane) * 8;
    bhc[nt] = *(const short8*)&Bph[bi0];
    blc[nt] = *(const short8*)&Bpl[bi0];
  }
  for (int kb = 0; kb < kbn; kb++) {
    int kn = kb + 1;
    if (kn < kbn) {
      ll64 a4 = (ll64)kn * 8 + quad * 2;
      if (mok) { aw0n = A4[a4]; aw1n = A4[a4 + 1]; }
#pragma unroll
      for (int nt = 0; nt < 4; nt++) {
        ll64 bi = ((ll64)(((col0 >> 4) + nt) * kbn + kn) * 64 + lane) * 8;
        bhn[nt] = *(const short8*)&Bph[bi];
        bln[nt] = *(const short8*)&Bpl[bi];
      }
    }
    short8 ah, al;
    unpack_raw(aw0c, aw1c, ah, al);
#pragma unroll
    for (int nt = 0; nt < 4; nt++) {
      acc[nt] = __builtin_amdgcn_mfma_f32_16x16x32_bf16(ah, bhc[nt], acc[nt], 0, 0, 0);
      acc[nt] = __builtin_amdgcn_mfma_f32_16x16x32_bf16(ah, blc[nt], acc[nt], 0, 0, 0);
      acc[nt] = __builtin_amdgcn_mfma_f32_16x16x32_bf16(al, bhc[nt], acc[nt], 0, 0, 0);
    }
    aw0c = aw0n; aw1c = aw1n;
#pragma unroll
    for (int nt = 0; nt < 4; nt++) { bhc[nt] = bhn[nt]; blc[nt] = bln[nt]; }
  }
#pragma unroll
  for (int nt = 0; nt < 4; nt++) {
    int cc = col0 + nt * 16 + l16;
    float bv = bias[cc];
#pragma unroll
    for (int r = 0; r < 4; r++) {
      int rr = row0 + wave * 16 + quad * 4 + r;
      if (rr < M) Co[(ll64)rr * N + cc] = packsplit(fmaxf(acc[nt][r] + bv, 0.0f));
    }
  }
}

// -------- Fused: h3 = relu(a3@W3+b3) (LDS) ; out = relu(h3@Wi+bi)@Wc + bc --------
// 64 rows/block, 4 waves; wave owns 128 output cols (8 ntiles); reg dbuf.
__global__ __launch_bounds__(256) void k_tail_fused(
    const uint32* __restrict__ a3, const u16* __restrict__ W3h,
    const u16* __restrict__ W3l, const float* __restrict__ b3,
    const u16* __restrict__ Wih, const u16* __restrict__ Wil,
    const float* __restrict__ bi, const float* __restrict__ Wc,
    const float* __restrict__ bc, float* __restrict__ out, int M) {
  __shared__ u16 h3s[64 * 512];     // 64 KB, col-octets xor-swizzled by row&7
  __shared__ float sRed[4][64][3];  // 3 KB
  int tid = threadIdx.x;
  int wave = tid >> 6, lane = tid & 63, quad = lane >> 4, l16 = lane & 15;
  int row0 = blockIdx.x * 64;
  uint4 z4 = {0, 0, 0, 0};

  ll64 ab[4];   // uint4-base of each A-fragment row
  bool mk[4];
#pragma unroll
  for (int f = 0; f < 4; f++) {
    int r = row0 + f * 16 + l16;
    mk[f] = (r < M);
    ab[f] = (ll64)r * 32;  // r*128 elems / 4 per uint4
  }
  const uint4* A4 = (const uint4*)a3;

  // ---- phase 1: layer-3 GEMM (K=128, kbn=4; N=512) into LDS ----
  for (int half = 0; half < 2; half++) {
    f32x4 acc[4][4];
#pragma unroll
    for (int f = 0; f < 4; f++)
#pragma unroll
      for (int nt = 0; nt < 4; nt++) acc[f][nt] = (f32x4){0, 0, 0, 0};
    uint4 awc[8], awn[8];
    short8 bhc[4] = {}, blc[4] = {}, bhn[4] = {}, bln[4] = {};
#pragma unroll
    for (int f = 0; f < 4; f++) {
      awc[2 * f] = mk[f] ? A4[ab[f] + quad * 2] : z4;
      awc[2 * f + 1] = mk[f] ? A4[ab[f] + quad * 2 + 1] : z4;
      awn[2 * f] = z4; awn[2 * f + 1] = z4;
    }
#pragma unroll
    for (int nt = 0; nt < 4; nt++) {
      int ntile = wave * 8 + half * 4 + nt;
      ll64 bi0 = ((ll64)(ntile * 4) * 64 + lane) * 8;
      bhc[nt] = *(const short8*)&W3h[bi0];
      blc[nt] = *(const short8*)&W3l[bi0];
    }
    for (int kb = 0; kb < 4; kb++) {
      int kn = kb + 1;
      if (kn < 4) {
#pragma unroll
        for (int f = 0; f < 4; f++) {
          ll64 a4 = ab[f] + (ll64)kn * 8 + quad * 2;
          awn[2 * f] = mk[f] ? A4[a4] : z4;
          awn[2 * f + 1] = mk[f] ? A4[a4 + 1] : z4;
        }
#pragma unroll
        for (int nt = 0; nt < 4; nt++) {
          int ntile = wave * 8 + half * 4 + nt;
          ll64 bi = ((ll64)(ntile * 4 + kn) * 64 + lane) * 8;
          bhn[nt] = *(const short8*)&W3h[bi];
          bln[nt] = *(const short8*)&W3l[bi];
        }
      }
      short8 ah[4], al[4];
#pragma unroll
      for (int f = 0; f < 4; f++) unpack_raw(awc[2 * f], awc[2 * f + 1], ah[f], al[f]);
#pragma unroll
      for (int nt = 0; nt < 4; nt++)
#pragma unroll
        for (int f = 0; f < 4; f++) {
          acc[f][nt] = __builtin_amdgcn_mfma_f32_16x16x32_bf16(ah[f], bhc[nt], acc[f][nt], 0, 0, 0);
          acc[f][nt] = __builtin_amdgcn_mfma_f32_16x16x32_bf16(ah[f], blc[nt], acc[f][nt], 0, 0, 0);
          acc[f][nt] = __builtin_amdgcn_mfma_f32_16x16x32_bf16(al[f], bhc[nt], acc[f][nt], 0, 0, 0);
        }
#pragma unroll
      for (int f = 0; f < 8; f++) awc[f] = awn[f];
#pragma unroll
      for (int nt = 0; nt < 4; nt++) { bhc[nt] = bhn[nt]; blc[nt] = bln[nt]; }
    }
#pragma unroll
    for (int nt = 0; nt < 4; nt++) {
      int col = (wave * 8 + half * 4 + nt) * 16 + l16;
      float bv = b3[col];
#pragma unroll
      for (int f = 0; f < 4; f++)
#pragma unroll
        for (int r = 0; r < 4; r++) {
          int row = f * 16 + quad * 4 + r;
          float v = fmaxf(acc[f][nt][r] + bv, 0.0f);
          h3s[row * 512 + (((col >> 3) ^ (row & 7)) << 3) + (col & 7)] = f2bf(v);
        }
    }
  }
  __syncthreads();

  // ---- phase 2: h3 @ Wi (K=512, kbn=16) + fold Wc ----
  float acc3[4][4][3] = {};
  for (int half = 0; half < 2; half++) {
    f32x4 acc[4][4];
#pragma unroll
    for (int f = 0; f < 4; f++)
#pragma unroll
      for (int nt = 0; nt < 4; nt++) acc[f][nt] = (f32x4){0, 0, 0, 0};
    short8 bhc[4] = {}, blc[4] = {}, bhn[4] = {}, bln[4] = {};
#pragma unroll
    for (int nt = 0; nt < 4; nt++) {
      int ntile = wave * 8 + half * 4 + nt;
      ll64 bi0 = ((ll64)(ntile * 16) * 64 + lane) * 8;
      bhc[nt] = *(const short8*)&Wih[bi0];
      blc[nt] = *(const short8*)&Wil[bi0];
    }
    for (int kb = 0; kb < 16; kb++) {
      int kn = kb + 1;
      if (kn < 16) {
#pragma unroll
        for (int nt = 0; nt < 4; nt++) {
          int ntile = wave * 8 + half * 4 + nt;
          ll64 bi = ((ll64)(ntile * 16 + kn) * 64 + lane) * 8;
          bhn[nt] = *(const short8*)&Wih[bi];
          bln[nt] = *(const short8*)&Wil[bi];
        }
      }
      short8 a[4];
#pragma unroll
      for (int f = 0; f < 4; f++) {
        int row = f * 16 + l16;
        int b8 = kb * 4 + quad;
        a[f] = *(const short8*)&h3s[row * 512 + ((b8 ^ (row & 7)) << 3)];
      }
#pragma unroll
      for (int nt = 0; nt < 4; nt++)
#pragma unroll
        for (int f = 0; f < 4; f++) {
          acc[f][nt] = __builtin_amdgcn_mfma_f32_16x16x32_bf16(a[f], bhc[nt], acc[f][nt], 0, 0, 0);
          acc[f][nt] = __builtin_amdgcn_mfma_f32_16x16x32_bf16(a[f], blc[nt], acc[f][nt], 0, 0, 0);
        }
#pragma unroll
      for (int nt = 0; nt < 4; nt++) { bhc[nt] = bhn[nt]; blc[nt] = bln[nt]; }
    }
#pragma unroll
    for (int nt = 0; nt < 4; nt++) {
      int col = (wave * 8 + half * 4 + nt) * 16 + l16;
      float bv = bi[col];
      float w0 = Wc[col * 3 + 0], w1 = Wc[col * 3 + 1], w2 = Wc[col * 3 + 2];
#pragma unroll
      for (int f = 0; f < 4; f++)
#pragma unroll
        for (int r = 0; r < 4; r++) {
          float v = fmaxf(acc[f][nt][r] + bv, 0.0f);
          acc3[f][r][0] += v * w0;
          acc3[f][r][1] += v * w1;
          acc3[f][r][2] += v * w2;
        }
    }
  }
#pragma unroll
  for (int f = 0; f < 4; f++)
#pragma unroll
    for (int r = 0; r < 4; r++)
#pragma unroll
      for (int c = 0; c < 3; c++) {
        float v = acc3[f][r][c];
        v += __shfl_xor(v, 1);
        v += __shfl_xor(v, 2);
        v += __shfl_xor(v, 4);
        v += __shfl_xor(v, 8);
        acc3[f][r][c] = v;
      }
  if (l16 == 0) {
#pragma unroll
    for (int f = 0; f < 4; f++)
#pragma unroll
      for (int r = 0; r < 4; r++)
#pragma unroll
        for (int c = 0; c < 3; c++)
          sRed[wave][f * 16 + quad * 4 + r][c] = acc3[f][r][c];
  }
  __syncthreads();
  if (tid < 192) {
    int row = tid / 3, c = tid % 3;
    int gr = row0 + row;
    if (gr < M)
      out[(ll64)gr * 3 + c] = sRed[0][row][c] + sRed[1][row][c] +
                              sRed[2][row][c] + sRed[3][row][c] + bc[c];
  }
}

// ---------------- launcher ----------------
extern "C" void kernel_launch(void* const* d_in, const int* in_sizes, int n_in,
                              void* d_out, int out_size, void* d_ws, size_t ws_size,
                              hipStream_t stream) {
  const float* x  = (const float*)d_in[0];
  const void*  ei = d_in[1];
  const float* W1 = (const float*)d_in[2];
  const float* b1 = (const float*)d_in[3];
  const float* W2 = (const float*)d_in[4];
  const float* b2 = (const float*)d_in[5];
  const float* W3 = (const float*)d_in[6];
  const float* b3 = (const float*)d_in[7];
  const float* Wi = (const float*)d_in[8];
  const float* bi = (const float*)d_in[9];
  const float* Wc = (const float*)d_in[10];
  const float* bc = (const float*)d_in[11];
  float* out = (float*)d_out;

  char* ws = (char*)d_ws;
  const ll64 KB = 1ll << 10, MB = 1ll << 20;
  float* dinv  = (float*)(ws + 0);
  int*   offs  = (int*)(ws + 512 * KB);
  int*   fill  = (int*)(ws + 1 * MB);
  int*   flag  = (int*)(ws + 1536 * KB);
  int*   part  = (int*)(ws + 1600 * KB);
  int*   total = (int*)(ws + 1700 * KB);
  int*   csr   = (int*)(ws + 2 * MB);            // 12.8 MB -> 14.8
  u16* pW1h = (u16*)(ws + 15 * MB);
  u16* pW1l = (u16*)(ws + 15 * MB + 256 * KB);
  u16* pW2h = (u16*)(ws + 15 * MB + 512 * KB);
  u16* pW2l = (u16*)(ws + 15 * MB + 768 * KB);
  u16* pW3h = (u16*)(ws + 16 * MB);
  u16* pW3l = (u16*)(ws + 16 * MB + 256 * KB);
  u16* pWih = (u16*)(ws + 16 * MB + 512 * KB);   // 512 KB
  u16* pWil = (u16*)(ws + 17 * MB);              // 512 KB
  uint32* bufA = (uint32*)(ws + 18 * MB);        // 51.2 MB -> 69.2
  uint32* bufB = (uint32*)(ws + 70 * MB);        // 51.2 MB -> 121.2

  const int TB = 256;
  const int SB = (NN + 255) / 256;       // 391
  const int NEB = (NE + TB - 1) / TB;
  k_init<<<SB, TB, 0, stream>>>((const int*)ei, flag, fill, NN);
  k_count<<<NEB, TB, 0, stream>>>(ei, flag, fill, NE);
  k_scan1<<<SB, TB, 0, stream>>>(fill, offs, part, dinv, NN);
  k_scan2<<<1, 512, 0, stream>>>(part, total, SB);
  k_scan3<<<SB, TB, 0, stream>>>(offs, fill, part, total, NN);
  k_fill<<<NEB, TB, 0, stream>>>(ei, flag, fill, csr, NE);
  k_packAll<<<1408, TB, 0, stream>>>(W1, W2, W3, Wi, pW1h, pW1l, pW2h, pW2l,
                                     pW3h, pW3l, pWih, pWil);

  const int MBk = (NN + 63) / 64;  // 1563
  int aggBlocks = (NN + 3) / 4;
  dim3 g128(MBk, 2);

  // layer 1
  k_agg<<<aggBlocks, TB, 0, stream>>>(x, nullptr, bufA, csr, offs, dinv, NN);
  k_gemm_mfma<<<g128, TB, 0, stream>>>(bufA, pW1h, pW1l, b1, bufB, NN, 128, 128);
  // layer 2
  k_agg<<<aggBlocks, TB, 0, stream>>>(nullptr, bufB, bufA, csr, offs, dinv, NN);
  k_gemm_mfma<<<g128, TB, 0, stream>>>(bufA, pW2h, pW2l, b2, bufB, NN, 128, 128);
  // layer 3 aggregation (128-dim), then fused GEMM512 + MLP head
  k_agg<<<aggBlocks, TB, 0, stream>>>(nullptr, bufB, bufA, csr, offs, dinv, NN);
  k_tail_fused<<<MBk, TB, 0, stream>>>(bufA, pW3h, pW3l, b3, pWih, pWil, bi,
                                       Wc, bc, out, NN);
}

// Round 7
// 1406.923 us; speedup vs baseline: 1.9905x; 1.1524x over previous
//
#include <hip/hip_runtime.h>
#include <hip/hip_fp16.h>

#define NN 100000
#define NE 3200000
// dims: IN=128, HID=128, INT=512, OUT=3
// fp32 tensors on device; edge_index dtype probed (int32/int64); fp32 output.
// Numerics: intermediates single fp16 (each rounding ~1.5e-5 at output, anchored on
// measured bf16-h3 = 1.22e-4); weights fp16 hi/lo split, 2-pass MFMA f16, fp32 acc.
// Round 7: un-fused tail (gemm512 -> h3 in L3 -> LDS-free head), VGPR-lean kernels.

typedef unsigned int uint32;
typedef unsigned short u16;
typedef long long ll64;
typedef __attribute__((ext_vector_type(8))) _Float16 half8;
typedef __attribute__((ext_vector_type(4))) float f32x4;

__device__ inline float2 h2f2(uint32 u) {
  __half2 h = *reinterpret_cast<__half2*>(&u);
  return __half22float2(h);
}
__device__ inline uint32 f2h2(float x, float y) {
  return (uint32)__half_as_ushort(__float2half(x)) |
         ((uint32)__half_as_ushort(__float2half(y)) << 16);
}

__device__ inline int edge_at(const void* ei, int is64, ll64 idx) {
  return is64 ? (int)((const ll64*)ei)[idx] : ((const int*)ei)[idx];
}

// ---------------- init: zero degree counters + edge dtype probe ----------------
__global__ void k_init(const int* __restrict__ ei, int* __restrict__ flag,
                       int* __restrict__ fill, int n) {
  int i = blockIdx.x * blockDim.x + threadIdx.x;
  if (i < n) fill[i] = 0;
  if (i == 0) {
    int acc = 0;
#pragma unroll
    for (int k = 1; k < 32; k += 2) acc |= ei[k];
    *flag = (acc == 0) ? 1 : 0;  // 1 => int64
  }
}
__global__ void k_count(const void* __restrict__ ei, const int* __restrict__ flag,
                        int* __restrict__ cnt, int e) {
  int i = blockIdx.x * blockDim.x + threadIdx.x;
  if (i < e) atomicAdd(&cnt[edge_at(ei, *flag, (ll64)NE + i)], 1);
}
__global__ void k_scan1(const int* __restrict__ cnt, int* __restrict__ offs,
                        int* __restrict__ part, float* __restrict__ dinv, int n) {
  __shared__ int sd[256];
  int tid = threadIdx.x, idx = blockIdx.x * 256 + tid;
  int v = (idx < n) ? cnt[idx] : 0;
  sd[tid] = v;
  __syncthreads();
  for (int off = 1; off < 256; off <<= 1) {
    int t = (tid >= off) ? sd[tid - off] : 0;
    __syncthreads();
    sd[tid] += t;
    __syncthreads();
  }
  if (idx < n) {
    offs[idx] = sd[tid] - v;
    dinv[idx] = rsqrtf((float)(v + 1));  // +1: self-loop
  }
  if (tid == 255) part[blockIdx.x] = sd[255];
}
__global__ void k_scan2(int* __restrict__ part, int* __restrict__ total, int nb) {
  __shared__ int sd[512];
  int tid = threadIdx.x;
  int v = (tid < nb) ? part[tid] : 0;
  sd[tid] = v;
  __syncthreads();
  for (int off = 1; off < 512; off <<= 1) {
    int t = (tid >= off) ? sd[tid - off] : 0;
    __syncthreads();
    sd[tid] += t;
    __syncthreads();
  }
  if (tid < nb) part[tid] = sd[tid] - v;
  if (tid == 511) *total = sd[511];
}
__global__ void k_scan3(int* __restrict__ offs, int* __restrict__ fill,
                        const int* __restrict__ part, const int* __restrict__ total, int n) {
  int i = blockIdx.x * 256 + threadIdx.x;
  if (i < n) {
    int o = offs[i] + part[blockIdx.x];
    offs[i] = o;
    fill[i] = o;
  }
  if (i == 0) offs[n] = *total;
}
__global__ void k_fill(const void* __restrict__ ei, const int* __restrict__ flag,
                       int* fill, int* __restrict__ csr, int e) {
  int i = blockIdx.x * blockDim.x + threadIdx.x;
  if (i < e) {
    int is64 = *flag;
    int s = edge_at(ei, is64, i);
    int d = edge_at(ei, is64, (ll64)NE + i);
    int pos = atomicAdd(&fill[d], 1);
    csr[pos] = s;
  }
}

// -------- weight pack: fp32 W[KxN] -> MFMA B-fragment order, fp16 hi/lo planes ------
// t = ((ntile*(K/32)+kb)*64 + lane)*8 + j  holds  W[kb*32+(lane>>4)*8+j][ntile*16+(lane&15)]
__device__ inline void packOne(const float* __restrict__ W, u16* __restrict__ ph,
                               u16* __restrict__ pl, int K, int N, int t) {
  int j = t & 7, lane = (t >> 3) & 63, tl = t >> 9;
  int kbn = K >> 5;
  int kb = tl % kbn, ntile = tl / kbn;
  int k = kb * 32 + (lane >> 4) * 8 + j;
  int n2 = ntile * 16 + (lane & 15);
  float v = W[k * N + n2];
  __half h = __float2half(v);
  ph[t] = __half_as_ushort(h);
  pl[t] = __half_as_ushort(__float2half(v - __half2float(h)));
}
__global__ void k_packAll(const float* W1, const float* W2, const float* W3,
                          const float* Wi, u16* p1h, u16* p1l, u16* p2h, u16* p2l,
                          u16* p3h, u16* p3l, u16* pih, u16* pil) {
  int t = blockIdx.x * blockDim.x + threadIdx.x;
  if (t < 16384) packOne(W1, p1h, p1l, 128, 128, t);
  else if (t < 32768) packOne(W2, p2h, p2l, 128, 128, t - 16384);
  else if (t < 98304) packOne(W3, p3h, p3l, 128, 512, t - 32768);
  else if (t < 360448) packOne(Wi, pih, pil, 512, 512, t - 98304);
}

// ---------------- x -> fp16 table (for agg1 gathers) ----------------
__global__ void k_half(const float4* __restrict__ x, ushort4* __restrict__ xh, int n4) {
  int i = blockIdx.x * blockDim.x + threadIdx.x;
  if (i < n4) {
    float4 v = x[i];
    ushort4 o;
    o.x = __half_as_ushort(__float2half(v.x));
    o.y = __half_as_ushort(__float2half(v.y));
    o.z = __half_as_ushort(__float2half(v.z));
    o.w = __half_as_ushort(__float2half(v.w));
    xh[i] = o;
  }
}

// ---------------- Aggregation (pull, one wave per node, unroll-4, fp16 IO) -------
// out[i] = dinv[i]*( sum dinv[s]*x[s] + dinv[i]*x[i] ); lane covers feats {2l,2l+1}
// (one uint32 = 2 fp16 per lane; row = 256 B contiguous).
__global__ void k_agg(const uint32* __restrict__ xi, uint32* __restrict__ o,
                      const int* __restrict__ csr, const int* __restrict__ offs,
                      const float* __restrict__ dinv, int n) {
  int node = blockIdx.x * 4 + (threadIdx.x >> 6);
  int lane = threadIdx.x & 63;
  if (node >= n) return;
  int beg = offs[node], end = offs[node + 1];
  float ax = 0.f, ay = 0.f;
  int j = beg;
  for (; j + 3 < end; j += 4) {
    int s0 = csr[j], s1 = csr[j + 1], s2 = csr[j + 2], s3 = csr[j + 3];
    float d0 = dinv[s0], d1 = dinv[s1], d2 = dinv[s2], d3 = dinv[s3];
    float2 r0 = h2f2(xi[(ll64)s0 * 64 + lane]);
    float2 r1 = h2f2(xi[(ll64)s1 * 64 + lane]);
    float2 r2 = h2f2(xi[(ll64)s2 * 64 + lane]);
    float2 r3 = h2f2(xi[(ll64)s3 * 64 + lane]);
    ax += d0 * r0.x + d1 * r1.x + d2 * r2.x + d3 * r3.x;
    ay += d0 * r0.y + d1 * r1.y + d2 * r2.y + d3 * r3.y;
  }
  for (; j < end; j++) {
    int s = csr[j];
    float d = dinv[s];
    float2 r = h2f2(xi[(ll64)s * 64 + lane]);
    ax += d * r.x;
    ay += d * r.y;
  }
  float di = dinv[node];
  float2 sf = h2f2(xi[(ll64)node * 64 + lane]);
  float vx = di * (ax + di * sf.x);
  float vy = di * (ay + di * sf.y);
  o[(ll64)node * 64 + lane] = f2h2(vx, vy);
}

// -------- MFMA GEMM: C = relu(A @ W + bias); A,C fp16; 2-pass B; reg dbuf --------
// Block 64 rows x 64 cols, 4 waves; wave w = rows [row0+16w, +16).
__global__ __launch_bounds__(256, 3) void k_gemm_mfma(
    const u16* __restrict__ A, const u16* __restrict__ Bph,
    const u16* __restrict__ Bpl, const float* __restrict__ bias,
    u16* __restrict__ Co, int M, int N, int K) {
  int wave = threadIdx.x >> 6, lane = threadIdx.x & 63;
  int quad = lane >> 4, l16 = lane & 15;
  int row0 = blockIdx.x * 64, col0 = blockIdx.y * 64;
  int m = row0 + wave * 16 + l16;
  int mc = (m < M) ? m : (M - 1);  // clamp: garbage rows land in unstored C rows
  int kbn = K >> 5;
  f32x4 acc[4] = {{0,0,0,0},{0,0,0,0},{0,0,0,0},{0,0,0,0}};
  const half8* Ar = (const half8*)&A[(ll64)mc * K];  // 16B units: idx = kb*4 + quad
  half8 ac = Ar[quad];
  half8 an = ac;
  half8 bhc[4], blc[4], bhn[4], bln[4];
#pragma unroll
  for (int nt = 0; nt < 4; nt++) {
    ll64 bi0 = ((ll64)(((col0 >> 4) + nt) * kbn) * 64 + lane) * 8;
    bhc[nt] = *(const half8*)&Bph[bi0];
    blc[nt] = *(const half8*)&Bpl[bi0];
  }
  for (int kb = 0; kb < kbn; kb++) {
    int kn = kb + 1;
    if (kn < kbn) {
      an = Ar[kn * 4 + quad];
#pragma unroll
      for (int nt = 0; nt < 4; nt++) {
        ll64 bidx = ((ll64)(((col0 >> 4) + nt) * kbn + kn) * 64 + lane) * 8;
        bhn[nt] = *(const half8*)&Bph[bidx];
        bln[nt] = *(const half8*)&Bpl[bidx];
      }
    }
#pragma unroll
    for (int nt = 0; nt < 4; nt++) {
      acc[nt] = __builtin_amdgcn_mfma_f32_16x16x32_f16(ac, bhc[nt], acc[nt], 0, 0, 0);
      acc[nt] = __builtin_amdgcn_mfma_f32_16x16x32_f16(ac, blc[nt], acc[nt], 0, 0, 0);
    }
    ac = an;
#pragma unroll
    for (int nt = 0; nt < 4; nt++) { bhc[nt] = bhn[nt]; blc[nt] = bln[nt]; }
  }
#pragma unroll
  for (int nt = 0; nt < 4; nt++) {
    int cc = col0 + nt * 16 + l16;
    float bv = bias[cc];
#pragma unroll
    for (int r = 0; r < 4; r++) {
      int rr = row0 + wave * 16 + quad * 4 + r;
      if (rr < M)
        Co[(ll64)rr * N + cc] =
            __half_as_ushort(__float2half(fmaxf(acc[nt][r] + bv, 0.0f)));
    }
  }
}

// -------- Head: out = relu(h3 @ Wi + bi) @ Wc + bc; LDS-free (A from L3) --------
// Block 64 rows, 4 waves; wave owns 128 cols via 2 halves of 4 ntiles.
__global__ __launch_bounds__(256, 3) void k_head(
    const u16* __restrict__ h3, const u16* __restrict__ Wih,
    const u16* __restrict__ Wil, const float* __restrict__ bi,
    const float* __restrict__ Wc, const float* __restrict__ bc,
    float* __restrict__ out, int M) {
  __shared__ float sRed[4][64][3];  // 3 KB
  int tid = threadIdx.x;
  int wave = tid >> 6, lane = tid & 63, quad = lane >> 4, l16 = lane & 15;
  int row0 = blockIdx.x * 64;
  ll64 abase[4];
#pragma unroll
  for (int f = 0; f < 4; f++) {
    int r = row0 + f * 16 + l16;
    abase[f] = (ll64)((r < M) ? r : (M - 1)) * 512;  // clamp; unstored rows absorb garbage
  }
  for (int half = 0; half < 2; half++) {
    f32x4 acc[4][4];
#pragma unroll
    for (int f = 0; f < 4; f++)
#pragma unroll
      for (int nt = 0; nt < 4; nt++) acc[f][nt] = (f32x4){0, 0, 0, 0};
    for (int kb = 0; kb < 16; kb++) {
      half8 a[4];
#pragma unroll
      for (int f = 0; f < 4; f++)
        a[f] = *(const half8*)&h3[abase[f] + kb * 32 + quad * 8];
#pragma unroll
      for (int nt = 0; nt < 4; nt++) {
        int ntile = wave * 8 + half * 4 + nt;
        ll64 bidx = ((ll64)(ntile * 16 + kb) * 64 + lane) * 8;
        half8 bh = *(const half8*)&Wih[bidx];
        half8 bl = *(const half8*)&Wil[bidx];
#pragma unroll
        for (int f = 0; f < 4; f++) {
          acc[f][nt] = __builtin_amdgcn_mfma_f32_16x16x32_f16(a[f], bh, acc[f][nt], 0, 0, 0);
          acc[f][nt] = __builtin_amdgcn_mfma_f32_16x16x32_f16(a[f], bl, acc[f][nt], 0, 0, 0);
        }
      }
    }
    // fold Wc for this half, reduce over l16, accumulate into sRed
    float acc3[4][4][3] = {};
#pragma unroll
    for (int nt = 0; nt < 4; nt++) {
      int col = (wave * 8 + half * 4 + nt) * 16 + l16;
      float bv = bi[col];
      float w0 = Wc[col * 3 + 0], w1 = Wc[col * 3 + 1], w2 = Wc[col * 3 + 2];
#pragma unroll
      for (int f = 0; f < 4; f++)
#pragma unroll
        for (int r = 0; r < 4; r++) {
          float v = fmaxf(acc[f][nt][r] + bv, 0.0f);
          acc3[f][r][0] += v * w0;
          acc3[f][r][1] += v * w1;
          acc3[f][r][2] += v * w2;
        }
    }
#pragma unroll
    for (int f = 0; f < 4; f++)
#pragma unroll
      for (int r = 0; r < 4; r++)
#pragma unroll
        for (int c = 0; c < 3; c++) {
          float v = acc3[f][r][c];
          v += __shfl_xor(v, 1);
          v += __shfl_xor(v, 2);
          v += __shfl_xor(v, 4);
          v += __shfl_xor(v, 8);
          acc3[f][r][c] = v;
        }
    if (l16 == 0) {
#pragma unroll
      for (int f = 0; f < 4; f++)
#pragma unroll
        for (int r = 0; r < 4; r++) {
          int row = f * 16 + quad * 4 + r;
#pragma unroll
          for (int c = 0; c < 3; c++) {
            if (half == 0) sRed[wave][row][c] = acc3[f][r][c];
            else           sRed[wave][row][c] += acc3[f][r][c];
          }
        }
    }
  }
  __syncthreads();
  if (tid < 192) {
    int row = tid / 3, c = tid % 3;
    int gr = row0 + row;
    if (gr < M)
      out[(ll64)gr * 3 + c] = sRed[0][row][c] + sRed[1][row][c] +
                              sRed[2][row][c] + sRed[3][row][c] + bc[c];
  }
}

// ---------------- launcher ----------------
extern "C" void kernel_launch(void* const* d_in, const int* in_sizes, int n_in,
                              void* d_out, int out_size, void* d_ws, size_t ws_size,
                              hipStream_t stream) {
  const float* x  = (const float*)d_in[0];
  const void*  ei = d_in[1];
  const float* W1 = (const float*)d_in[2];
  const float* b1 = (const float*)d_in[3];
  const float* W2 = (const float*)d_in[4];
  const float* b2 = (const float*)d_in[5];
  const float* W3 = (const float*)d_in[6];
  const float* b3 = (const float*)d_in[7];
  const float* Wi = (const float*)d_in[8];
  const float* bi = (const float*)d_in[9];
  const float* Wc = (const float*)d_in[10];
  const float* bc = (const float*)d_in[11];
  float* out = (float*)d_out;

  char* ws = (char*)d_ws;
  const ll64 KB = 1ll << 10, MB = 1ll << 20;
  float* dinv  = (float*)(ws + 0);
  int*   offs  = (int*)(ws + 512 * KB);
  int*   fill  = (int*)(ws + 1 * MB);
  int*   flag  = (int*)(ws + 1536 * KB);
  int*   part  = (int*)(ws + 1600 * KB);
  int*   total = (int*)(ws + 1700 * KB);
  int*   csr   = (int*)(ws + 2 * MB);              // 12.8 MB -> 14.8
  u16* pW1h = (u16*)(ws + 15 * MB);                // 32 KB each
  u16* pW1l = (u16*)(ws + 15 * MB + 64 * KB);
  u16* pW2h = (u16*)(ws + 15 * MB + 128 * KB);
  u16* pW2l = (u16*)(ws + 15 * MB + 192 * KB);
  u16* pW3h = (u16*)(ws + 15 * MB + 256 * KB);     // 128 KB each
  u16* pW3l = (u16*)(ws + 15 * MB + 384 * KB);
  u16* pWih = (u16*)(ws + 15 * MB + 512 * KB);     // 512 KB each
  u16* pWil = (u16*)(ws + 16 * MB);
  u16* xh   = (u16*)(ws + 17 * MB);                // 25.6 MB -> 42.6
  u16* bufA = (u16*)(ws + 43 * MB);                // 25.6 MB -> 68.6
  u16* bufB = (u16*)(ws + 69 * MB);                // 25.6 MB -> 94.6
  u16* h3   = (u16*)(ws + 69 * MB);                // 102.4 MB -> 171.4 (over bufB; h2 dead)

  const int TB = 256;
  const int SB = (NN + 255) / 256;       // 391
  const int NEB = (NE + TB - 1) / TB;
  k_init<<<SB, TB, 0, stream>>>((const int*)ei, flag, fill, NN);
  k_count<<<NEB, TB, 0, stream>>>(ei, flag, fill, NE);
  k_scan1<<<SB, TB, 0, stream>>>(fill, offs, part, dinv, NN);
  k_scan2<<<1, 512, 0, stream>>>(part, total, SB);
  k_scan3<<<SB, TB, 0, stream>>>(offs, fill, part, total, NN);
  k_fill<<<NEB, TB, 0, stream>>>(ei, flag, fill, csr, NE);
  k_packAll<<<1408, TB, 0, stream>>>(W1, W2, W3, Wi, pW1h, pW1l, pW2h, pW2l,
                                     pW3h, pW3l, pWih, pWil);
  k_half<<<(NN * 32 + TB - 1) / TB, TB, 0, stream>>>((const float4*)x,
                                                     (ushort4*)xh, NN * 32);

  const int MBk = (NN + 63) / 64;  // 1563
  int aggBlocks = (NN + 3) / 4;
  dim3 g128(MBk, 2), g512(MBk, 8);

  // layer 1
  k_agg<<<aggBlocks, TB, 0, stream>>>((const uint32*)xh, (uint32*)bufA, csr, offs, dinv, NN);
  k_gemm_mfma<<<g128, TB, 0, stream>>>(bufA, pW1h, pW1l, b1, bufB, NN, 128, 128);
  // layer 2
  k_agg<<<aggBlocks, TB, 0, stream>>>((const uint32*)bufB, (uint32*)bufA, csr, offs, dinv, NN);
  k_gemm_mfma<<<g128, TB, 0, stream>>>(bufA, pW2h, pW2l, b2, bufB, NN, 128, 128);
  // layer 3: aggregate (128-dim), GEMM 128->512 (h3 fp16, L3-resident)
  k_agg<<<aggBlocks, TB, 0, stream>>>((const uint32*)bufB, (uint32*)bufA, csr, offs, dinv, NN);
  k_gemm_mfma<<<g512, TB, 0, stream>>>(bufA, pW3h, pW3l, b3, h3, NN, 512, 128);
  // MLP head
  k_head<<<MBk, TB, 0, stream>>>(h3, pWih, pWil, bi, Wc, bc, out, NN);
}

// Round 8
// 1054.137 us; speedup vs baseline: 2.6566x; 1.3347x over previous
//
#include <hip/hip_runtime.h>
#include <hip/hip_fp16.h>

#define NN 100000
#define NE 3200000
// dims: IN=128, HID=128, INT=512, OUT=3
// fp32 tensors on device; edge_index dtype probed (int32/int64); fp32 output.
// Numerics: fp16 intermediates + SINGLE-pass fp16 weights (measured comparison floor
// 1.2207e-4 = 2^-13 dominates; weight rounding adds <~5e-5). MFMA f16 fp32-acc.
// Round 8: fused 32-row tail (32KB LDS, 4 blk/CU, no h3 buffer), 2 MFMA per B-load.

typedef unsigned int uint32;
typedef unsigned short u16;
typedef long long ll64;
typedef __attribute__((ext_vector_type(8))) _Float16 half8;
typedef __attribute__((ext_vector_type(4))) float f32x4;

__device__ inline float2 h2f2(uint32 u) {
  __half2 h = *reinterpret_cast<__half2*>(&u);
  return __half22float2(h);
}
__device__ inline uint32 f2h2(float x, float y) {
  return (uint32)__half_as_ushort(__float2half(x)) |
         ((uint32)__half_as_ushort(__float2half(y)) << 16);
}

__device__ inline int edge_at(const void* ei, int is64, ll64 idx) {
  return is64 ? (int)((const ll64*)ei)[idx] : ((const int*)ei)[idx];
}

// ---------------- init: zero degree counters + edge dtype probe ----------------
__global__ void k_init(const int* __restrict__ ei, int* __restrict__ flag,
                       int* __restrict__ fill, int n) {
  int i = blockIdx.x * blockDim.x + threadIdx.x;
  if (i < n) fill[i] = 0;
  if (i == 0) {
    int acc = 0;
#pragma unroll
    for (int k = 1; k < 32; k += 2) acc |= ei[k];
    *flag = (acc == 0) ? 1 : 0;  // 1 => int64
  }
}
__global__ void k_count(const void* __restrict__ ei, const int* __restrict__ flag,
                        int* __restrict__ cnt, int e) {
  int i = blockIdx.x * blockDim.x + threadIdx.x;
  if (i < e) atomicAdd(&cnt[edge_at(ei, *flag, (ll64)NE + i)], 1);
}
__global__ void k_scan1(const int* __restrict__ cnt, int* __restrict__ offs,
                        int* __restrict__ part, float* __restrict__ dinv, int n) {
  __shared__ int sd[256];
  int tid = threadIdx.x, idx = blockIdx.x * 256 + tid;
  int v = (idx < n) ? cnt[idx] : 0;
  sd[tid] = v;
  __syncthreads();
  for (int off = 1; off < 256; off <<= 1) {
    int t = (tid >= off) ? sd[tid - off] : 0;
    __syncthreads();
    sd[tid] += t;
    __syncthreads();
  }
  if (idx < n) {
    offs[idx] = sd[tid] - v;
    dinv[idx] = rsqrtf((float)(v + 1));  // +1: self-loop
  }
  if (tid == 255) part[blockIdx.x] = sd[255];
}
__global__ void k_scan2(int* __restrict__ part, int* __restrict__ total, int nb) {
  __shared__ int sd[512];
  int tid = threadIdx.x;
  int v = (tid < nb) ? part[tid] : 0;
  sd[tid] = v;
  __syncthreads();
  for (int off = 1; off < 512; off <<= 1) {
    int t = (tid >= off) ? sd[tid - off] : 0;
    __syncthreads();
    sd[tid] += t;
    __syncthreads();
  }
  if (tid < nb) part[tid] = sd[tid] - v;
  if (tid == 511) *total = sd[511];
}
__global__ void k_scan3(int* __restrict__ offs, int* __restrict__ fill,
                        const int* __restrict__ part, const int* __restrict__ total, int n) {
  int i = blockIdx.x * 256 + threadIdx.x;
  if (i < n) {
    int o = offs[i] + part[blockIdx.x];
    offs[i] = o;
    fill[i] = o;
  }
  if (i == 0) offs[n] = *total;
}
__global__ void k_fill(const void* __restrict__ ei, const int* __restrict__ flag,
                       int* fill, int* __restrict__ csr, int e) {
  int i = blockIdx.x * blockDim.x + threadIdx.x;
  if (i < e) {
    int is64 = *flag;
    int s = edge_at(ei, is64, i);
    int d = edge_at(ei, is64, (ll64)NE + i);
    int pos = atomicAdd(&fill[d], 1);
    csr[pos] = s;
  }
}

// ---- weight pack: fp32 W[KxN] -> MFMA B-fragment order, single fp16 plane ----
// t = ((ntile*(K/32)+kb)*64 + lane)*8 + j  holds  W[kb*32+(lane>>4)*8+j][ntile*16+(lane&15)]
__device__ inline void packOne(const float* __restrict__ W, u16* __restrict__ ph,
                               int K, int N, int t) {
  int j = t & 7, lane = (t >> 3) & 63, tl = t >> 9;
  int kbn = K >> 5;
  int kb = tl % kbn, ntile = tl / kbn;
  int k = kb * 32 + (lane >> 4) * 8 + j;
  int n2 = ntile * 16 + (lane & 15);
  ph[t] = __half_as_ushort(__float2half(W[k * N + n2]));
}
__global__ void k_packAll(const float* W1, const float* W2, const float* W3,
                          const float* Wi, u16* p1, u16* p2, u16* p3, u16* pi) {
  int t = blockIdx.x * blockDim.x + threadIdx.x;
  if (t < 16384) packOne(W1, p1, 128, 128, t);
  else if (t < 32768) packOne(W2, p2, 128, 128, t - 16384);
  else if (t < 98304) packOne(W3, p3, 128, 512, t - 32768);
  else if (t < 360448) packOne(Wi, pi, 512, 512, t - 98304);
}

// ---------------- x -> fp16 table (for agg1 gathers) ----------------
__global__ void k_half(const float4* __restrict__ x, ushort4* __restrict__ xh, int n4) {
  int i = blockIdx.x * blockDim.x + threadIdx.x;
  if (i < n4) {
    float4 v = x[i];
    ushort4 o;
    o.x = __half_as_ushort(__float2half(v.x));
    o.y = __half_as_ushort(__float2half(v.y));
    o.z = __half_as_ushort(__float2half(v.z));
    o.w = __half_as_ushort(__float2half(v.w));
    xh[i] = o;
  }
}

// ---------------- Aggregation (pull, one wave per node, unroll-4, fp16 IO) -------
__global__ void k_agg(const uint32* __restrict__ xi, uint32* __restrict__ o,
                      const int* __restrict__ csr, const int* __restrict__ offs,
                      const float* __restrict__ dinv, int n) {
  int node = blockIdx.x * 4 + (threadIdx.x >> 6);
  int lane = threadIdx.x & 63;
  if (node >= n) return;
  int beg = offs[node], end = offs[node + 1];
  float ax = 0.f, ay = 0.f;
  int j = beg;
  for (; j + 3 < end; j += 4) {
    int s0 = csr[j], s1 = csr[j + 1], s2 = csr[j + 2], s3 = csr[j + 3];
    float d0 = dinv[s0], d1 = dinv[s1], d2 = dinv[s2], d3 = dinv[s3];
    float2 r0 = h2f2(xi[(ll64)s0 * 64 + lane]);
    float2 r1 = h2f2(xi[(ll64)s1 * 64 + lane]);
    float2 r2 = h2f2(xi[(ll64)s2 * 64 + lane]);
    float2 r3 = h2f2(xi[(ll64)s3 * 64 + lane]);
    ax += d0 * r0.x + d1 * r1.x + d2 * r2.x + d3 * r3.x;
    ay += d0 * r0.y + d1 * r1.y + d2 * r2.y + d3 * r3.y;
  }
  for (; j < end; j++) {
    int s = csr[j];
    float d = dinv[s];
    float2 r = h2f2(xi[(ll64)s * 64 + lane]);
    ax += d * r.x;
    ay += d * r.y;
  }
  float di = dinv[node];
  float2 sf = h2f2(xi[(ll64)node * 64 + lane]);
  float vx = di * (ax + di * sf.x);
  float vy = di * (ay + di * sf.y);
  o[(ll64)node * 64 + lane] = f2h2(vx, vy);
}

// -------- MFMA GEMM: C = relu(A @ W + bias); A,C fp16; single-pass B; reg dbuf ------
__global__ __launch_bounds__(256, 4) void k_gemm_mfma(
    const u16* __restrict__ A, const u16* __restrict__ Bp,
    const float* __restrict__ bias, u16* __restrict__ Co, int M, int N, int K) {
  int wave = threadIdx.x >> 6, lane = threadIdx.x & 63;
  int quad = lane >> 4, l16 = lane & 15;
  int row0 = blockIdx.x * 64, col0 = blockIdx.y * 64;
  int m = row0 + wave * 16 + l16;
  int mc = (m < M) ? m : (M - 1);  // clamp: garbage rows land in unstored C rows
  int kbn = K >> 5;
  f32x4 acc[4] = {{0,0,0,0},{0,0,0,0},{0,0,0,0},{0,0,0,0}};
  const half8* Ar = (const half8*)&A[(ll64)mc * K];
  half8 ac = Ar[quad];
  half8 an = ac;
  half8 bc_[4], bn_[4];
#pragma unroll
  for (int nt = 0; nt < 4; nt++)
    bc_[nt] = *(const half8*)&Bp[((ll64)(((col0 >> 4) + nt) * kbn) * 64 + lane) * 8];
  for (int kb = 0; kb < kbn; kb++) {
    int kn = kb + 1;
    if (kn < kbn) {
      an = Ar[kn * 4 + quad];
#pragma unroll
      for (int nt = 0; nt < 4; nt++)
        bn_[nt] = *(const half8*)&Bp[((ll64)(((col0 >> 4) + nt) * kbn + kn) * 64 + lane) * 8];
    }
#pragma unroll
    for (int nt = 0; nt < 4; nt++)
      acc[nt] = __builtin_amdgcn_mfma_f32_16x16x32_f16(ac, bc_[nt], acc[nt], 0, 0, 0);
    ac = an;
#pragma unroll
    for (int nt = 0; nt < 4; nt++) bc_[nt] = bn_[nt];
  }
#pragma unroll
  for (int nt = 0; nt < 4; nt++) {
    int cc = col0 + nt * 16 + l16;
    float bv = bias[cc];
#pragma unroll
    for (int r = 0; r < 4; r++) {
      int rr = row0 + wave * 16 + quad * 4 + r;
      if (rr < M)
        Co[(ll64)rr * N + cc] =
            __half_as_ushort(__float2half(fmaxf(acc[nt][r] + bv, 0.0f)));
    }
  }
}

// ---- Fused tail: h3tile = relu(a3@W3+b3) in LDS; out = relu(h3@Wi+bi)@Wc + bc ----
// 32 rows/block (32 KB LDS -> 4 blk/CU). Wave w owns 8 ntiles x BOTH row-tiles
// (2 MFMA per B-load, zero intra-block B redundancy). One-deep B prefetch.
__global__ __launch_bounds__(256, 4) void k_tail32(
    const u16* __restrict__ a3, const u16* __restrict__ W3p,
    const float* __restrict__ b3, const u16* __restrict__ Wip,
    const float* __restrict__ bi, const float* __restrict__ Wc,
    const float* __restrict__ bc, float* __restrict__ out, int M) {
  __shared__ u16 h3s[32 * 512];     // 32 KB, col-octets xor-swizzled by row&7
  __shared__ float sRed[4][32][3];  // 1.5 KB
  int tid = threadIdx.x;
  int wave = tid >> 6, lane = tid & 63, quad = lane >> 4, l16 = lane & 15;
  int row0 = blockIdx.x * 32;  // NN % 32 == 0: no OOB rows

  // ---- phase 1: 32x512 = a3[32x128] @ W3 into LDS ----
  half8 af[2][4];
#pragma unroll
  for (int rt = 0; rt < 2; rt++) {
    const half8* Ar = (const half8*)&a3[(ll64)(row0 + rt * 16 + l16) * 128];
#pragma unroll
    for (int kb = 0; kb < 4; kb++) af[rt][kb] = Ar[kb * 4 + quad];
  }
  {
    f32x4 acc0 = {0, 0, 0, 0}, acc1 = {0, 0, 0, 0};
    half8 bcur = *(const half8*)&W3p[((ll64)(wave * 32) * 64 + lane) * 8];
    half8 bnxt = bcur;
    for (int t = 0; t < 32; t++) {
      if (t + 1 < 32)
        bnxt = *(const half8*)&W3p[((ll64)(wave * 32 + t + 1) * 64 + lane) * 8];
      int kb = t & 3;
      acc0 = __builtin_amdgcn_mfma_f32_16x16x32_f16(af[0][kb], bcur, acc0, 0, 0, 0);
      acc1 = __builtin_amdgcn_mfma_f32_16x16x32_f16(af[1][kb], bcur, acc1, 0, 0, 0);
      if (kb == 3) {
        int nt = wave * 8 + (t >> 2);
        int col = nt * 16 + l16;
        float bv = b3[col];
#pragma unroll
        for (int r = 0; r < 4; r++) {
          int row0l = quad * 4 + r;
          float v0 = fmaxf(acc0[r] + bv, 0.0f);
          float v1 = fmaxf(acc1[r] + bv, 0.0f);
          int oct0 = (col >> 3) ^ (row0l & 7);
          h3s[row0l * 512 + oct0 * 8 + (col & 7)] = __half_as_ushort(__float2half(v0));
          int row1l = 16 + row0l;
          int oct1 = (col >> 3) ^ (row1l & 7);
          h3s[row1l * 512 + oct1 * 8 + (col & 7)] = __half_as_ushort(__float2half(v1));
        }
        acc0 = (f32x4){0, 0, 0, 0};
        acc1 = (f32x4){0, 0, 0, 0};
      }
      bcur = bnxt;
    }
  }
  __syncthreads();

  // ---- phase 2: h3s @ Wi (K=512) + fold Wc ----
  float acc3[2][4][3] = {};
  {
    f32x4 acc0 = {0, 0, 0, 0}, acc1 = {0, 0, 0, 0};
    half8 bcur = *(const half8*)&Wip[((ll64)(wave * 128) * 64 + lane) * 8];
    half8 bnxt = bcur;
    int r0l = l16, r1l = 16 + l16;
    int sw0 = r0l & 7;  // same as r1l & 7
    for (int t = 0; t < 128; t++) {
      if (t + 1 < 128)
        bnxt = *(const half8*)&Wip[((ll64)(wave * 128 + t + 1) * 64 + lane) * 8];
      int kb = t & 15;
      int oct = ((kb * 4 + quad) ^ sw0);
      half8 a0 = *(const half8*)&h3s[r0l * 512 + oct * 8];
      half8 a1 = *(const half8*)&h3s[r1l * 512 + oct * 8];
      acc0 = __builtin_amdgcn_mfma_f32_16x16x32_f16(a0, bcur, acc0, 0, 0, 0);
      acc1 = __builtin_amdgcn_mfma_f32_16x16x32_f16(a1, bcur, acc1, 0, 0, 0);
      if (kb == 15) {
        int nt = wave * 8 + (t >> 4);
        int col = nt * 16 + l16;
        float bv = bi[col];
        float w0 = Wc[col * 3 + 0], w1 = Wc[col * 3 + 1], w2 = Wc[col * 3 + 2];
#pragma unroll
        for (int r = 0; r < 4; r++) {
          float v0 = fmaxf(acc0[r] + bv, 0.0f);
          float v1 = fmaxf(acc1[r] + bv, 0.0f);
          acc3[0][r][0] += v0 * w0; acc3[0][r][1] += v0 * w1; acc3[0][r][2] += v0 * w2;
          acc3[1][r][0] += v1 * w0; acc3[1][r][1] += v1 * w1; acc3[1][r][2] += v1 * w2;
        }
        acc0 = (f32x4){0, 0, 0, 0};
        acc1 = (f32x4){0, 0, 0, 0};
      }
      bcur = bnxt;
    }
  }
  // reduce over the 16 l16 lanes, stash per-wave partials
#pragma unroll
  for (int rt = 0; rt < 2; rt++)
#pragma unroll
    for (int r = 0; r < 4; r++)
#pragma unroll
      for (int c = 0; c < 3; c++) {
        float v = acc3[rt][r][c];
        v += __shfl_xor(v, 1);
        v += __shfl_xor(v, 2);
        v += __shfl_xor(v, 4);
        v += __shfl_xor(v, 8);
        acc3[rt][r][c] = v;
      }
  if (l16 == 0) {
#pragma unroll
    for (int rt = 0; rt < 2; rt++)
#pragma unroll
      for (int r = 0; r < 4; r++)
#pragma unroll
        for (int c = 0; c < 3; c++)
          sRed[wave][rt * 16 + quad * 4 + r][c] = acc3[rt][r][c];
  }
  __syncthreads();
  if (tid < 96) {
    int row = tid / 3, c = tid % 3;
    out[(ll64)(row0 + row) * 3 + c] = sRed[0][row][c] + sRed[1][row][c] +
                                      sRed[2][row][c] + sRed[3][row][c] + bc[c];
  }
}

// ---------------- launcher ----------------
extern "C" void kernel_launch(void* const* d_in, const int* in_sizes, int n_in,
                              void* d_out, int out_size, void* d_ws, size_t ws_size,
                              hipStream_t stream) {
  const float* x  = (const float*)d_in[0];
  const void*  ei = d_in[1];
  const float* W1 = (const float*)d_in[2];
  const float* b1 = (const float*)d_in[3];
  const float* W2 = (const float*)d_in[4];
  const float* b2 = (const float*)d_in[5];
  const float* W3 = (const float*)d_in[6];
  const float* b3 = (const float*)d_in[7];
  const float* Wi = (const float*)d_in[8];
  const float* bi = (const float*)d_in[9];
  const float* Wc = (const float*)d_in[10];
  const float* bc = (const float*)d_in[11];
  float* out = (float*)d_out;

  char* ws = (char*)d_ws;
  const ll64 KB = 1ll << 10, MB = 1ll << 20;
  float* dinv  = (float*)(ws + 0);
  int*   offs  = (int*)(ws + 512 * KB);
  int*   fill  = (int*)(ws + 1 * MB);
  int*   flag  = (int*)(ws + 1536 * KB);
  int*   part  = (int*)(ws + 1600 * KB);
  int*   total = (int*)(ws + 1700 * KB);
  int*   csr   = (int*)(ws + 2 * MB);              // 12.8 MB -> 14.8
  u16* pW1 = (u16*)(ws + 15 * MB);                 // 32 KB
  u16* pW2 = (u16*)(ws + 15 * MB + 64 * KB);       // 32 KB
  u16* pW3 = (u16*)(ws + 15 * MB + 128 * KB);      // 128 KB
  u16* pWi = (u16*)(ws + 15 * MB + 512 * KB);      // 512 KB
  u16* xh   = (u16*)(ws + 16 * MB);                // 25.6 MB -> 41.6
  u16* bufA = (u16*)(ws + 42 * MB);                // 25.6 MB -> 67.6
  u16* bufB = (u16*)(ws + 68 * MB);                // 25.6 MB -> 93.6

  const int TB = 256;
  const int SB = (NN + 255) / 256;       // 391
  const int NEB = (NE + TB - 1) / TB;
  k_init<<<SB, TB, 0, stream>>>((const int*)ei, flag, fill, NN);
  k_count<<<NEB, TB, 0, stream>>>(ei, flag, fill, NE);
  k_scan1<<<SB, TB, 0, stream>>>(fill, offs, part, dinv, NN);
  k_scan2<<<1, 512, 0, stream>>>(part, total, SB);
  k_scan3<<<SB, TB, 0, stream>>>(offs, fill, part, total, NN);
  k_fill<<<NEB, TB, 0, stream>>>(ei, flag, fill, csr, NE);
  k_packAll<<<1408, TB, 0, stream>>>(W1, W2, W3, Wi, pW1, pW2, pW3, pWi);
  k_half<<<(NN * 32 + TB - 1) / TB, TB, 0, stream>>>((const float4*)x,
                                                     (ushort4*)xh, NN * 32);

  const int MBk = (NN + 63) / 64;  // 1563
  int aggBlocks = (NN + 3) / 4;
  dim3 g128(MBk, 2);

  // layer 1
  k_agg<<<aggBlocks, TB, 0, stream>>>((const uint32*)xh, (uint32*)bufA, csr, offs, dinv, NN);
  k_gemm_mfma<<<g128, TB, 0, stream>>>(bufA, pW1, b1, bufB, NN, 128, 128);
  // layer 2
  k_agg<<<aggBlocks, TB, 0, stream>>>((const uint32*)bufB, (uint32*)bufA, csr, offs, dinv, NN);
  k_gemm_mfma<<<g128, TB, 0, stream>>>(bufA, pW2, b2, bufB, NN, 128, 128);
  // layer 3 aggregation, then fused GEMM512 + MLP head (no h3 buffer)
  k_agg<<<aggBlocks, TB, 0, stream>>>((const uint32*)bufB, (uint32*)bufA, csr, offs, dinv, NN);
  k_tail32<<<NN / 32, TB, 0, stream>>>(bufA, pW3, b3, pWi, bi, Wc, bc, out, NN);
}

// Round 9
// 752.134 us; speedup vs baseline: 3.7233x; 1.4015x over previous
//
#include <hip/hip_runtime.h>
#include <hip/hip_fp16.h>

#define NN 100000
#define NE 3200000
#define NB 391          // coarse buckets of 256 nodes (dst >> 8)
#define NBLK 512        // edge-partition blocks for bin build
#define EPB 6250        // edges per block (NBLK * EPB == NE)
// dims: IN=128, HID=128, INT=512, OUT=3
// fp32 tensors on device; edge_index dtype probed (int32/int64); fp32 output.
// Numerics: fp16 intermediates + single-pass fp16 weights; MFMA f16, fp32 acc
// (comparison floor measured at 1.2207e-4 = 2^-13 dominates all of it).
// Round 9: CSR via 2-level counting sort — all scatters block-private (kills the
// 194 MB cross-XCD line-bounce of the old k_fill; also removes k_count + scans).

typedef unsigned int uint32;
typedef unsigned short u16;
typedef long long ll64;
typedef __attribute__((ext_vector_type(8))) _Float16 half8;
typedef __attribute__((ext_vector_type(4))) float f32x4;

__device__ inline float2 h2f2(uint32 u) {
  __half2 h = *reinterpret_cast<__half2*>(&u);
  return __half22float2(h);
}
__device__ inline uint32 f2h2(float x, float y) {
  return (uint32)__half_as_ushort(__float2half(x)) |
         ((uint32)__half_as_ushort(__float2half(y)) << 16);
}
__device__ inline int edge_at(const void* ei, int is64, ll64 idx) {
  return is64 ? (int)((const ll64*)ei)[idx] : ((const int*)ei)[idx];
}

// ---------------- edge dtype probe ----------------
__global__ void k_probe(const int* __restrict__ ei, int* __restrict__ flag) {
  if (threadIdx.x == 0) {
    int acc = 0;
#pragma unroll
    for (int i = 1; i < 32; i += 2) acc |= ei[i];
    *flag = (acc == 0) ? 1 : 0;  // 1 => int64
  }
}

// ---- CSR build, 2-level counting sort ----
// B: per-block LDS histogram over NB buckets -> tbl[k][b]
__global__ __launch_bounds__(256) void k_binB(const void* __restrict__ ei,
                                              const int* __restrict__ flag,
                                              int* __restrict__ tbl) {
  __shared__ int h[NB];
  int k = blockIdx.x, tid = threadIdx.x;
  for (int i = tid; i < NB; i += 256) h[i] = 0;
  __syncthreads();
  int is64 = *flag;
  ll64 beg = (ll64)k * EPB, end = beg + EPB;
  for (ll64 i = beg + tid; i < end; i += 256)
    atomicAdd(&h[edge_at(ei, is64, (ll64)NE + i) >> 8], 1);
  __syncthreads();
  for (int i = tid; i < NB; i += 256) tbl[k * NB + i] = h[i];
}
// C1: per-bucket exclusive scan across the NBLK blocks; bucket totals out
__global__ __launch_bounds__(512) void k_binC1(int* __restrict__ tbl,
                                               int* __restrict__ total) {
  __shared__ int sd[NBLK];
  int b = blockIdx.x, tid = threadIdx.x;
  int v = tbl[tid * NB + b];
  sd[tid] = v;
  __syncthreads();
  for (int off = 1; off < NBLK; off <<= 1) {
    int t = (tid >= off) ? sd[tid - off] : 0;
    __syncthreads();
    sd[tid] += t;
    __syncthreads();
  }
  tbl[tid * NB + b] = sd[tid] - v;
  if (tid == NBLK - 1) total[b] = sd[NBLK - 1];
}
// C2: exclusive scan of bucket totals -> bucket base (edge-space)
__global__ __launch_bounds__(512) void k_binC2(const int* __restrict__ total,
                                               int* __restrict__ bbase,
                                               int* __restrict__ offs) {
  __shared__ int sd[512];
  int tid = threadIdx.x;
  int v = (tid < NB) ? total[tid] : 0;
  sd[tid] = v;
  __syncthreads();
  for (int off = 1; off < 512; off <<= 1) {
    int t = (tid >= off) ? sd[tid - off] : 0;
    __syncthreads();
    sd[tid] += t;
    __syncthreads();
  }
  if (tid < NB) bbase[tid] = sd[tid] - v;
  if (tid == 0) offs[NN] = NE;
}
// D: scatter edges into block-private dense slices of bucket regions
__global__ __launch_bounds__(256) void k_binD(const void* __restrict__ ei,
                                              const int* __restrict__ flag,
                                              const int* __restrict__ tbl,
                                              const int* __restrict__ bbase,
                                              uint32* __restrict__ binned) {
  __shared__ int lb[NB];
  __shared__ int lc[NB];
  int k = blockIdx.x, tid = threadIdx.x;
  for (int i = tid; i < NB; i += 256) {
    lb[i] = tbl[k * NB + i] + bbase[i];
    lc[i] = 0;
  }
  __syncthreads();
  int is64 = *flag;
  ll64 beg = (ll64)k * EPB, end = beg + EPB;
  for (ll64 i = beg + tid; i < end; i += 256) {
    int s = edge_at(ei, is64, i);
    int d = edge_at(ei, is64, (ll64)NE + i);
    int b = d >> 8;
    int r = atomicAdd(&lc[b], 1);
    binned[lb[b] + r] = (uint32)s | ((uint32)(d & 255) << 24);
  }
}
// E: per-bucket (1 block): node counts -> offs + dinv, then dense csr scatter
__global__ __launch_bounds__(256) void k_binE(const uint32* __restrict__ binned,
                                              const int* __restrict__ bbase,
                                              const int* __restrict__ total,
                                              int* __restrict__ offs,
                                              float* __restrict__ dinv,
                                              int* __restrict__ csr) {
  __shared__ int cnt[256], pref[256], fil[256];
  int b = blockIdx.x, tid = threadIdx.x;
  cnt[tid] = 0;
  fil[tid] = 0;
  __syncthreads();
  int base = bbase[b], tot = total[b];
  for (int i = tid; i < tot; i += 256) atomicAdd(&cnt[binned[base + i] >> 24], 1);
  __syncthreads();
  int v = cnt[tid];
  pref[tid] = v;
  __syncthreads();
  for (int off = 1; off < 256; off <<= 1) {
    int t = (tid >= off) ? pref[tid - off] : 0;
    __syncthreads();
    pref[tid] += t;
    __syncthreads();
  }
  int myoff = pref[tid] - v;  // exclusive
  pref[tid] = myoff;
  int node = b * 256 + tid;
  if (node < NN) {
    offs[node] = base + myoff;
    dinv[node] = rsqrtf((float)(v + 1));  // +1: self-loop
  }
  __syncthreads();
  for (int i = tid; i < tot; i += 256) {
    uint32 w = binned[base + i];
    int dl = w >> 24;
    int r = atomicAdd(&fil[dl], 1);
    csr[base + pref[dl] + r] = (int)(w & 0xFFFFFFu);
  }
}

// ---- weight pack: fp32 W[KxN] -> MFMA B-fragment order, single fp16 plane ----
__device__ inline void packOne(const float* __restrict__ W, u16* __restrict__ ph,
                               int K, int N, int t) {
  int j = t & 7, lane = (t >> 3) & 63, tl = t >> 9;
  int kbn = K >> 5;
  int kb = tl % kbn, ntile = tl / kbn;
  int k = kb * 32 + (lane >> 4) * 8 + j;
  int n2 = ntile * 16 + (lane & 15);
  ph[t] = __half_as_ushort(__float2half(W[k * N + n2]));
}
__global__ void k_packAll(const float* W1, const float* W2, const float* W3,
                          const float* Wi, u16* p1, u16* p2, u16* p3, u16* pi) {
  int t = blockIdx.x * blockDim.x + threadIdx.x;
  if (t < 16384) packOne(W1, p1, 128, 128, t);
  else if (t < 32768) packOne(W2, p2, 128, 128, t - 16384);
  else if (t < 98304) packOne(W3, p3, 128, 512, t - 32768);
  else if (t < 360448) packOne(Wi, pi, 512, 512, t - 98304);
}

// ---------------- x -> fp16 table ----------------
__global__ void k_half(const float4* __restrict__ x, ushort4* __restrict__ xh, int n4) {
  int i = blockIdx.x * blockDim.x + threadIdx.x;
  if (i < n4) {
    float4 v = x[i];
    ushort4 o;
    o.x = __half_as_ushort(__float2half(v.x));
    o.y = __half_as_ushort(__float2half(v.y));
    o.z = __half_as_ushort(__float2half(v.z));
    o.w = __half_as_ushort(__float2half(v.w));
    xh[i] = o;
  }
}

// ---------------- Aggregation (pull, one wave per node, unroll-4, fp16 IO) -------
__global__ void k_agg(const uint32* __restrict__ xi, uint32* __restrict__ o,
                      const int* __restrict__ csr, const int* __restrict__ offs,
                      const float* __restrict__ dinv, int n) {
  int node = blockIdx.x * 4 + (threadIdx.x >> 6);
  int lane = threadIdx.x & 63;
  if (node >= n) return;
  int beg = offs[node], end = offs[node + 1];
  float ax = 0.f, ay = 0.f;
  int j = beg;
  for (; j + 3 < end; j += 4) {
    int s0 = csr[j], s1 = csr[j + 1], s2 = csr[j + 2], s3 = csr[j + 3];
    float d0 = dinv[s0], d1 = dinv[s1], d2 = dinv[s2], d3 = dinv[s3];
    float2 r0 = h2f2(xi[(ll64)s0 * 64 + lane]);
    float2 r1 = h2f2(xi[(ll64)s1 * 64 + lane]);
    float2 r2 = h2f2(xi[(ll64)s2 * 64 + lane]);
    float2 r3 = h2f2(xi[(ll64)s3 * 64 + lane]);
    ax += d0 * r0.x + d1 * r1.x + d2 * r2.x + d3 * r3.x;
    ay += d0 * r0.y + d1 * r1.y + d2 * r2.y + d3 * r3.y;
  }
  for (; j < end; j++) {
    int s = csr[j];
    float d = dinv[s];
    float2 r = h2f2(xi[(ll64)s * 64 + lane]);
    ax += d * r.x;
    ay += d * r.y;
  }
  float di = dinv[node];
  float2 sf = h2f2(xi[(ll64)node * 64 + lane]);
  float vx = di * (ax + di * sf.x);
  float vy = di * (ay + di * sf.y);
  o[(ll64)node * 64 + lane] = f2h2(vx, vy);
}

// -------- MFMA GEMM: C = relu(A @ W + bias); A,C fp16; single-pass B; reg dbuf ------
__global__ __launch_bounds__(256, 4) void k_gemm_mfma(
    const u16* __restrict__ A, const u16* __restrict__ Bp,
    const float* __restrict__ bias, u16* __restrict__ Co, int M, int N, int K) {
  int wave = threadIdx.x >> 6, lane = threadIdx.x & 63;
  int quad = lane >> 4, l16 = lane & 15;
  int row0 = blockIdx.x * 64, col0 = blockIdx.y * 64;
  int m = row0 + wave * 16 + l16;
  int mc = (m < M) ? m : (M - 1);
  int kbn = K >> 5;
  f32x4 acc[4] = {{0,0,0,0},{0,0,0,0},{0,0,0,0},{0,0,0,0}};
  const half8* Ar = (const half8*)&A[(ll64)mc * K];
  half8 ac = Ar[quad];
  half8 an = ac;
  half8 bc_[4], bn_[4];
#pragma unroll
  for (int nt = 0; nt < 4; nt++)
    bc_[nt] = *(const half8*)&Bp[((ll64)(((col0 >> 4) + nt) * kbn) * 64 + lane) * 8];
  for (int kb = 0; kb < kbn; kb++) {
    int kn = kb + 1;
    if (kn < kbn) {
      an = Ar[kn * 4 + quad];
#pragma unroll
      for (int nt = 0; nt < 4; nt++)
        bn_[nt] = *(const half8*)&Bp[((ll64)(((col0 >> 4) + nt) * kbn + kn) * 64 + lane) * 8];
    }
#pragma unroll
    for (int nt = 0; nt < 4; nt++)
      acc[nt] = __builtin_amdgcn_mfma_f32_16x16x32_f16(ac, bc_[nt], acc[nt], 0, 0, 0);
    ac = an;
#pragma unroll
    for (int nt = 0; nt < 4; nt++) bc_[nt] = bn_[nt];
  }
#pragma unroll
  for (int nt = 0; nt < 4; nt++) {
    int cc = col0 + nt * 16 + l16;
    float bv = bias[cc];
#pragma unroll
    for (int r = 0; r < 4; r++) {
      int rr = row0 + wave * 16 + quad * 4 + r;
      if (rr < M)
        Co[(ll64)rr * N + cc] =
            __half_as_ushort(__float2half(fmaxf(acc[nt][r] + bv, 0.0f)));
    }
  }
}

// ---- Fused tail: h3tile = relu(a3@W3+b3) in LDS; out = relu(h3@Wi+bi)@Wc + bc ----
__global__ __launch_bounds__(256, 4) void k_tail32(
    const u16* __restrict__ a3, const u16* __restrict__ W3p,
    const float* __restrict__ b3, const u16* __restrict__ Wip,
    const float* __restrict__ bi, const float* __restrict__ Wc,
    const float* __restrict__ bc, float* __restrict__ out, int M) {
  __shared__ u16 h3s[32 * 512];     // 32 KB, col-octets xor-swizzled by row&7
  __shared__ float sRed[4][32][3];  // 1.5 KB
  int tid = threadIdx.x;
  int wave = tid >> 6, lane = tid & 63, quad = lane >> 4, l16 = lane & 15;
  int row0 = blockIdx.x * 32;  // NN % 32 == 0

  half8 af[2][4];
#pragma unroll
  for (int rt = 0; rt < 2; rt++) {
    const half8* Ar = (const half8*)&a3[(ll64)(row0 + rt * 16 + l16) * 128];
#pragma unroll
    for (int kb = 0; kb < 4; kb++) af[rt][kb] = Ar[kb * 4 + quad];
  }
  {
    f32x4 acc0 = {0, 0, 0, 0}, acc1 = {0, 0, 0, 0};
    half8 bcur = *(const half8*)&W3p[((ll64)(wave * 32) * 64 + lane) * 8];
    half8 bnxt = bcur;
    for (int t = 0; t < 32; t++) {
      if (t + 1 < 32)
        bnxt = *(const half8*)&W3p[((ll64)(wave * 32 + t + 1) * 64 + lane) * 8];
      int kb = t & 3;
      acc0 = __builtin_amdgcn_mfma_f32_16x16x32_f16(af[0][kb], bcur, acc0, 0, 0, 0);
      acc1 = __builtin_amdgcn_mfma_f32_16x16x32_f16(af[1][kb], bcur, acc1, 0, 0, 0);
      if (kb == 3) {
        int nt = wave * 8 + (t >> 2);
        int col = nt * 16 + l16;
        float bv = b3[col];
#pragma unroll
        for (int r = 0; r < 4; r++) {
          int row0l = quad * 4 + r;
          float v0 = fmaxf(acc0[r] + bv, 0.0f);
          float v1 = fmaxf(acc1[r] + bv, 0.0f);
          int oct0 = (col >> 3) ^ (row0l & 7);
          h3s[row0l * 512 + oct0 * 8 + (col & 7)] = __half_as_ushort(__float2half(v0));
          int row1l = 16 + row0l;
          int oct1 = (col >> 3) ^ (row1l & 7);
          h3s[row1l * 512 + oct1 * 8 + (col & 7)] = __half_as_ushort(__float2half(v1));
        }
        acc0 = (f32x4){0, 0, 0, 0};
        acc1 = (f32x4){0, 0, 0, 0};
      }
      bcur = bnxt;
    }
  }
  __syncthreads();

  float acc3[2][4][3] = {};
  {
    f32x4 acc0 = {0, 0, 0, 0}, acc1 = {0, 0, 0, 0};
    half8 bcur = *(const half8*)&Wip[((ll64)(wave * 128) * 64 + lane) * 8];
    half8 bnxt = bcur;
    int r0l = l16, r1l = 16 + l16;
    int sw0 = r0l & 7;
    for (int t = 0; t < 128; t++) {
      if (t + 1 < 128)
        bnxt = *(const half8*)&Wip[((ll64)(wave * 128 + t + 1) * 64 + lane) * 8];
      int kb = t & 15;
      int oct = ((kb * 4 + quad) ^ sw0);
      half8 a0 = *(const half8*)&h3s[r0l * 512 + oct * 8];
      half8 a1 = *(const half8*)&h3s[r1l * 512 + oct * 8];
      acc0 = __builtin_amdgcn_mfma_f32_16x16x32_f16(a0, bcur, acc0, 0, 0, 0);
      acc1 = __builtin_amdgcn_mfma_f32_16x16x32_f16(a1, bcur, acc1, 0, 0, 0);
      if (kb == 15) {
        int nt = wave * 8 + (t >> 4);
        int col = nt * 16 + l16;
        float bv = bi[col];
        float w0 = Wc[col * 3 + 0], w1 = Wc[col * 3 + 1], w2 = Wc[col * 3 + 2];
#pragma unroll
        for (int r = 0; r < 4; r++) {
          float v0 = fmaxf(acc0[r] + bv, 0.0f);
          float v1 = fmaxf(acc1[r] + bv, 0.0f);
          acc3[0][r][0] += v0 * w0; acc3[0][r][1] += v0 * w1; acc3[0][r][2] += v0 * w2;
          acc3[1][r][0] += v1 * w0; acc3[1][r][1] += v1 * w1; acc3[1][r][2] += v1 * w2;
        }
        acc0 = (f32x4){0, 0, 0, 0};
        acc1 = (f32x4){0, 0, 0, 0};
      }
      bcur = bnxt;
    }
  }
#pragma unroll
  for (int rt = 0; rt < 2; rt++)
#pragma unroll
    for (int r = 0; r < 4; r++)
#pragma unroll
      for (int c = 0; c < 3; c++) {
        float v = acc3[rt][r][c];
        v += __shfl_xor(v, 1);
        v += __shfl_xor(v, 2);
        v += __shfl_xor(v, 4);
        v += __shfl_xor(v, 8);
        acc3[rt][r][c] = v;
      }
  if (l16 == 0) {
#pragma unroll
    for (int rt = 0; rt < 2; rt++)
#pragma unroll
      for (int r = 0; r < 4; r++)
#pragma unroll
        for (int c = 0; c < 3; c++)
          sRed[wave][rt * 16 + quad * 4 + r][c] = acc3[rt][r][c];
  }
  __syncthreads();
  if (tid < 96) {
    int row = tid / 3, c = tid % 3;
    out[(ll64)(row0 + row) * 3 + c] = sRed[0][row][c] + sRed[1][row][c] +
                                      sRed[2][row][c] + sRed[3][row][c] + bc[c];
  }
}

// ---------------- launcher ----------------
extern "C" void kernel_launch(void* const* d_in, const int* in_sizes, int n_in,
                              void* d_out, int out_size, void* d_ws, size_t ws_size,
                              hipStream_t stream) {
  const float* x  = (const float*)d_in[0];
  const void*  ei = d_in[1];
  const float* W1 = (const float*)d_in[2];
  const float* b1 = (const float*)d_in[3];
  const float* W2 = (const float*)d_in[4];
  const float* b2 = (const float*)d_in[5];
  const float* W3 = (const float*)d_in[6];
  const float* b3 = (const float*)d_in[7];
  const float* Wi = (const float*)d_in[8];
  const float* bi = (const float*)d_in[9];
  const float* Wc = (const float*)d_in[10];
  const float* bc = (const float*)d_in[11];
  float* out = (float*)d_out;

  char* ws = (char*)d_ws;
  const ll64 KB = 1ll << 10, MB = 1ll << 20;
  float* dinv  = (float*)(ws + 0);                 // 400 KB
  int*   offs  = (int*)(ws + 512 * KB);            // 400 KB (NN+1)
  int*   flag  = (int*)(ws + 1 * MB);
  int*   total = (int*)(ws + 1 * MB + 64 * KB);    // 1.6 KB
  int*   bbase = (int*)(ws + 1 * MB + 128 * KB);   // 1.6 KB
  int*   tbl   = (int*)(ws + 1 * MB + 192 * KB);   // 800 KB -> ends ~2 MB
  uint32* binned = (uint32*)(ws + 2 * MB);         // 12.8 MB -> 14.8
  int*   csr   = (int*)(ws + 15 * MB);             // 12.8 MB -> 27.8
  u16* pW1 = (u16*)(ws + 28 * MB);                 // 32 KB
  u16* pW2 = (u16*)(ws + 28 * MB + 64 * KB);       // 32 KB
  u16* pW3 = (u16*)(ws + 28 * MB + 128 * KB);      // 128 KB
  u16* pWi = (u16*)(ws + 28 * MB + 512 * KB);      // 512 KB
  u16* xh   = (u16*)(ws + 29 * MB);                // 25.6 MB -> 54.6
  u16* bufA = (u16*)(ws + 55 * MB);                // 25.6 MB -> 80.6
  u16* bufB = (u16*)(ws + 81 * MB);                // 25.6 MB -> 106.6

  const int TB = 256;
  k_probe<<<1, 64, 0, stream>>>((const int*)ei, flag);
  k_binB<<<NBLK, TB, 0, stream>>>(ei, flag, tbl);
  k_binC1<<<NB, NBLK, 0, stream>>>(tbl, total);
  k_binC2<<<1, 512, 0, stream>>>(total, bbase, offs);
  k_binD<<<NBLK, TB, 0, stream>>>(ei, flag, tbl, bbase, binned);
  k_binE<<<NB, TB, 0, stream>>>(binned, bbase, total, offs, dinv, csr);
  k_packAll<<<1408, TB, 0, stream>>>(W1, W2, W3, Wi, pW1, pW2, pW3, pWi);
  k_half<<<(NN * 32 + TB - 1) / TB, TB, 0, stream>>>((const float4*)x,
                                                     (ushort4*)xh, NN * 32);

  const int MBk = (NN + 63) / 64;  // 1563
  int aggBlocks = (NN + 3) / 4;
  dim3 g128(MBk, 2);

  // layer 1
  k_agg<<<aggBlocks, TB, 0, stream>>>((const uint32*)xh, (uint32*)bufA, csr, offs, dinv, NN);
  k_gemm_mfma<<<g128, TB, 0, stream>>>(bufA, pW1, b1, bufB, NN, 128, 128);
  // layer 2
  k_agg<<<aggBlocks, TB, 0, stream>>>((const uint32*)bufB, (uint32*)bufA, csr, offs, dinv, NN);
  k_gemm_mfma<<<g128, TB, 0, stream>>>(bufA, pW2, b2, bufB, NN, 128, 128);
  // layer 3 aggregation, then fused GEMM512 + MLP head
  k_agg<<<aggBlocks, TB, 0, stream>>>((const uint32*)bufB, (uint32*)bufA, csr, offs, dinv, NN);
  k_tail32<<<NN / 32, TB, 0, stream>>>(bufA, pW3, b3, pWi, bi, Wc, bc, out, NN);
}

// Round 10
// 737.301 us; speedup vs baseline: 3.7982x; 1.0201x over previous
//
#include <hip/hip_runtime.h>
#include <hip/hip_fp16.h>

#define NN 100000
#define NE 3200000
#define NB 391          // coarse buckets of 256 nodes (dst >> 8)
#define NBLK 512        // edge-partition blocks for bin build
#define EPB 6250        // edges per block (NBLK * EPB == NE)
// dims: IN=128, HID=128, INT=512, OUT=3
// fp32 tensors on device; edge_index dtype probed per-block (int32/int64); fp32 out.
// Numerics: fp16 intermediates + single-pass fp16 weights; MFMA f16, fp32 acc
// (comparison floor measured at 1.2207e-4 = 2^-13 dominates).
// Round 10: 48-row fused tail (3 MFMA/B-load, Wi traffic 1.07 GB, 3 blk/CU),
// conflict-free paired-u32 LDS writes, agg unroll-8, -2 launches.

typedef unsigned int uint32;
typedef unsigned short u16;
typedef long long ll64;
typedef __attribute__((ext_vector_type(8))) _Float16 half8;
typedef __attribute__((ext_vector_type(4))) float f32x4;

__device__ inline float2 h2f2(uint32 u) {
  __half2 h = *reinterpret_cast<__half2*>(&u);
  return __half22float2(h);
}
__device__ inline uint32 f2h2(float x, float y) {
  return (uint32)__half_as_ushort(__float2half(x)) |
         ((uint32)__half_as_ushort(__float2half(y)) << 16);
}
__device__ inline int edge_at(const void* ei, int is64, ll64 idx) {
  return is64 ? (int)((const ll64*)ei)[idx] : ((const int*)ei)[idx];
}
// per-block edge-dtype detection (int64 => odd int32 words of first entries all 0)
__device__ inline int detect64(const int* ei32) {
  int acc = 0;
#pragma unroll
  for (int k = 1; k < 32; k += 2) acc |= ei32[k];
  return (acc == 0) ? 1 : 0;
}

// ---- CSR build, 2-level counting sort ----
__global__ __launch_bounds__(256) void k_binB(const void* __restrict__ ei,
                                              int* __restrict__ tbl) {
  __shared__ int h[NB];
  __shared__ int sIs64;
  int k = blockIdx.x, tid = threadIdx.x;
  for (int i = tid; i < NB; i += 256) h[i] = 0;
  if (tid == 0) sIs64 = detect64((const int*)ei);
  __syncthreads();
  int is64 = sIs64;
  ll64 beg = (ll64)k * EPB, end = beg + EPB;
  for (ll64 i = beg + tid; i < end; i += 256)
    atomicAdd(&h[edge_at(ei, is64, (ll64)NE + i) >> 8], 1);
  __syncthreads();
  for (int i = tid; i < NB; i += 256) tbl[k * NB + i] = h[i];
}
__global__ __launch_bounds__(512) void k_binC1(int* __restrict__ tbl,
                                               int* __restrict__ total) {
  __shared__ int sd[NBLK];
  int b = blockIdx.x, tid = threadIdx.x;
  int v = tbl[tid * NB + b];
  sd[tid] = v;
  __syncthreads();
  for (int off = 1; off < NBLK; off <<= 1) {
    int t = (tid >= off) ? sd[tid - off] : 0;
    __syncthreads();
    sd[tid] += t;
    __syncthreads();
  }
  tbl[tid * NB + b] = sd[tid] - v;
  if (tid == NBLK - 1) total[b] = sd[NBLK - 1];
}
__global__ __launch_bounds__(512) void k_binC2(const int* __restrict__ total,
                                               int* __restrict__ bbase,
                                               int* __restrict__ offs) {
  __shared__ int sd[512];
  int tid = threadIdx.x;
  int v = (tid < NB) ? total[tid] : 0;
  sd[tid] = v;
  __syncthreads();
  for (int off = 1; off < 512; off <<= 1) {
    int t = (tid >= off) ? sd[tid - off] : 0;
    __syncthreads();
    sd[tid] += t;
    __syncthreads();
  }
  if (tid < NB) bbase[tid] = sd[tid] - v;
  if (tid == 0) offs[NN] = NE;
}
__global__ __launch_bounds__(256) void k_binD(const void* __restrict__ ei,
                                              const int* __restrict__ tbl,
                                              const int* __restrict__ bbase,
                                              uint32* __restrict__ binned) {
  __shared__ int lb[NB];
  __shared__ int lc[NB];
  __shared__ int sIs64;
  int k = blockIdx.x, tid = threadIdx.x;
  for (int i = tid; i < NB; i += 256) {
    lb[i] = tbl[k * NB + i] + bbase[i];
    lc[i] = 0;
  }
  if (tid == 0) sIs64 = detect64((const int*)ei);
  __syncthreads();
  int is64 = sIs64;
  ll64 beg = (ll64)k * EPB, end = beg + EPB;
  for (ll64 i = beg + tid; i < end; i += 256) {
    int s = edge_at(ei, is64, i);
    int d = edge_at(ei, is64, (ll64)NE + i);
    int b = d >> 8;
    int r = atomicAdd(&lc[b], 1);
    binned[lb[b] + r] = (uint32)s | ((uint32)(d & 255) << 24);
  }
}
__global__ __launch_bounds__(256) void k_binE(const uint32* __restrict__ binned,
                                              const int* __restrict__ bbase,
                                              const int* __restrict__ total,
                                              int* __restrict__ offs,
                                              float* __restrict__ dinv,
                                              int* __restrict__ csr) {
  __shared__ int cnt[256], pref[256], fil[256];
  int b = blockIdx.x, tid = threadIdx.x;
  cnt[tid] = 0;
  fil[tid] = 0;
  __syncthreads();
  int base = bbase[b], tot = total[b];
  for (int i = tid; i < tot; i += 256) atomicAdd(&cnt[binned[base + i] >> 24], 1);
  __syncthreads();
  int v = cnt[tid];
  pref[tid] = v;
  __syncthreads();
  for (int off = 1; off < 256; off <<= 1) {
    int t = (tid >= off) ? pref[tid - off] : 0;
    __syncthreads();
    pref[tid] += t;
    __syncthreads();
  }
  int myoff = pref[tid] - v;  // exclusive
  pref[tid] = myoff;
  int node = b * 256 + tid;
  if (node < NN) {
    offs[node] = base + myoff;
    dinv[node] = rsqrtf((float)(v + 1));  // +1: self-loop
  }
  __syncthreads();
  for (int i = tid; i < tot; i += 256) {
    uint32 w = binned[base + i];
    int dl = w >> 24;
    int r = atomicAdd(&fil[dl], 1);
    csr[base + pref[dl] + r] = (int)(w & 0xFFFFFFu);
  }
}

// ---- weight pack (fp16 B-fragment order) + x->fp16, one kernel ----
__device__ inline void packOne(const float* __restrict__ W, u16* __restrict__ ph,
                               int K, int N, int t) {
  int j = t & 7, lane = (t >> 3) & 63, tl = t >> 9;
  int kbn = K >> 5;
  int kb = tl % kbn, ntile = tl / kbn;
  int k = kb * 32 + (lane >> 4) * 8 + j;
  int n2 = ntile * 16 + (lane & 15);
  ph[t] = __half_as_ushort(__float2half(W[k * N + n2]));
}
__global__ void k_packhalf(const float* W1, const float* W2, const float* W3,
                           const float* Wi, u16* p1, u16* p2, u16* p3, u16* pi,
                           const float4* __restrict__ x, ushort4* __restrict__ xh) {
  int t = blockIdx.x * blockDim.x + threadIdx.x;
  if (t < 16384) packOne(W1, p1, 128, 128, t);
  else if (t < 32768) packOne(W2, p2, 128, 128, t - 16384);
  else if (t < 98304) packOne(W3, p3, 128, 512, t - 32768);
  else if (t < 360448) packOne(Wi, pi, 512, 512, t - 98304);
  else {
    int i = t - 360448;
    if (i < NN * 32) {
      float4 v = x[i];
      ushort4 o;
      o.x = __half_as_ushort(__float2half(v.x));
      o.y = __half_as_ushort(__float2half(v.y));
      o.z = __half_as_ushort(__float2half(v.z));
      o.w = __half_as_ushort(__float2half(v.w));
      xh[i] = o;
    }
  }
}

// ---------------- Aggregation (pull, one wave per node, unroll-8, fp16 IO) -------
__global__ void k_agg(const uint32* __restrict__ xi, uint32* __restrict__ o,
                      const int* __restrict__ csr, const int* __restrict__ offs,
                      const float* __restrict__ dinv, int n) {
  int node = blockIdx.x * 4 + (threadIdx.x >> 6);
  int lane = threadIdx.x & 63;
  if (node >= n) return;
  int beg = offs[node], end = offs[node + 1];
  float ax = 0.f, ay = 0.f;
  int j = beg;
  for (; j + 7 < end; j += 8) {
    int s[8];
    float dd[8];
    float2 rr[8];
#pragma unroll
    for (int q = 0; q < 8; q++) s[q] = csr[j + q];
#pragma unroll
    for (int q = 0; q < 8; q++) dd[q] = dinv[s[q]];
#pragma unroll
    for (int q = 0; q < 8; q++) rr[q] = h2f2(xi[(ll64)s[q] * 64 + lane]);
#pragma unroll
    for (int q = 0; q < 8; q++) {
      ax += dd[q] * rr[q].x;
      ay += dd[q] * rr[q].y;
    }
  }
  for (; j < end; j++) {
    int s = csr[j];
    float d = dinv[s];
    float2 r = h2f2(xi[(ll64)s * 64 + lane]);
    ax += d * r.x;
    ay += d * r.y;
  }
  float di = dinv[node];
  float2 sf = h2f2(xi[(ll64)node * 64 + lane]);
  float vx = di * (ax + di * sf.x);
  float vy = di * (ay + di * sf.y);
  o[(ll64)node * 64 + lane] = f2h2(vx, vy);
}

// -------- MFMA GEMM: C = relu(A @ W + bias); A,C fp16; single-pass B; reg dbuf ------
__global__ __launch_bounds__(256, 4) void k_gemm_mfma(
    const u16* __restrict__ A, const u16* __restrict__ Bp,
    const float* __restrict__ bias, u16* __restrict__ Co, int M, int N, int K) {
  int wave = threadIdx.x >> 6, lane = threadIdx.x & 63;
  int quad = lane >> 4, l16 = lane & 15;
  int row0 = blockIdx.x * 64, col0 = blockIdx.y * 64;
  int m = row0 + wave * 16 + l16;
  int mc = (m < M) ? m : (M - 1);
  int kbn = K >> 5;
  f32x4 acc[4] = {{0,0,0,0},{0,0,0,0},{0,0,0,0},{0,0,0,0}};
  const half8* Ar = (const half8*)&A[(ll64)mc * K];
  half8 ac = Ar[quad];
  half8 an = ac;
  half8 bc_[4], bn_[4];
#pragma unroll
  for (int nt = 0; nt < 4; nt++)
    bc_[nt] = *(const half8*)&Bp[((ll64)(((col0 >> 4) + nt) * kbn) * 64 + lane) * 8];
  for (int kb = 0; kb < kbn; kb++) {
    int kn = kb + 1;
    if (kn < kbn) {
      an = Ar[kn * 4 + quad];
#pragma unroll
      for (int nt = 0; nt < 4; nt++)
        bn_[nt] = *(const half8*)&Bp[((ll64)(((col0 >> 4) + nt) * kbn + kn) * 64 + lane) * 8];
    }
#pragma unroll
    for (int nt = 0; nt < 4; nt++)
      acc[nt] = __builtin_amdgcn_mfma_f32_16x16x32_f16(ac, bc_[nt], acc[nt], 0, 0, 0);
    ac = an;
#pragma unroll
    for (int nt = 0; nt < 4; nt++) bc_[nt] = bn_[nt];
  }
#pragma unroll
  for (int nt = 0; nt < 4; nt++) {
    int cc = col0 + nt * 16 + l16;
    float bv = bias[cc];
#pragma unroll
    for (int r = 0; r < 4; r++) {
      int rr = row0 + wave * 16 + quad * 4 + r;
      if (rr < M)
        Co[(ll64)rr * N + cc] =
            __half_as_ushort(__float2half(fmaxf(acc[nt][r] + bv, 0.0f)));
    }
  }
}

// ---- Fused tail, 48-row tile: h3 = relu(a3@W3+b3) in LDS; out = relu(h3@Wi+bi)@Wc+bc
// 3 row-tiles of 16; wave owns 8 ntiles; 3 MFMA per B-load; paired-u32 LDS writes.
__global__ __launch_bounds__(256, 3) void k_tail48(
    const u16* __restrict__ a3, const u16* __restrict__ W3p,
    const float* __restrict__ b3, const u16* __restrict__ Wip,
    const float* __restrict__ bi, const float* __restrict__ Wc,
    const float* __restrict__ bc, float* __restrict__ out, int M) {
  __shared__ u16 h3s[48 * 512];  // 48 KB; col-octets xor-swizzled by row&7
  float* sRed = (float*)h3s;     // aliased after phase 2: [4][48][3]
  int tid = threadIdx.x;
  int wave = tid >> 6, lane = tid & 63, quad = lane >> 4, l16 = lane & 15;
  int row0 = blockIdx.x * 48;

  // ---- phase 1: 48x512 = a3[48x128] @ W3 into LDS ----
  half8 af[3][4];
#pragma unroll
  for (int rt = 0; rt < 3; rt++) {
    int r = row0 + rt * 16 + l16;
    int rc = (r < M) ? r : (M - 1);  // clamp: OOB rows never stored
    const half8* Ar = (const half8*)&a3[(ll64)rc * 128];
#pragma unroll
    for (int kb = 0; kb < 4; kb++) af[rt][kb] = Ar[kb * 4 + quad];
  }
  {
    f32x4 acc[3] = {{0,0,0,0},{0,0,0,0},{0,0,0,0}};
    half8 bcur = *(const half8*)&W3p[((ll64)(wave * 32) * 64 + lane) * 8];
    half8 bnxt = bcur;
    for (int t = 0; t < 32; t++) {
      if (t + 1 < 32)
        bnxt = *(const half8*)&W3p[((ll64)(wave * 32 + t + 1) * 64 + lane) * 8];
      int kb = t & 3;
#pragma unroll
      for (int rt = 0; rt < 3; rt++)
        acc[rt] = __builtin_amdgcn_mfma_f32_16x16x32_f16(af[rt][kb], bcur, acc[rt], 0, 0, 0);
      if (kb == 3) {
        int nt = wave * 8 + (t >> 2);
        int col = nt * 16 + l16;
        float bv = b3[col];
#pragma unroll
        for (int rt = 0; rt < 3; rt++)
#pragma unroll
          for (int r = 0; r < 4; r++) {
            int row = rt * 16 + quad * 4 + r;
            u16 h = __half_as_ushort(__float2half(fmaxf(acc[rt][r] + bv, 0.0f)));
            // pair adjacent lanes -> even lane writes u32 (conflict-free)
            u16 nb = (u16)__shfl_xor((int)h, 1);
            if ((l16 & 1) == 0) {
              int oct = (col >> 3) ^ (row & 7);
              uint32 w = (uint32)h | ((uint32)nb << 16);
              *(uint32*)&h3s[row * 512 + oct * 8 + (col & 7)] = w;
            }
          }
        acc[0] = (f32x4){0,0,0,0};
        acc[1] = (f32x4){0,0,0,0};
        acc[2] = (f32x4){0,0,0,0};
      }
      bcur = bnxt;
    }
  }
  __syncthreads();

  // ---- phase 2: h3s @ Wi (K=512) + fold Wc ----
  float acc3[3][4][3] = {};
  {
    f32x4 acc[3] = {{0,0,0,0},{0,0,0,0},{0,0,0,0}};
    half8 bcur = *(const half8*)&Wip[((ll64)(wave * 128) * 64 + lane) * 8];
    half8 bnxt = bcur;
    int sw = l16 & 7;
    for (int t = 0; t < 128; t++) {
      if (t + 1 < 128)
        bnxt = *(const half8*)&Wip[((ll64)(wave * 128 + t + 1) * 64 + lane) * 8];
      int kb = t & 15;
      int oct = (kb * 4 + quad) ^ sw;
      half8 a0 = *(const half8*)&h3s[(l16)      * 512 + oct * 8];
      half8 a1 = *(const half8*)&h3s[(16 + l16) * 512 + oct * 8];
      half8 a2 = *(const half8*)&h3s[(32 + l16) * 512 + oct * 8];
      acc[0] = __builtin_amdgcn_mfma_f32_16x16x32_f16(a0, bcur, acc[0], 0, 0, 0);
      acc[1] = __builtin_amdgcn_mfma_f32_16x16x32_f16(a1, bcur, acc[1], 0, 0, 0);
      acc[2] = __builtin_amdgcn_mfma_f32_16x16x32_f16(a2, bcur, acc[2], 0, 0, 0);
      if (kb == 15) {
        int col = (wave * 8 + (t >> 4)) * 16 + l16;
        float bv = bi[col];
        float w0 = Wc[col * 3 + 0], w1 = Wc[col * 3 + 1], w2 = Wc[col * 3 + 2];
#pragma unroll
        for (int rt = 0; rt < 3; rt++)
#pragma unroll
          for (int r = 0; r < 4; r++) {
            float v = fmaxf(acc[rt][r] + bv, 0.0f);
            acc3[rt][r][0] += v * w0;
            acc3[rt][r][1] += v * w1;
            acc3[rt][r][2] += v * w2;
          }
        acc[0] = (f32x4){0,0,0,0};
        acc[1] = (f32x4){0,0,0,0};
        acc[2] = (f32x4){0,0,0,0};
      }
      bcur = bnxt;
    }
  }
  // reduce over the 16 l16 lanes
#pragma unroll
  for (int rt = 0; rt < 3; rt++)
#pragma unroll
    for (int r = 0; r < 4; r++)
#pragma unroll
      for (int c = 0; c < 3; c++) {
        float v = acc3[rt][r][c];
        v += __shfl_xor(v, 1);
        v += __shfl_xor(v, 2);
        v += __shfl_xor(v, 4);
        v += __shfl_xor(v, 8);
        acc3[rt][r][c] = v;
      }
  __syncthreads();  // all phase-2 LDS reads done; safe to alias sRed over h3s
  if (l16 == 0) {
#pragma unroll
    for (int rt = 0; rt < 3; rt++)
#pragma unroll
      for (int r = 0; r < 4; r++)
#pragma unroll
        for (int c = 0; c < 3; c++)
          sRed[(wave * 48 + rt * 16 + quad * 4 + r) * 3 + c] = acc3[rt][r][c];
  }
  __syncthreads();
  if (tid < 144) {
    int row = tid / 3, c = tid % 3;
    int gr = row0 + row;
    if (gr < M)
      out[(ll64)gr * 3 + c] = sRed[(0 * 48 + row) * 3 + c] + sRed[(1 * 48 + row) * 3 + c] +
                              sRed[(2 * 48 + row) * 3 + c] + sRed[(3 * 48 + row) * 3 + c] +
                              bc[c];
  }
}

// ---------------- launcher ----------------
extern "C" void kernel_launch(void* const* d_in, const int* in_sizes, int n_in,
                              void* d_out, int out_size, void* d_ws, size_t ws_size,
                              hipStream_t stream) {
  const float* x  = (const float*)d_in[0];
  const void*  ei = d_in[1];
  const float* W1 = (const float*)d_in[2];
  const float* b1 = (const float*)d_in[3];
  const float* W2 = (const float*)d_in[4];
  const float* b2 = (const float*)d_in[5];
  const float* W3 = (const float*)d_in[6];
  const float* b3 = (const float*)d_in[7];
  const float* Wi = (const float*)d_in[8];
  const float* bi = (const float*)d_in[9];
  const float* Wc = (const float*)d_in[10];
  const float* bc = (const float*)d_in[11];
  float* out = (float*)d_out;

  char* ws = (char*)d_ws;
  const ll64 KB = 1ll << 10, MB = 1ll << 20;
  float* dinv  = (float*)(ws + 0);                 // 400 KB
  int*   offs  = (int*)(ws + 512 * KB);            // 400 KB (NN+1)
  int*   total = (int*)(ws + 1 * MB + 64 * KB);    // 1.6 KB
  int*   bbase = (int*)(ws + 1 * MB + 128 * KB);   // 1.6 KB
  int*   tbl   = (int*)(ws + 1 * MB + 192 * KB);   // 800 KB -> ends ~2 MB
  uint32* binned = (uint32*)(ws + 2 * MB);         // 12.8 MB -> 14.8
  int*   csr   = (int*)(ws + 15 * MB);             // 12.8 MB -> 27.8
  u16* pW1 = (u16*)(ws + 28 * MB);                 // 32 KB
  u16* pW2 = (u16*)(ws + 28 * MB + 64 * KB);       // 32 KB
  u16* pW3 = (u16*)(ws + 28 * MB + 128 * KB);      // 128 KB
  u16* pWi = (u16*)(ws + 28 * MB + 512 * KB);      // 512 KB
  u16* xh   = (u16*)(ws + 29 * MB);                // 25.6 MB -> 54.6
  u16* bufA = (u16*)(ws + 55 * MB);                // 25.6 MB -> 80.6
  u16* bufB = (u16*)(ws + 81 * MB);                // 25.6 MB -> 106.6

  const int TB = 256;
  k_binB<<<NBLK, TB, 0, stream>>>(ei, tbl);
  k_binC1<<<NB, NBLK, 0, stream>>>(tbl, total);
  k_binC2<<<1, 512, 0, stream>>>(total, bbase, offs);
  k_binD<<<NBLK, TB, 0, stream>>>(ei, tbl, bbase, binned);
  k_binE<<<NB, TB, 0, stream>>>(binned, bbase, total, offs, dinv, csr);
  // pack weights + convert x to fp16 (360448 pack items + NN*32 convert items)
  k_packhalf<<<(360448 + NN * 32 + TB - 1) / TB, TB, 0, stream>>>(
      W1, W2, W3, Wi, pW1, pW2, pW3, pWi, (const float4*)x, (ushort4*)xh);

  const int MBk = (NN + 63) / 64;  // 1563
  int aggBlocks = (NN + 3) / 4;
  dim3 g128(MBk, 2);

  // layer 1
  k_agg<<<aggBlocks, TB, 0, stream>>>((const uint32*)xh, (uint32*)bufA, csr, offs, dinv, NN);
  k_gemm_mfma<<<g128, TB, 0, stream>>>(bufA, pW1, b1, bufB, NN, 128, 128);
  // layer 2
  k_agg<<<aggBlocks, TB, 0, stream>>>((const uint32*)bufB, (uint32*)bufA, csr, offs, dinv, NN);
  k_gemm_mfma<<<g128, TB, 0, stream>>>(bufA, pW2, b2, bufB, NN, 128, 128);
  // layer 3 aggregation, then fused GEMM512 + MLP head
  k_agg<<<aggBlocks, TB, 0, stream>>>((const uint32*)bufB, (uint32*)bufA, csr, offs, dinv, NN);
  k_tail48<<<(NN + 47) / 48, TB, 0, stream>>>(bufA, pW3, b3, pWi, bi, Wc, bc, out, NN);
}

// Round 11
// 716.041 us; speedup vs baseline: 3.9110x; 1.0297x over previous
//
#include <hip/hip_runtime.h>
#include <hip/hip_fp16.h>

#define NN 100000
#define NE 3200000
#define NB 391          // coarse buckets of 256 nodes (dst >> 8)
#define NBLK 512        // edge-partition blocks for bin build
#define EPB 6250        // edges per block (NBLK * EPB == NE)
// dims: IN=128, HID=128, INT=512, OUT=3
// fp32 tensors on device; edge_index dtype probed per-block (int32/int64); fp32 out.
// Numerics: fp16 intermediates + single-pass fp16 weights; MFMA f16, fp32 acc
// (comparison floor measured at 1.2207e-4 = 2^-13).
// Round 11: revert tail to 32-row (r9-measured 130 µs; 48-row lost occupancy),
// fold dinv into stored activations (agg loses dinv gathers: -1/3 loads/edge).

typedef unsigned int uint32;
typedef unsigned short u16;
typedef long long ll64;
typedef __attribute__((ext_vector_type(8))) _Float16 half8;
typedef __attribute__((ext_vector_type(4))) float f32x4;

__device__ inline float2 h2f2(uint32 u) {
  __half2 h = *reinterpret_cast<__half2*>(&u);
  return __half22float2(h);
}
__device__ inline uint32 f2h2(float x, float y) {
  return (uint32)__half_as_ushort(__float2half(x)) |
         ((uint32)__half_as_ushort(__float2half(y)) << 16);
}
__device__ inline int edge_at(const void* ei, int is64, ll64 idx) {
  return is64 ? (int)((const ll64*)ei)[idx] : ((const int*)ei)[idx];
}
__device__ inline int detect64(const int* ei32) {
  int acc = 0;
#pragma unroll
  for (int k = 1; k < 32; k += 2) acc |= ei32[k];
  return (acc == 0) ? 1 : 0;
}

// ---- CSR build, 2-level counting sort ----
__global__ __launch_bounds__(256) void k_binB(const void* __restrict__ ei,
                                              int* __restrict__ tbl) {
  __shared__ int h[NB];
  __shared__ int sIs64;
  int k = blockIdx.x, tid = threadIdx.x;
  for (int i = tid; i < NB; i += 256) h[i] = 0;
  if (tid == 0) sIs64 = detect64((const int*)ei);
  __syncthreads();
  int is64 = sIs64;
  ll64 beg = (ll64)k * EPB, end = beg + EPB;
  for (ll64 i = beg + tid; i < end; i += 256)
    atomicAdd(&h[edge_at(ei, is64, (ll64)NE + i) >> 8], 1);
  __syncthreads();
  for (int i = tid; i < NB; i += 256) tbl[k * NB + i] = h[i];
}
__global__ __launch_bounds__(512) void k_binC1(int* __restrict__ tbl,
                                               int* __restrict__ total) {
  __shared__ int sd[NBLK];
  int b = blockIdx.x, tid = threadIdx.x;
  int v = tbl[tid * NB + b];
  sd[tid] = v;
  __syncthreads();
  for (int off = 1; off < NBLK; off <<= 1) {
    int t = (tid >= off) ? sd[tid - off] : 0;
    __syncthreads();
    sd[tid] += t;
    __syncthreads();
  }
  tbl[tid * NB + b] = sd[tid] - v;
  if (tid == NBLK - 1) total[b] = sd[NBLK - 1];
}
__global__ __launch_bounds__(512) void k_binC2(const int* __restrict__ total,
                                               int* __restrict__ bbase,
                                               int* __restrict__ offs) {
  __shared__ int sd[512];
  int tid = threadIdx.x;
  int v = (tid < NB) ? total[tid] : 0;
  sd[tid] = v;
  __syncthreads();
  for (int off = 1; off < 512; off <<= 1) {
    int t = (tid >= off) ? sd[tid - off] : 0;
    __syncthreads();
    sd[tid] += t;
    __syncthreads();
  }
  if (tid < NB) bbase[tid] = sd[tid] - v;
  if (tid == 0) offs[NN] = NE;
}
__global__ __launch_bounds__(256) void k_binD(const void* __restrict__ ei,
                                              const int* __restrict__ tbl,
                                              const int* __restrict__ bbase,
                                              uint32* __restrict__ binned) {
  __shared__ int lb[NB];
  __shared__ int lc[NB];
  __shared__ int sIs64;
  int k = blockIdx.x, tid = threadIdx.x;
  for (int i = tid; i < NB; i += 256) {
    lb[i] = tbl[k * NB + i] + bbase[i];
    lc[i] = 0;
  }
  if (tid == 0) sIs64 = detect64((const int*)ei);
  __syncthreads();
  int is64 = sIs64;
  ll64 beg = (ll64)k * EPB, end = beg + EPB;
  for (ll64 i = beg + tid; i < end; i += 256) {
    int s = edge_at(ei, is64, i);
    int d = edge_at(ei, is64, (ll64)NE + i);
    int b = d >> 8;
    int r = atomicAdd(&lc[b], 1);
    binned[lb[b] + r] = (uint32)s | ((uint32)(d & 255) << 24);
  }
}
__global__ __launch_bounds__(256) void k_binE(const uint32* __restrict__ binned,
                                              const int* __restrict__ bbase,
                                              const int* __restrict__ total,
                                              int* __restrict__ offs,
                                              float* __restrict__ dinv,
                                              int* __restrict__ csr) {
  __shared__ int cnt[256], pref[256], fil[256];
  int b = blockIdx.x, tid = threadIdx.x;
  cnt[tid] = 0;
  fil[tid] = 0;
  __syncthreads();
  int base = bbase[b], tot = total[b];
  for (int i = tid; i < tot; i += 256) atomicAdd(&cnt[binned[base + i] >> 24], 1);
  __syncthreads();
  int v = cnt[tid];
  pref[tid] = v;
  __syncthreads();
  for (int off = 1; off < 256; off <<= 1) {
    int t = (tid >= off) ? pref[tid - off] : 0;
    __syncthreads();
    pref[tid] += t;
    __syncthreads();
  }
  int myoff = pref[tid] - v;  // exclusive
  pref[tid] = myoff;
  int node = b * 256 + tid;
  if (node < NN) {
    offs[node] = base + myoff;
    dinv[node] = rsqrtf((float)(v + 1));  // +1: self-loop
  }
  __syncthreads();
  for (int i = tid; i < tot; i += 256) {
    uint32 w = binned[base + i];
    int dl = w >> 24;
    int r = atomicAdd(&fil[dl], 1);
    csr[base + pref[dl] + r] = (int)(w & 0xFFFFFFu);
  }
}

// ---- weight pack (fp16 B-fragment order) + x -> dinv-prescaled fp16 ----
__device__ inline void packOne(const float* __restrict__ W, u16* __restrict__ ph,
                               int K, int N, int t) {
  int j = t & 7, lane = (t >> 3) & 63, tl = t >> 9;
  int kbn = K >> 5;
  int kb = tl % kbn, ntile = tl / kbn;
  int k = kb * 32 + (lane >> 4) * 8 + j;
  int n2 = ntile * 16 + (lane & 15);
  ph[t] = __half_as_ushort(__float2half(W[k * N + n2]));
}
__global__ void k_packhalf(const float* W1, const float* W2, const float* W3,
                           const float* Wi, u16* p1, u16* p2, u16* p3, u16* pi,
                           const float4* __restrict__ x, ushort4* __restrict__ xh,
                           const float* __restrict__ dinv) {
  int t = blockIdx.x * blockDim.x + threadIdx.x;
  if (t < 16384) packOne(W1, p1, 128, 128, t);
  else if (t < 32768) packOne(W2, p2, 128, 128, t - 16384);
  else if (t < 98304) packOne(W3, p3, 128, 512, t - 32768);
  else if (t < 360448) packOne(Wi, pi, 512, 512, t - 98304);
  else {
    int i = t - 360448;
    if (i < NN * 32) {
      float4 v = x[i];
      float sc = dinv[i >> 5];  // 32 float4 per 128-dim row
      ushort4 o;
      o.x = __half_as_ushort(__float2half(v.x * sc));
      o.y = __half_as_ushort(__float2half(v.y * sc));
      o.z = __half_as_ushort(__float2half(v.z * sc));
      o.w = __half_as_ushort(__float2half(v.w * sc));
      xh[i] = o;
    }
  }
}

// ------- Aggregation (pull, one wave/node, unroll-8, PRE-SCALED fp16 input) -------
// input rows already carry dinv[s]; out[i] = dinv[i]*(sum_s x'[s] + x'[i]) (plain)
__global__ void k_agg(const uint32* __restrict__ xi, uint32* __restrict__ o,
                      const int* __restrict__ csr, const int* __restrict__ offs,
                      const float* __restrict__ dinv, int n) {
  int node = blockIdx.x * 4 + (threadIdx.x >> 6);
  int lane = threadIdx.x & 63;
  if (node >= n) return;
  int beg = offs[node], end = offs[node + 1];
  float ax = 0.f, ay = 0.f;
  int j = beg;
  for (; j + 7 < end; j += 8) {
    int s[8];
    float2 rr[8];
#pragma unroll
    for (int q = 0; q < 8; q++) s[q] = csr[j + q];
#pragma unroll
    for (int q = 0; q < 8; q++) rr[q] = h2f2(xi[(ll64)s[q] * 64 + lane]);
#pragma unroll
    for (int q = 0; q < 8; q++) {
      ax += rr[q].x;
      ay += rr[q].y;
    }
  }
  for (; j < end; j++) {
    float2 r = h2f2(xi[(ll64)csr[j] * 64 + lane]);
    ax += r.x;
    ay += r.y;
  }
  float di = dinv[node];
  float2 sf = h2f2(xi[(ll64)node * 64 + lane]);
  float vx = di * (ax + sf.x);
  float vy = di * (ay + sf.y);
  o[(ll64)node * 64 + lane] = f2h2(vx, vy);
}

// -- MFMA GEMM: C = dinv[row]*relu(A@W + bias) (pre-scaled for next agg); reg dbuf --
__global__ __launch_bounds__(256, 4) void k_gemm_mfma(
    const u16* __restrict__ A, const u16* __restrict__ Bp,
    const float* __restrict__ bias, const float* __restrict__ dscale,
    u16* __restrict__ Co, int M, int N, int K) {
  int wave = threadIdx.x >> 6, lane = threadIdx.x & 63;
  int quad = lane >> 4, l16 = lane & 15;
  int row0 = blockIdx.x * 64, col0 = blockIdx.y * 64;
  int m = row0 + wave * 16 + l16;
  int mc = (m < M) ? m : (M - 1);
  int kbn = K >> 5;
  f32x4 acc[4] = {{0,0,0,0},{0,0,0,0},{0,0,0,0},{0,0,0,0}};
  const half8* Ar = (const half8*)&A[(ll64)mc * K];
  half8 ac = Ar[quad];
  half8 an = ac;
  half8 bc_[4], bn_[4];
#pragma unroll
  for (int nt = 0; nt < 4; nt++)
    bc_[nt] = *(const half8*)&Bp[((ll64)(((col0 >> 4) + nt) * kbn) * 64 + lane) * 8];
  for (int kb = 0; kb < kbn; kb++) {
    int kn = kb + 1;
    if (kn < kbn) {
      an = Ar[kn * 4 + quad];
#pragma unroll
      for (int nt = 0; nt < 4; nt++)
        bn_[nt] = *(const half8*)&Bp[((ll64)(((col0 >> 4) + nt) * kbn + kn) * 64 + lane) * 8];
    }
#pragma unroll
    for (int nt = 0; nt < 4; nt++)
      acc[nt] = __builtin_amdgcn_mfma_f32_16x16x32_f16(ac, bc_[nt], acc[nt], 0, 0, 0);
    ac = an;
#pragma unroll
    for (int nt = 0; nt < 4; nt++) bc_[nt] = bn_[nt];
  }
  float ds[4];
#pragma unroll
  for (int r = 0; r < 4; r++) {
    int rr = row0 + wave * 16 + quad * 4 + r;
    ds[r] = dscale[(rr < M) ? rr : (M - 1)];
  }
#pragma unroll
  for (int nt = 0; nt < 4; nt++) {
    int cc = col0 + nt * 16 + l16;
    float bv = bias[cc];
#pragma unroll
    for (int r = 0; r < 4; r++) {
      int rr = row0 + wave * 16 + quad * 4 + r;
      if (rr < M)
        Co[(ll64)rr * N + cc] =
            __half_as_ushort(__float2half(fmaxf(acc[nt][r] + bv, 0.0f) * ds[r]));
    }
  }
}

// ---- Fused tail (r9 32-row, measured 130 µs): h3 in LDS; out = relu(h3@Wi+bi)@Wc+bc
__global__ __launch_bounds__(256, 4) void k_tail32(
    const u16* __restrict__ a3, const u16* __restrict__ W3p,
    const float* __restrict__ b3, const u16* __restrict__ Wip,
    const float* __restrict__ bi, const float* __restrict__ Wc,
    const float* __restrict__ bc, float* __restrict__ out, int M) {
  __shared__ u16 h3s[32 * 512];     // 32 KB, col-octets xor-swizzled by row&7
  __shared__ float sRed[4][32][3];  // 1.5 KB
  int tid = threadIdx.x;
  int wave = tid >> 6, lane = tid & 63, quad = lane >> 4, l16 = lane & 15;
  int row0 = blockIdx.x * 32;  // NN % 32 == 0

  half8 af[2][4];
#pragma unroll
  for (int rt = 0; rt < 2; rt++) {
    const half8* Ar = (const half8*)&a3[(ll64)(row0 + rt * 16 + l16) * 128];
#pragma unroll
    for (int kb = 0; kb < 4; kb++) af[rt][kb] = Ar[kb * 4 + quad];
  }
  {
    f32x4 acc0 = {0, 0, 0, 0}, acc1 = {0, 0, 0, 0};
    half8 bcur = *(const half8*)&W3p[((ll64)(wave * 32) * 64 + lane) * 8];
    half8 bnxt = bcur;
    for (int t = 0; t < 32; t++) {
      if (t + 1 < 32)
        bnxt = *(const half8*)&W3p[((ll64)(wave * 32 + t + 1) * 64 + lane) * 8];
      int kb = t & 3;
      acc0 = __builtin_amdgcn_mfma_f32_16x16x32_f16(af[0][kb], bcur, acc0, 0, 0, 0);
      acc1 = __builtin_amdgcn_mfma_f32_16x16x32_f16(af[1][kb], bcur, acc1, 0, 0, 0);
      if (kb == 3) {
        int nt = wave * 8 + (t >> 2);
        int col = nt * 16 + l16;
        float bv = b3[col];
#pragma unroll
        for (int r = 0; r < 4; r++) {
          int row0l = quad * 4 + r;
          float v0 = fmaxf(acc0[r] + bv, 0.0f);
          float v1 = fmaxf(acc1[r] + bv, 0.0f);
          int oct0 = (col >> 3) ^ (row0l & 7);
          h3s[row0l * 512 + oct0 * 8 + (col & 7)] = __half_as_ushort(__float2half(v0));
          int row1l = 16 + row0l;
          int oct1 = (col >> 3) ^ (row1l & 7);
          h3s[row1l * 512 + oct1 * 8 + (col & 7)] = __half_as_ushort(__float2half(v1));
        }
        acc0 = (f32x4){0, 0, 0, 0};
        acc1 = (f32x4){0, 0, 0, 0};
      }
      bcur = bnxt;
    }
  }
  __syncthreads();

  float acc3[2][4][3] = {};
  {
    f32x4 acc0 = {0, 0, 0, 0}, acc1 = {0, 0, 0, 0};
    half8 bcur = *(const half8*)&Wip[((ll64)(wave * 128) * 64 + lane) * 8];
    half8 bnxt = bcur;
    int r0l = l16, r1l = 16 + l16;
    int sw0 = r0l & 7;
    for (int t = 0; t < 128; t++) {
      if (t + 1 < 128)
        bnxt = *(const half8*)&Wip[((ll64)(wave * 128 + t + 1) * 64 + lane) * 8];
      int kb = t & 15;
      int oct = ((kb * 4 + quad) ^ sw0);
      half8 a0 = *(const half8*)&h3s[r0l * 512 + oct * 8];
      half8 a1 = *(const half8*)&h3s[r1l * 512 + oct * 8];
      acc0 = __builtin_amdgcn_mfma_f32_16x16x32_f16(a0, bcur, acc0, 0, 0, 0);
      acc1 = __builtin_amdgcn_mfma_f32_16x16x32_f16(a1, bcur, acc1, 0, 0, 0);
      if (kb == 15) {
        int nt = wave * 8 + (t >> 4);
        int col = nt * 16 + l16;
        float bv = bi[col];
        float w0 = Wc[col * 3 + 0], w1 = Wc[col * 3 + 1], w2 = Wc[col * 3 + 2];
#pragma unroll
        for (int r = 0; r < 4; r++) {
          float v0 = fmaxf(acc0[r] + bv, 0.0f);
          float v1 = fmaxf(acc1[r] + bv, 0.0f);
          acc3[0][r][0] += v0 * w0; acc3[0][r][1] += v0 * w1; acc3[0][r][2] += v0 * w2;
          acc3[1][r][0] += v1 * w0; acc3[1][r][1] += v1 * w1; acc3[1][r][2] += v1 * w2;
        }
        acc0 = (f32x4){0, 0, 0, 0};
        acc1 = (f32x4){0, 0, 0, 0};
      }
      bcur = bnxt;
    }
  }
#pragma unroll
  for (int rt = 0; rt < 2; rt++)
#pragma unroll
    for (int r = 0; r < 4; r++)
#pragma unroll
      for (int c = 0; c < 3; c++) {
        float v = acc3[rt][r][c];
        v += __shfl_xor(v, 1);
        v += __shfl_xor(v, 2);
        v += __shfl_xor(v, 4);
        v += __shfl_xor(v, 8);
        acc3[rt][r][c] = v;
      }
  if (l16 == 0) {
#pragma unroll
    for (int rt = 0; rt < 2; rt++)
#pragma unroll
      for (int r = 0; r < 4; r++)
#pragma unroll
        for (int c = 0; c < 3; c++)
          sRed[wave][rt * 16 + quad * 4 + r][c] = acc3[rt][r][c];
  }
  __syncthreads();
  if (tid < 96) {
    int row = tid / 3, c = tid % 3;
    out[(ll64)(row0 + row) * 3 + c] = sRed[0][row][c] + sRed[1][row][c] +
                                      sRed[2][row][c] + sRed[3][row][c] + bc[c];
  }
}

// ---------------- launcher ----------------
extern "C" void kernel_launch(void* const* d_in, const int* in_sizes, int n_in,
                              void* d_out, int out_size, void* d_ws, size_t ws_size,
                              hipStream_t stream) {
  const float* x  = (const float*)d_in[0];
  const void*  ei = d_in[1];
  const float* W1 = (const float*)d_in[2];
  const float* b1 = (const float*)d_in[3];
  const float* W2 = (const float*)d_in[4];
  const float* b2 = (const float*)d_in[5];
  const float* W3 = (const float*)d_in[6];
  const float* b3 = (const float*)d_in[7];
  const float* Wi = (const float*)d_in[8];
  const float* bi = (const float*)d_in[9];
  const float* Wc = (const float*)d_in[10];
  const float* bc = (const float*)d_in[11];
  float* out = (float*)d_out;

  char* ws = (char*)d_ws;
  const ll64 KB = 1ll << 10, MB = 1ll << 20;
  float* dinv  = (float*)(ws + 0);                 // 400 KB
  int*   offs  = (int*)(ws + 512 * KB);            // 400 KB (NN+1)
  int*   total = (int*)(ws + 1 * MB + 64 * KB);    // 1.6 KB
  int*   bbase = (int*)(ws + 1 * MB + 128 * KB);   // 1.6 KB
  int*   tbl   = (int*)(ws + 1 * MB + 192 * KB);   // 800 KB -> ends ~2 MB
  uint32* binned = (uint32*)(ws + 2 * MB);         // 12.8 MB -> 14.8
  int*   csr   = (int*)(ws + 15 * MB);             // 12.8 MB -> 27.8
  u16* pW1 = (u16*)(ws + 28 * MB);                 // 32 KB
  u16* pW2 = (u16*)(ws + 28 * MB + 64 * KB);       // 32 KB
  u16* pW3 = (u16*)(ws + 28 * MB + 128 * KB);      // 128 KB
  u16* pWi = (u16*)(ws + 28 * MB + 512 * KB);      // 512 KB
  u16* xh   = (u16*)(ws + 29 * MB);                // 25.6 MB -> 54.6
  u16* bufA = (u16*)(ws + 55 * MB);                // 25.6 MB -> 80.6
  u16* bufB = (u16*)(ws + 81 * MB);                // 25.6 MB -> 106.6

  const int TB = 256;
  k_binB<<<NBLK, TB, 0, stream>>>(ei, tbl);
  k_binC1<<<NB, NBLK, 0, stream>>>(tbl, total);
  k_binC2<<<1, 512, 0, stream>>>(total, bbase, offs);
  k_binD<<<NBLK, TB, 0, stream>>>(ei, tbl, bbase, binned);
  k_binE<<<NB, TB, 0, stream>>>(binned, bbase, total, offs, dinv, csr);
  // pack weights + convert x to dinv-prescaled fp16 (after binE: dinv ready)
  k_packhalf<<<(360448 + NN * 32 + TB - 1) / TB, TB, 0, stream>>>(
      W1, W2, W3, Wi, pW1, pW2, pW3, pWi, (const float4*)x, (ushort4*)xh, dinv);

  const int MBk = (NN + 63) / 64;  // 1563
  int aggBlocks = (NN + 3) / 4;
  dim3 g128(MBk, 2);

  // layer 1
  k_agg<<<aggBlocks, TB, 0, stream>>>((const uint32*)xh, (uint32*)bufA, csr, offs, dinv, NN);
  k_gemm_mfma<<<g128, TB, 0, stream>>>(bufA, pW1, b1, dinv, bufB, NN, 128, 128);
  // layer 2
  k_agg<<<aggBlocks, TB, 0, stream>>>((const uint32*)bufB, (uint32*)bufA, csr, offs, dinv, NN);
  k_gemm_mfma<<<g128, TB, 0, stream>>>(bufA, pW2, b2, dinv, bufB, NN, 128, 128);
  // layer 3 aggregation, then fused GEMM512 + MLP head
  k_agg<<<aggBlocks, TB, 0, stream>>>((const uint32*)bufB, (uint32*)bufA, csr, offs, dinv, NN);
  k_tail32<<<NN / 32, TB, 0, stream>>>(bufA, pW3, b3, pWi, bi, Wc, bc, out, NN);
}

// Round 12
// 698.382 us; speedup vs baseline: 4.0099x; 1.0253x over previous
//
#include <hip/hip_runtime.h>
#include <hip/hip_fp16.h>

#define NN 100000
#define NE 3200000
#define NB 391          // coarse buckets of 256 nodes (dst >> 8)
#define NBLK 512        // edge-partition blocks for bin build
#define EPB 6250        // edges per block (NBLK * EPB == NE)
// dims: IN=128, HID=128, INT=512, OUT=3
// fp32 tensors on device; edge_index dtype probed per-block (int32/int64); fp32 out.
// Numerics: fp16 intermediates (dinv-prescaled) + single-pass fp16 weights; MFMA f16,
// fp32 acc (comparison floor measured at 1.2207e-4 = 2^-13).
// Round 12: agg = 4 nodes/wave with uint4 gathers (1 KB/instr, 4x fewer issues);
// tail32 B-prefetch depth-3 ring.

typedef unsigned int uint32;
typedef unsigned short u16;
typedef long long ll64;
typedef __attribute__((ext_vector_type(8))) _Float16 half8;
typedef __attribute__((ext_vector_type(4))) float f32x4;

__device__ inline float2 h2f2(uint32 u) {
  __half2 h = *reinterpret_cast<__half2*>(&u);
  return __half22float2(h);
}
__device__ inline uint32 f2h2(float x, float y) {
  return (uint32)__half_as_ushort(__float2half(x)) |
         ((uint32)__half_as_ushort(__float2half(y)) << 16);
}
__device__ inline int edge_at(const void* ei, int is64, ll64 idx) {
  return is64 ? (int)((const ll64*)ei)[idx] : ((const int*)ei)[idx];
}
__device__ inline int detect64(const int* ei32) {
  int acc = 0;
#pragma unroll
  for (int k = 1; k < 32; k += 2) acc |= ei32[k];
  return (acc == 0) ? 1 : 0;
}

// ---- CSR build, 2-level counting sort ----
__global__ __launch_bounds__(256) void k_binB(const void* __restrict__ ei,
                                              int* __restrict__ tbl) {
  __shared__ int h[NB];
  __shared__ int sIs64;
  int k = blockIdx.x, tid = threadIdx.x;
  for (int i = tid; i < NB; i += 256) h[i] = 0;
  if (tid == 0) sIs64 = detect64((const int*)ei);
  __syncthreads();
  int is64 = sIs64;
  ll64 beg = (ll64)k * EPB, end = beg + EPB;
  for (ll64 i = beg + tid; i < end; i += 256)
    atomicAdd(&h[edge_at(ei, is64, (ll64)NE + i) >> 8], 1);
  __syncthreads();
  for (int i = tid; i < NB; i += 256) tbl[k * NB + i] = h[i];
}
__global__ __launch_bounds__(512) void k_binC1(int* __restrict__ tbl,
                                               int* __restrict__ total) {
  __shared__ int sd[NBLK];
  int b = blockIdx.x, tid = threadIdx.x;
  int v = tbl[tid * NB + b];
  sd[tid] = v;
  __syncthreads();
  for (int off = 1; off < NBLK; off <<= 1) {
    int t = (tid >= off) ? sd[tid - off] : 0;
    __syncthreads();
    sd[tid] += t;
    __syncthreads();
  }
  tbl[tid * NB + b] = sd[tid] - v;
  if (tid == NBLK - 1) total[b] = sd[NBLK - 1];
}
__global__ __launch_bounds__(512) void k_binC2(const int* __restrict__ total,
                                               int* __restrict__ bbase,
                                               int* __restrict__ offs) {
  __shared__ int sd[512];
  int tid = threadIdx.x;
  int v = (tid < NB) ? total[tid] : 0;
  sd[tid] = v;
  __syncthreads();
  for (int off = 1; off < 512; off <<= 1) {
    int t = (tid >= off) ? sd[tid - off] : 0;
    __syncthreads();
    sd[tid] += t;
    __syncthreads();
  }
  if (tid < NB) bbase[tid] = sd[tid] - v;
  if (tid == 0) offs[NN] = NE;
}
__global__ __launch_bounds__(256) void k_binD(const void* __restrict__ ei,
                                              const int* __restrict__ tbl,
                                              const int* __restrict__ bbase,
                                              uint32* __restrict__ binned) {
  __shared__ int lb[NB];
  __shared__ int lc[NB];
  __shared__ int sIs64;
  int k = blockIdx.x, tid = threadIdx.x;
  for (int i = tid; i < NB; i += 256) {
    lb[i] = tbl[k * NB + i] + bbase[i];
    lc[i] = 0;
  }
  if (tid == 0) sIs64 = detect64((const int*)ei);
  __syncthreads();
  int is64 = sIs64;
  ll64 beg = (ll64)k * EPB, end = beg + EPB;
  for (ll64 i = beg + tid; i < end; i += 256) {
    int s = edge_at(ei, is64, i);
    int d = edge_at(ei, is64, (ll64)NE + i);
    int b = d >> 8;
    int r = atomicAdd(&lc[b], 1);
    binned[lb[b] + r] = (uint32)s | ((uint32)(d & 255) << 24);
  }
}
__global__ __launch_bounds__(256) void k_binE(const uint32* __restrict__ binned,
                                              const int* __restrict__ bbase,
                                              const int* __restrict__ total,
                                              int* __restrict__ offs,
                                              float* __restrict__ dinv,
                                              int* __restrict__ csr) {
  __shared__ int cnt[256], pref[256], fil[256];
  int b = blockIdx.x, tid = threadIdx.x;
  cnt[tid] = 0;
  fil[tid] = 0;
  __syncthreads();
  int base = bbase[b], tot = total[b];
  for (int i = tid; i < tot; i += 256) atomicAdd(&cnt[binned[base + i] >> 24], 1);
  __syncthreads();
  int v = cnt[tid];
  pref[tid] = v;
  __syncthreads();
  for (int off = 1; off < 256; off <<= 1) {
    int t = (tid >= off) ? pref[tid - off] : 0;
    __syncthreads();
    pref[tid] += t;
    __syncthreads();
  }
  int myoff = pref[tid] - v;  // exclusive
  pref[tid] = myoff;
  int node = b * 256 + tid;
  if (node < NN) {
    offs[node] = base + myoff;
    dinv[node] = rsqrtf((float)(v + 1));  // +1: self-loop
  }
  __syncthreads();
  for (int i = tid; i < tot; i += 256) {
    uint32 w = binned[base + i];
    int dl = w >> 24;
    int r = atomicAdd(&fil[dl], 1);
    csr[base + pref[dl] + r] = (int)(w & 0xFFFFFFu);
  }
}

// ---- weight pack (fp16 B-fragment order) + x -> dinv-prescaled fp16 ----
__device__ inline void packOne(const float* __restrict__ W, u16* __restrict__ ph,
                               int K, int N, int t) {
  int j = t & 7, lane = (t >> 3) & 63, tl = t >> 9;
  int kbn = K >> 5;
  int kb = tl % kbn, ntile = tl / kbn;
  int k = kb * 32 + (lane >> 4) * 8 + j;
  int n2 = ntile * 16 + (lane & 15);
  ph[t] = __half_as_ushort(__float2half(W[k * N + n2]));
}
__global__ void k_packhalf(const float* W1, const float* W2, const float* W3,
                           const float* Wi, u16* p1, u16* p2, u16* p3, u16* pi,
                           const float4* __restrict__ x, ushort4* __restrict__ xh,
                           const float* __restrict__ dinv) {
  int t = blockIdx.x * blockDim.x + threadIdx.x;
  if (t < 16384) packOne(W1, p1, 128, 128, t);
  else if (t < 32768) packOne(W2, p2, 128, 128, t - 16384);
  else if (t < 98304) packOne(W3, p3, 128, 512, t - 32768);
  else if (t < 360448) packOne(Wi, pi, 512, 512, t - 98304);
  else {
    int i = t - 360448;
    if (i < NN * 32) {
      float4 v = x[i];
      float sc = dinv[i >> 5];  // 32 float4 per 128-dim row
      ushort4 o;
      o.x = __half_as_ushort(__float2half(v.x * sc));
      o.y = __half_as_ushort(__float2half(v.y * sc));
      o.z = __half_as_ushort(__float2half(v.z * sc));
      o.w = __half_as_ushort(__float2half(v.w * sc));
      xh[i] = o;
    }
  }
}

// ---- Aggregation: 4 nodes/wave (16 lanes per node, uint4 = 16B/lane gathers) ----
// input rows carry dinv[s]; out[i] = dinv[i]*(sum_s x'[s] + x'[i])
__global__ void k_agg(const uint32* __restrict__ xi, uint32* __restrict__ o,
                      const int* __restrict__ csr, const int* __restrict__ offs,
                      const float* __restrict__ dinv, int n) {
  int tid = threadIdx.x;
  int lane = tid & 63;
  int sub = lane >> 4, fl = lane & 15;
  int node = blockIdx.x * 16 + (tid >> 6) * 4 + sub;
  if (node >= n) return;
  int beg = offs[node], end = offs[node + 1];
  const uint4* xv = (const uint4*)xi;  // 16 uint4 per 128-dim row
  float acc[8] = {};
  int j = beg;
  for (; j + 3 < end; j += 4) {
    int s[4];
    uint4 r[4];
#pragma unroll
    for (int q = 0; q < 4; q++) s[q] = csr[j + q];
#pragma unroll
    for (int q = 0; q < 4; q++) r[q] = xv[(ll64)s[q] * 16 + fl];
#pragma unroll
    for (int q = 0; q < 4; q++) {
      float2 p0 = h2f2(r[q].x), p1 = h2f2(r[q].y);
      float2 p2 = h2f2(r[q].z), p3 = h2f2(r[q].w);
      acc[0] += p0.x; acc[1] += p0.y; acc[2] += p1.x; acc[3] += p1.y;
      acc[4] += p2.x; acc[5] += p2.y; acc[6] += p3.x; acc[7] += p3.y;
    }
  }
  for (; j < end; j++) {
    uint4 r = xv[(ll64)csr[j] * 16 + fl];
    float2 p0 = h2f2(r.x), p1 = h2f2(r.y), p2 = h2f2(r.z), p3 = h2f2(r.w);
    acc[0] += p0.x; acc[1] += p0.y; acc[2] += p1.x; acc[3] += p1.y;
    acc[4] += p2.x; acc[5] += p2.y; acc[6] += p3.x; acc[7] += p3.y;
  }
  float di = dinv[node];
  uint4 sf = xv[(ll64)node * 16 + fl];
  float2 q0 = h2f2(sf.x), q1 = h2f2(sf.y), q2 = h2f2(sf.z), q3 = h2f2(sf.w);
  uint4 ov;
  ov.x = f2h2(di * (acc[0] + q0.x), di * (acc[1] + q0.y));
  ov.y = f2h2(di * (acc[2] + q1.x), di * (acc[3] + q1.y));
  ov.z = f2h2(di * (acc[4] + q2.x), di * (acc[5] + q2.y));
  ov.w = f2h2(di * (acc[6] + q3.x), di * (acc[7] + q3.y));
  ((uint4*)o)[(ll64)node * 16 + fl] = ov;
}

// -- MFMA GEMM: C = dinv[row]*relu(A@W + bias) (pre-scaled for next agg); reg dbuf --
__global__ __launch_bounds__(256, 4) void k_gemm_mfma(
    const u16* __restrict__ A, const u16* __restrict__ Bp,
    const float* __restrict__ bias, const float* __restrict__ dscale,
    u16* __restrict__ Co, int M, int N, int K) {
  int wave = threadIdx.x >> 6, lane = threadIdx.x & 63;
  int quad = lane >> 4, l16 = lane & 15;
  int row0 = blockIdx.x * 64, col0 = blockIdx.y * 64;
  int m = row0 + wave * 16 + l16;
  int mc = (m < M) ? m : (M - 1);
  int kbn = K >> 5;
  f32x4 acc[4] = {{0,0,0,0},{0,0,0,0},{0,0,0,0},{0,0,0,0}};
  const half8* Ar = (const half8*)&A[(ll64)mc * K];
  half8 ac = Ar[quad];
  half8 an = ac;
  half8 bc_[4], bn_[4];
#pragma unroll
  for (int nt = 0; nt < 4; nt++)
    bc_[nt] = *(const half8*)&Bp[((ll64)(((col0 >> 4) + nt) * kbn) * 64 + lane) * 8];
  for (int kb = 0; kb < kbn; kb++) {
    int kn = kb + 1;
    if (kn < kbn) {
      an = Ar[kn * 4 + quad];
#pragma unroll
      for (int nt = 0; nt < 4; nt++)
        bn_[nt] = *(const half8*)&Bp[((ll64)(((col0 >> 4) + nt) * kbn + kn) * 64 + lane) * 8];
    }
#pragma unroll
    for (int nt = 0; nt < 4; nt++)
      acc[nt] = __builtin_amdgcn_mfma_f32_16x16x32_f16(ac, bc_[nt], acc[nt], 0, 0, 0);
    ac = an;
#pragma unroll
    for (int nt = 0; nt < 4; nt++) bc_[nt] = bn_[nt];
  }
  float ds[4];
#pragma unroll
  for (int r = 0; r < 4; r++) {
    int rr = row0 + wave * 16 + quad * 4 + r;
    ds[r] = dscale[(rr < M) ? rr : (M - 1)];
  }
#pragma unroll
  for (int nt = 0; nt < 4; nt++) {
    int cc = col0 + nt * 16 + l16;
    float bv = bias[cc];
#pragma unroll
    for (int r = 0; r < 4; r++) {
      int rr = row0 + wave * 16 + quad * 4 + r;
      if (rr < M)
        Co[(ll64)rr * N + cc] =
            __half_as_ushort(__float2half(fmaxf(acc[nt][r] + bv, 0.0f) * ds[r]));
    }
  }
}

// ---- Fused tail 32-row: h3 in LDS; out = relu(h3@Wi+bi)@Wc+bc; depth-3 B ring ----
__global__ __launch_bounds__(256, 4) void k_tail32(
    const u16* __restrict__ a3, const u16* __restrict__ W3p,
    const float* __restrict__ b3, const u16* __restrict__ Wip,
    const float* __restrict__ bi, const float* __restrict__ Wc,
    const float* __restrict__ bc, float* __restrict__ out, int M) {
  __shared__ u16 h3s[32 * 512];     // 32 KB, col-octets xor-swizzled by row&7
  __shared__ float sRed[4][32][3];  // 1.5 KB
  int tid = threadIdx.x;
  int wave = tid >> 6, lane = tid & 63, quad = lane >> 4, l16 = lane & 15;
  int row0 = blockIdx.x * 32;  // NN % 32 == 0

  half8 af[2][4];
#pragma unroll
  for (int rt = 0; rt < 2; rt++) {
    const half8* Ar = (const half8*)&a3[(ll64)(row0 + rt * 16 + l16) * 128];
#pragma unroll
    for (int kb = 0; kb < 4; kb++) af[rt][kb] = Ar[kb * 4 + quad];
  }
  // ---- phase 1: 32x512 = a3[32x128] @ W3 into LDS; ring prefetch depth 3 ----
  {
    f32x4 acc0 = {0, 0, 0, 0}, acc1 = {0, 0, 0, 0};
    half8 bq[4];
#pragma unroll
    for (int p = 0; p < 3; p++)
      bq[p] = *(const half8*)&W3p[((ll64)(wave * 32 + p) * 64 + lane) * 8];
#pragma unroll 4
    for (int t = 0; t < 32; t++) {
      if (t + 3 < 32)
        bq[(t + 3) & 3] = *(const half8*)&W3p[((ll64)(wave * 32 + t + 3) * 64 + lane) * 8];
      half8 bcur = bq[t & 3];
      int kb = t & 3;
      acc0 = __builtin_amdgcn_mfma_f32_16x16x32_f16(af[0][kb], bcur, acc0, 0, 0, 0);
      acc1 = __builtin_amdgcn_mfma_f32_16x16x32_f16(af[1][kb], bcur, acc1, 0, 0, 0);
      if (kb == 3) {
        int nt = wave * 8 + (t >> 2);
        int col = nt * 16 + l16;
        float bv = b3[col];
#pragma unroll
        for (int r = 0; r < 4; r++) {
          int row0l = quad * 4 + r;
          float v0 = fmaxf(acc0[r] + bv, 0.0f);
          float v1 = fmaxf(acc1[r] + bv, 0.0f);
          int oct0 = (col >> 3) ^ (row0l & 7);
          h3s[row0l * 512 + oct0 * 8 + (col & 7)] = __half_as_ushort(__float2half(v0));
          int row1l = 16 + row0l;
          int oct1 = (col >> 3) ^ (row1l & 7);
          h3s[row1l * 512 + oct1 * 8 + (col & 7)] = __half_as_ushort(__float2half(v1));
        }
        acc0 = (f32x4){0, 0, 0, 0};
        acc1 = (f32x4){0, 0, 0, 0};
      }
    }
  }
  __syncthreads();

  // ---- phase 2: h3s @ Wi (K=512) + fold Wc; ring prefetch depth 3 ----
  float acc3[2][4][3] = {};
  {
    f32x4 acc0 = {0, 0, 0, 0}, acc1 = {0, 0, 0, 0};
    half8 bq[4];
#pragma unroll
    for (int p = 0; p < 3; p++)
      bq[p] = *(const half8*)&Wip[((ll64)(wave * 128 + p) * 64 + lane) * 8];
    int r0l = l16, r1l = 16 + l16;
    int sw0 = r0l & 7;
#pragma unroll 4
    for (int t = 0; t < 128; t++) {
      if (t + 3 < 128)
        bq[(t + 3) & 3] = *(const half8*)&Wip[((ll64)(wave * 128 + t + 3) * 64 + lane) * 8];
      half8 bcur = bq[t & 3];
      int kb = t & 15;
      int oct = ((kb * 4 + quad) ^ sw0);
      half8 a0 = *(const half8*)&h3s[r0l * 512 + oct * 8];
      half8 a1 = *(const half8*)&h3s[r1l * 512 + oct * 8];
      acc0 = __builtin_amdgcn_mfma_f32_16x16x32_f16(a0, bcur, acc0, 0, 0, 0);
      acc1 = __builtin_amdgcn_mfma_f32_16x16x32_f16(a1, bcur, acc1, 0, 0, 0);
      if (kb == 15) {
        int nt = wave * 8 + (t >> 4);
        int col = nt * 16 + l16;
        float bv = bi[col];
        float w0 = Wc[col * 3 + 0], w1 = Wc[col * 3 + 1], w2 = Wc[col * 3 + 2];
#pragma unroll
        for (int r = 0; r < 4; r++) {
          float v0 = fmaxf(acc0[r] + bv, 0.0f);
          float v1 = fmaxf(acc1[r] + bv, 0.0f);
          acc3[0][r][0] += v0 * w0; acc3[0][r][1] += v0 * w1; acc3[0][r][2] += v0 * w2;
          acc3[1][r][0] += v1 * w0; acc3[1][r][1] += v1 * w1; acc3[1][r][2] += v1 * w2;
        }
        acc0 = (f32x4){0, 0, 0, 0};
        acc1 = (f32x4){0, 0, 0, 0};
      }
    }
  }
#pragma unroll
  for (int rt = 0; rt < 2; rt++)
#pragma unroll
    for (int r = 0; r < 4; r++)
#pragma unroll
      for (int c = 0; c < 3; c++) {
        float v = acc3[rt][r][c];
        v += __shfl_xor(v, 1);
        v += __shfl_xor(v, 2);
        v += __shfl_xor(v, 4);
        v += __shfl_xor(v, 8);
        acc3[rt][r][c] = v;
      }
  if (l16 == 0) {
#pragma unroll
    for (int rt = 0; rt < 2; rt++)
#pragma unroll
      for (int r = 0; r < 4; r++)
#pragma unroll
        for (int c = 0; c < 3; c++)
          sRed[wave][rt * 16 + quad * 4 + r][c] = acc3[rt][r][c];
  }
  __syncthreads();
  if (tid < 96) {
    int row = tid / 3, c = tid % 3;
    out[(ll64)(row0 + row) * 3 + c] = sRed[0][row][c] + sRed[1][row][c] +
                                      sRed[2][row][c] + sRed[3][row][c] + bc[c];
  }
}

// ---------------- launcher ----------------
extern "C" void kernel_launch(void* const* d_in, const int* in_sizes, int n_in,
                              void* d_out, int out_size, void* d_ws, size_t ws_size,
                              hipStream_t stream) {
  const float* x  = (const float*)d_in[0];
  const void*  ei = d_in[1];
  const float* W1 = (const float*)d_in[2];
  const float* b1 = (const float*)d_in[3];
  const float* W2 = (const float*)d_in[4];
  const float* b2 = (const float*)d_in[5];
  const float* W3 = (const float*)d_in[6];
  const float* b3 = (const float*)d_in[7];
  const float* Wi = (const float*)d_in[8];
  const float* bi = (const float*)d_in[9];
  const float* Wc = (const float*)d_in[10];
  const float* bc = (const float*)d_in[11];
  float* out = (float*)d_out;

  char* ws = (char*)d_ws;
  const ll64 KB = 1ll << 10, MB = 1ll << 20;
  float* dinv  = (float*)(ws + 0);                 // 400 KB
  int*   offs  = (int*)(ws + 512 * KB);            // 400 KB (NN+1)
  int*   total = (int*)(ws + 1 * MB + 64 * KB);    // 1.6 KB
  int*   bbase = (int*)(ws + 1 * MB + 128 * KB);   // 1.6 KB
  int*   tbl   = (int*)(ws + 1 * MB + 192 * KB);   // 800 KB -> ends ~2 MB
  uint32* binned = (uint32*)(ws + 2 * MB);         // 12.8 MB -> 14.8
  int*   csr   = (int*)(ws + 15 * MB);             // 12.8 MB -> 27.8
  u16* pW1 = (u16*)(ws + 28 * MB);                 // 32 KB
  u16* pW2 = (u16*)(ws + 28 * MB + 64 * KB);       // 32 KB
  u16* pW3 = (u16*)(ws + 28 * MB + 128 * KB);      // 128 KB
  u16* pWi = (u16*)(ws + 28 * MB + 512 * KB);      // 512 KB
  u16* xh   = (u16*)(ws + 29 * MB);                // 25.6 MB -> 54.6
  u16* bufA = (u16*)(ws + 55 * MB);                // 25.6 MB -> 80.6
  u16* bufB = (u16*)(ws + 81 * MB);                // 25.6 MB -> 106.6

  const int TB = 256;
  k_binB<<<NBLK, TB, 0, stream>>>(ei, tbl);
  k_binC1<<<NB, NBLK, 0, stream>>>(tbl, total);
  k_binC2<<<1, 512, 0, stream>>>(total, bbase, offs);
  k_binD<<<NBLK, TB, 0, stream>>>(ei, tbl, bbase, binned);
  k_binE<<<NB, TB, 0, stream>>>(binned, bbase, total, offs, dinv, csr);
  // pack weights + convert x to dinv-prescaled fp16 (after binE: dinv ready)
  k_packhalf<<<(360448 + NN * 32 + TB - 1) / TB, TB, 0, stream>>>(
      W1, W2, W3, Wi, pW1, pW2, pW3, pWi, (const float4*)x, (ushort4*)xh, dinv);

  const int MBk = (NN + 63) / 64;  // 1563
  int aggBlocks = (NN + 15) / 16;  // 16 nodes per block (4 per wave)
  dim3 g128(MBk, 2);

  // layer 1
  k_agg<<<aggBlocks, TB, 0, stream>>>((const uint32*)xh, (uint32*)bufA, csr, offs, dinv, NN);
  k_gemm_mfma<<<g128, TB, 0, stream>>>(bufA, pW1, b1, dinv, bufB, NN, 128, 128);
  // layer 2
  k_agg<<<aggBlocks, TB, 0, stream>>>((const uint32*)bufB, (uint32*)bufA, csr, offs, dinv, NN);
  k_gemm_mfma<<<g128, TB, 0, stream>>>(bufA, pW2, b2, dinv, bufB, NN, 128, 128);
  // layer 3 aggregation, then fused GEMM512 + MLP head
  k_agg<<<aggBlocks, TB, 0, stream>>>((const uint32*)bufB, (uint32*)bufA, csr, offs, dinv, NN);
  k_tail32<<<NN / 32, TB, 0, stream>>>(bufA, pW3, b3, pWi, bi, Wc, bc, out, NN);
}